// Round 2
// baseline (563.666 us; speedup 1.0000x reference)
//
#include <hip/hip_runtime.h>
#include <hip/hip_bf16.h>
#include <math.h>

typedef __hip_bfloat16 bf16;
typedef __attribute__((ext_vector_type(4))) float f32x4;
typedef __attribute__((ext_vector_type(8))) short s16x8;

#define T_SEQ 2048
#define DIM   2048
#define NH    16
#define HD    128
#define LAT   512
#define RD    64
#define TOPK  32

// ---------------------------------------------------------------------------
// load8: read 8 consecutive elements as bf16 (converting from fp32 if needed)
// ---------------------------------------------------------------------------
__device__ __forceinline__ void load8(const float* __restrict__ src, bf16* dst)
{
    float4 a = *(const float4*)src;
    float4 b = *(const float4*)(src + 4);
    dst[0] = __float2bfloat16(a.x); dst[1] = __float2bfloat16(a.y);
    dst[2] = __float2bfloat16(a.z); dst[3] = __float2bfloat16(a.w);
    dst[4] = __float2bfloat16(b.x); dst[5] = __float2bfloat16(b.y);
    dst[6] = __float2bfloat16(b.z); dst[7] = __float2bfloat16(b.w);
}
__device__ __forceinline__ void load8(const bf16* __restrict__ src, bf16* dst)
{
    *(uint4*)dst = *(const uint4*)src;
}
__device__ __forceinline__ void storeC(float* C, size_t idx, float v) { C[idx] = v; }
__device__ __forceinline__ void storeC(bf16*  C, size_t idx, float v) { C[idx] = __float2bfloat16(v); }

// ---------------------------------------------------------------------------
// Generic GEMM: C(M,N) = A(M,K) @ B(K,N), row-major. A/B fp32 or bf16
// (converted to bf16 during LDS staging), fp32 accumulate via
// v_mfma_f32_16x16x32_bf16, C written as bf16 or fp32.
// Block = 256 threads = 4 waves; tile 64x64, BK=32; wave does 32x32 (2x2 MFMA).
// All M,N,K multiples of tile dims for every call here -> no bounds checks.
// ---------------------------------------------------------------------------
template<typename TA, typename TB, typename TC>
__global__ __launch_bounds__(256)
void gemm64(const TA* __restrict__ A, const TB* __restrict__ B,
            TC* __restrict__ C, int M, int N, int K)
{
    // row stride 40 elems = 80B = 5*16B keeps ds_read_b128 alignment
    __shared__ bf16 a_lds[64][40];   // [m][k]
    __shared__ bf16 b_lds[64][40];   // [n][k]  (B staged transposed)

    const int tid  = threadIdx.x;
    const int wave = tid >> 6;
    const int lane = tid & 63;
    const int quad = lane >> 4;
    const int l16  = lane & 15;

    const int tile_m = blockIdx.y * 64;
    const int tile_n = blockIdx.x * 64;
    const int wrow = (wave >> 1) * 32;
    const int wcol = (wave & 1) * 32;

    f32x4 acc[2][2] = {};

    const int ar   = tid >> 2;          // A: 64 rows x 32 cols, 8 elems/thread
    const int aseg = (tid & 3) * 8;
    const int bk   = tid >> 3;          // B: 32 rows x 64 cols, 8 elems/thread
    const int bn   = (tid & 7) * 8;

    for (int k0 = 0; k0 < K; k0 += 32) {
        {   // stage A tile
            bf16 tmp[8];
            load8(A + (size_t)(tile_m + ar) * K + k0 + aseg, tmp);
            *(uint4*)(&a_lds[ar][aseg]) = *(uint4*)tmp;
        }
        {   // stage B tile, transposed into [n][k]
            bf16 tmp[8];
            load8(B + (size_t)(k0 + bk) * N + tile_n + bn, tmp);
#pragma unroll
            for (int j = 0; j < 8; ++j) b_lds[bn + j][bk] = tmp[j];
        }
        __syncthreads();

        // fragments: A[m=l16][k=quad*8+j], B[k=quad*8+j][n=l16]
        s16x8 af[2], bfr[2];
#pragma unroll
        for (int i = 0; i < 2; ++i)
            af[i] = *(const s16x8*)(&a_lds[wrow + i * 16 + l16][quad * 8]);
#pragma unroll
        for (int j = 0; j < 2; ++j)
            bfr[j] = *(const s16x8*)(&b_lds[wcol + j * 16 + l16][quad * 8]);

#pragma unroll
        for (int i = 0; i < 2; ++i)
#pragma unroll
            for (int j = 0; j < 2; ++j)
                acc[i][j] = __builtin_amdgcn_mfma_f32_16x16x32_bf16(
                    af[i], bfr[j], acc[i][j], 0, 0, 0);
        __syncthreads();
    }

    // D mapping: col=lane&15, row=(lane>>4)*4+reg   [m89-verified]
#pragma unroll
    for (int i = 0; i < 2; ++i) {
#pragma unroll
        for (int j = 0; j < 2; ++j) {
            const int col = tile_n + wcol + j * 16 + l16;
#pragma unroll
            for (int r = 0; r < 4; ++r) {
                const int row = tile_m + wrow + i * 16 + quad * 4 + r;
                storeC(C, (size_t)row * N + col, acc[i][j][r]);
            }
        }
    }
}

// ---------------------------------------------------------------------------
// In-place RoPE over (T, nvec, 64): thread handles rotation pair (i, i+32).
// freqs match ref: 10000^(-i/32), i = 0..31; position = t.
// ---------------------------------------------------------------------------
__global__ __launch_bounds__(256)
void rope_kernel(bf16* buf, int nvec)
{
    int idx = blockIdx.x * blockDim.x + threadIdx.x;
    int total = T_SEQ * nvec * 32;
    if (idx >= total) return;
    int i    = idx & 31;
    int rest = idx >> 5;
    int vec  = rest % nvec;
    int t    = rest / nvec;

    bf16* p = buf + ((size_t)t * nvec + vec) * 64;
    float x0 = (float)p[i];
    float x1 = (float)p[i + 32];
    float ang = (float)t * powf(10000.f, -(float)i / 32.f);
    float c = cosf(ang), s = sinf(ang);
    p[i]      = __float2bfloat16(x0 * c - x1 * s);
    p[i + 32] = __float2bfloat16(x1 * c + x0 * s);
}

// ---------------------------------------------------------------------------
// Top-k sparse attention. One wave per (h, t). 2 lanes per selected token
// compute the score (split over 128 q-dims + 64 rope dims), pair-sum via
// shfl_xor(1), wave softmax via xor strides 2..32 (parity classes cover all
// 32 tokens). PV: lane owns output dims (2*lane, 2*lane+1).
// ---------------------------------------------------------------------------
__device__ __forceinline__ float dot8(const bf16* __restrict__ a,
                                      const bf16* __restrict__ b, float acc)
{
    union { uint4 u; __hip_bfloat162 h[4]; } ua, ub;
    ua.u = *(const uint4*)a;
    ub.u = *(const uint4*)b;
#pragma unroll
    for (int i = 0; i < 4; ++i) {
        float2 fa = __bfloat1622float2(ua.h[i]);
        float2 fb = __bfloat1622float2(ub.h[i]);
        acc += fa.x * fb.x + fa.y * fb.y;
    }
    return acc;
}

__global__ __launch_bounds__(256)
void attn_kernel(const bf16* __restrict__ q, const bf16* __restrict__ qr,
                 const bf16* __restrict__ k, const bf16* __restrict__ v,
                 const bf16* __restrict__ kr, const int* __restrict__ topk,
                 bf16* __restrict__ o)
{
    const int wid  = (blockIdx.x * blockDim.x + threadIdx.x) >> 6;
    const int lane = threadIdx.x & 63;
    const int h = wid >> 11;           // / T_SEQ
    const int t = wid & (T_SEQ - 1);
    const int tok  = lane >> 1;
    const int half = lane & 1;

    int j = topk[(size_t)t * TOPK + tok];
    j = (j < 0 || j >= T_SEQ) ? 0 : j;   // defensive: wrong-not-crash

    const bf16* qp  = q  + (size_t)t * DIM + h * HD;
    const bf16* kp  = k  + (size_t)j * DIM + h * HD;
    const bf16* qrp = qr + (size_t)t * (NH * RD) + h * RD;
    const bf16* krp = kr + (size_t)j * RD;

    float s = 0.f;
    if (half == 0) {
#pragma unroll
        for (int c = 0; c < 12; ++c)            // q/k dims 0..95
            s = dot8(qp + c * 8, kp + c * 8, s);
    } else {
#pragma unroll
        for (int c = 12; c < 16; ++c)           // q/k dims 96..127
            s = dot8(qp + c * 8, kp + c * 8, s);
#pragma unroll
        for (int c = 0; c < 8; ++c)             // rope dims 0..63
            s = dot8(qrp + c * 8, krp + c * 8, s);
    }
    s += __shfl_xor(s, 1);
    const float scale = 0.0721687836487032f;    // 1/sqrt(192)
    s *= scale;

    float m = s;
#pragma unroll
    for (int off = 2; off < 64; off <<= 1) m = fmaxf(m, __shfl_xor(m, off));
    float p = __expf(s - m);
    float l = p;
#pragma unroll
    for (int off = 2; off < 64; off <<= 1) l += __shfl_xor(l, off);
    const float inv = 1.f / l;

    float o0 = 0.f, o1 = 0.f;
#pragma unroll
    for (int tk = 0; tk < TOPK; ++tk) {
        const float pw = __shfl(p, tk * 2) * inv;
        const int  jj  = __shfl(j, tk * 2);
        const bf16* vp = v + (size_t)jj * DIM + h * HD + lane * 2;
        float2 vf = __bfloat1622float2(*(const __hip_bfloat162*)vp);
        o0 += pw * vf.x;
        o1 += pw * vf.y;
    }
    __hip_bfloat162 res;
    res.x = __float2bfloat16(o0);
    res.y = __float2bfloat16(o1);
    *(__hip_bfloat162*)(o + (size_t)t * DIM + h * HD + lane * 2) = res;
}

// ---------------------------------------------------------------------------
extern "C" void kernel_launch(void* const* d_in, const int* in_sizes, int n_in,
                              void* d_out, int out_size, void* d_ws, size_t ws_size,
                              hipStream_t stream)
{
    // Reference dtypes: all float tensors fp32, topk int32, output fp32.
    const float* x    = (const float*)d_in[0];
    const float* Wqd  = (const float*)d_in[1];
    const float* Wqu  = (const float*)d_in[2];
    const float* Wqr  = (const float*)d_in[3];
    const float* Wkvd = (const float*)d_in[4];
    const float* Wku  = (const float*)d_in[5];
    const float* Wvu  = (const float*)d_in[6];
    const float* Wkr  = (const float*)d_in[7];
    const float* Wo   = (const float*)d_in[8];
    const int*   topk = (const int*)d_in[9];
    float* out = (float*)d_out;

    char* ws = (char*)d_ws;
    bf16* ql  = (bf16*)ws;  ws += (size_t)T_SEQ * LAT * 2;
    bf16* ckv = (bf16*)ws;  ws += (size_t)T_SEQ * LAT * 2;
    bf16* q   = (bf16*)ws;  ws += (size_t)T_SEQ * DIM * 2;
    bf16* qr  = (bf16*)ws;  ws += (size_t)T_SEQ * NH * RD * 2;
    bf16* k   = (bf16*)ws;  ws += (size_t)T_SEQ * DIM * 2;
    bf16* v   = (bf16*)ws;  ws += (size_t)T_SEQ * DIM * 2;
    bf16* kr  = (bf16*)ws;  ws += (size_t)T_SEQ * RD * 2;
    bf16* o   = (bf16*)ws;  ws += (size_t)T_SEQ * DIM * 2;
    // total ws use: 40.25 MB

    dim3 blk(256);

    // ql = x @ Wqd            (2048 x 512, K=2048)
    gemm64<float, float, bf16><<<dim3(LAT / 64, T_SEQ / 64), blk, 0, stream>>>(x, Wqd, ql, T_SEQ, LAT, DIM);
    // ckv = x @ Wkvd
    gemm64<float, float, bf16><<<dim3(LAT / 64, T_SEQ / 64), blk, 0, stream>>>(x, Wkvd, ckv, T_SEQ, LAT, DIM);
    // q = ql @ Wqu            (2048 x 2048, K=512)
    gemm64<bf16, float, bf16><<<dim3(DIM / 64, T_SEQ / 64), blk, 0, stream>>>(ql, Wqu, q, T_SEQ, DIM, LAT);
    // qr = ql @ Wqr           (2048 x 1024, K=512)
    gemm64<bf16, float, bf16><<<dim3((NH * RD) / 64, T_SEQ / 64), blk, 0, stream>>>(ql, Wqr, qr, T_SEQ, NH * RD, LAT);
    // k = ckv @ Wku
    gemm64<bf16, float, bf16><<<dim3(DIM / 64, T_SEQ / 64), blk, 0, stream>>>(ckv, Wku, k, T_SEQ, DIM, LAT);
    // v = ckv @ Wvu
    gemm64<bf16, float, bf16><<<dim3(DIM / 64, T_SEQ / 64), blk, 0, stream>>>(ckv, Wvu, v, T_SEQ, DIM, LAT);
    // kr = x @ Wkr            (2048 x 64, K=2048)
    gemm64<float, float, bf16><<<dim3(RD / 64, T_SEQ / 64), blk, 0, stream>>>(x, Wkr, kr, T_SEQ, RD, DIM);

    // RoPE in-place: qr per (t,h), kr per t
    rope_kernel<<<(T_SEQ * NH * 32 + 255) / 256, blk, 0, stream>>>(qr, NH);
    rope_kernel<<<(T_SEQ * 1 * 32 + 255) / 256, blk, 0, stream>>>(kr, 1);

    // sparse attention -> o (T, D) laid out (t, h*HD+d)
    attn_kernel<<<(NH * T_SEQ) / 4, blk, 0, stream>>>(q, qr, k, v, kr, topk, o);

    // out = o @ Wo            (2048 x 2048, K=2048), fp32 out
    gemm64<bf16, float, float><<<dim3(DIM / 64, T_SEQ / 64), blk, 0, stream>>>(o, Wo, out, T_SEQ, DIM, DIM);
}

// Round 3
// 396.797 us; speedup vs baseline: 1.4205x; 1.4205x over previous
//
#include <hip/hip_runtime.h>
#include <hip/hip_bf16.h>
#include <math.h>

typedef __hip_bfloat16 bf16;
typedef __attribute__((ext_vector_type(4))) float f32x4;
typedef __attribute__((ext_vector_type(8))) short s16x8;

#define T_SEQ 2048
#define DIM   2048
#define NH    16
#define HD    128
#define LAT   512
#define RD    64
#define TOPK  32
#define QLD   3072   // qq row stride: [q (2048) | qr (1024)]
#define KLD   4096   // kv row stride: [k (2048) | v (2048)]

typedef const __attribute__((address_space(1))) void* gas_ptr;
typedef __attribute__((address_space(3))) void* las_ptr;

// ---------------------------------------------------------------------------
// m97-style GEMM: C(M,N) = A(M,K) @ BT(N,K)^T. A, BT bf16 row-major with
// leading dims lda/ldb; C (ldc) bf16 or fp32. Tile = FR*32 square, BK=32,
// global_load_lds width=16 staging, 2-barrier K-loop, 16x16x32 MFMA.
// FR=4: 128x128 tile, wave does 64x64 (4x4 frags). FR=2: 64x64.
// LDS layout [row][k] packed 32 elems/row = 64B -> matches the wave-uniform
// base + lane*16 DMA rule exactly (16 rows per instruction).
// ---------------------------------------------------------------------------
template<int FR, typename TC>
__global__ __launch_bounds__(256)
void gemm_bt(const bf16* __restrict__ A, const bf16* __restrict__ BT,
             TC* __restrict__ C, int M, int N, int K,
             int lda, int ldb, int ldc)
{
    constexpr int TILE = FR * 32;
    __shared__ bf16 aL[TILE * 32];
    __shared__ bf16 bL[TILE * 32];

    const int tid  = threadIdx.x;
    const int wave = tid >> 6;
    const int lane = tid & 63;
    const int quad = lane >> 4;
    const int l16  = lane & 15;

    const int tile_m = blockIdx.y * TILE;
    const int tile_n = blockIdx.x * TILE;
    const int wrow = (wave >> 1) * (FR * 16);
    const int wcol = (wave & 1) * (FR * 16);

    const int lrow = lane >> 2;          // 0..15: row within 16-row chunk
    const int lke  = (lane & 3) * 8;     // element offset in k (8 bf16 = 16B)

    f32x4 acc[FR][FR] = {};

    for (int k0 = 0; k0 < K; k0 += 32) {
#pragma unroll
        for (int p = 0; p < FR / 2; ++p) {
            const int R = (wave * (FR / 2) + p) * 16;
            const bf16* src = A + (size_t)(tile_m + R + lrow) * lda + k0 + lke;
            __builtin_amdgcn_global_load_lds((gas_ptr)src, (las_ptr)(aL + R * 32), 16, 0, 0);
        }
#pragma unroll
        for (int p = 0; p < FR / 2; ++p) {
            const int R = (wave * (FR / 2) + p) * 16;
            const bf16* src = BT + (size_t)(tile_n + R + lrow) * ldb + k0 + lke;
            __builtin_amdgcn_global_load_lds((gas_ptr)src, (las_ptr)(bL + R * 32), 16, 0, 0);
        }
        __syncthreads();

        s16x8 af[FR], bfr[FR];
#pragma unroll
        for (int i = 0; i < FR; ++i)
            af[i] = *(const s16x8*)(&aL[(wrow + i * 16 + l16) * 32 + quad * 8]);
#pragma unroll
        for (int j = 0; j < FR; ++j)
            bfr[j] = *(const s16x8*)(&bL[(wcol + j * 16 + l16) * 32 + quad * 8]);

#pragma unroll
        for (int i = 0; i < FR; ++i)
#pragma unroll
            for (int j = 0; j < FR; ++j)
                acc[i][j] = __builtin_amdgcn_mfma_f32_16x16x32_bf16(
                    af[i], bfr[j], acc[i][j], 0, 0, 0);
        __syncthreads();
    }

    // D mapping: col = lane&15, row = (lane>>4)*4 + reg   [m89-verified]
#pragma unroll
    for (int i = 0; i < FR; ++i) {
#pragma unroll
        for (int j = 0; j < FR; ++j) {
            const int col = tile_n + wcol + j * 16 + l16;
#pragma unroll
            for (int r = 0; r < 4; ++r) {
                const int row = tile_m + wrow + i * 16 + quad * 4 + r;
                float vv = acc[i][j][r];
                if constexpr (__is_same(TC, float)) C[(size_t)row * ldc + col] = vv;
                else C[(size_t)row * ldc + col] = __float2bfloat16(vv);
            }
        }
    }
}

// ---------------------------------------------------------------------------
// Batched transpose+convert: src fp32 (R x C) -> dst bf16 (C x R).
// 32x32 LDS tiles, coalesced both sides.
// ---------------------------------------------------------------------------
struct TDesc { const float* src; bf16* dst; int R; int C; int tiles; int ctiles; };
struct TPack { TDesc d[4]; int n; };

__global__ __launch_bounds__(256)
void transpose_batch(TPack p)
{
    int b = blockIdx.x;
    int mi = 0;
    while (mi < p.n - 1 && b >= p.d[mi].tiles) { b -= p.d[mi].tiles; ++mi; }
    const TDesc d = p.d[mi];
    const int tr = b / d.ctiles, tc = b % d.ctiles;
    const int r0 = tr * 32, c0 = tc * 32;

    __shared__ float lds[32][33];
    const int tx = threadIdx.x & 31, ty = threadIdx.x >> 5;   // ty 0..7
#pragma unroll
    for (int i = 0; i < 4; ++i)
        lds[ty * 4 + i][tx] = d.src[(size_t)(r0 + ty * 4 + i) * d.C + c0 + tx];
    __syncthreads();
#pragma unroll
    for (int i = 0; i < 4; ++i)
        d.dst[(size_t)(c0 + ty * 4 + i) * d.R + r0 + tx] =
            __float2bfloat16(lds[tx][ty * 4 + i]);
}

// ---------------------------------------------------------------------------
// fp32 -> bf16 convert (x), 8 elems/thread
// ---------------------------------------------------------------------------
__global__ __launch_bounds__(256)
void convert_kernel(const float* __restrict__ src, bf16* __restrict__ dst, int n8)
{
    int i = blockIdx.x * blockDim.x + threadIdx.x;
    if (i >= n8) return;
    const float4 a = *(const float4*)(src + (size_t)i * 8);
    const float4 b = *(const float4*)(src + (size_t)i * 8 + 4);
    bf16 t[8];
    t[0] = __float2bfloat16(a.x); t[1] = __float2bfloat16(a.y);
    t[2] = __float2bfloat16(a.z); t[3] = __float2bfloat16(a.w);
    t[4] = __float2bfloat16(b.x); t[5] = __float2bfloat16(b.y);
    t[6] = __float2bfloat16(b.z); t[7] = __float2bfloat16(b.w);
    *(uint4*)(dst + (size_t)i * 8) = *(uint4*)t;
}

// ---------------------------------------------------------------------------
// In-place RoPE over rows t (stride ld), nvec vectors of 64 per row.
// ---------------------------------------------------------------------------
__global__ __launch_bounds__(256)
void rope_kernel(bf16* buf, int nvec, int ld)
{
    int idx = blockIdx.x * blockDim.x + threadIdx.x;
    int total = T_SEQ * nvec * 32;
    if (idx >= total) return;
    int i    = idx & 31;
    int rest = idx >> 5;
    int vec  = rest % nvec;
    int t    = rest / nvec;

    bf16* p = buf + (size_t)t * ld + vec * 64;
    float x0 = (float)p[i];
    float x1 = (float)p[i + 32];
    float ang = (float)t * powf(10000.f, -(float)i / 32.f);
    float c = cosf(ang), s = sinf(ang);
    p[i]      = __float2bfloat16(x0 * c - x1 * s);
    p[i + 32] = __float2bfloat16(x1 * c + x0 * s);
}

// ---------------------------------------------------------------------------
// Top-k sparse attention (round-2 structure, new strides).
// One wave per (h,t); 2 lanes/token for scores; wave softmax; PV coalesced.
// ---------------------------------------------------------------------------
__device__ __forceinline__ float dot8(const bf16* __restrict__ a,
                                      const bf16* __restrict__ b, float acc)
{
    union { uint4 u; __hip_bfloat162 h[4]; } ua, ub;
    ua.u = *(const uint4*)a;
    ub.u = *(const uint4*)b;
#pragma unroll
    for (int i = 0; i < 4; ++i) {
        float2 fa = __bfloat1622float2(ua.h[i]);
        float2 fb = __bfloat1622float2(ub.h[i]);
        acc += fa.x * fb.x + fa.y * fb.y;
    }
    return acc;
}

__global__ __launch_bounds__(256)
void attn_kernel(const bf16* __restrict__ qq, const bf16* __restrict__ kv,
                 const bf16* __restrict__ kr, const int* __restrict__ topk,
                 bf16* __restrict__ o)
{
    const int wid  = (blockIdx.x * blockDim.x + threadIdx.x) >> 6;
    const int lane = threadIdx.x & 63;
    const int h = wid >> 11;           // / T_SEQ
    const int t = wid & (T_SEQ - 1);
    const int tok  = lane >> 1;
    const int half = lane & 1;

    int j = topk[(size_t)t * TOPK + tok];
    j = (j < 0 || j >= T_SEQ) ? 0 : j;

    const bf16* qp  = qq + (size_t)t * QLD + h * HD;
    const bf16* qrp = qq + (size_t)t * QLD + DIM + h * RD;
    const bf16* kp  = kv + (size_t)j * KLD + h * HD;
    const bf16* krp = kr + (size_t)j * RD;

    float s = 0.f;
    if (half == 0) {
#pragma unroll
        for (int c = 0; c < 12; ++c)
            s = dot8(qp + c * 8, kp + c * 8, s);
    } else {
#pragma unroll
        for (int c = 12; c < 16; ++c)
            s = dot8(qp + c * 8, kp + c * 8, s);
#pragma unroll
        for (int c = 0; c < 8; ++c)
            s = dot8(qrp + c * 8, krp + c * 8, s);
    }
    s += __shfl_xor(s, 1);
    s *= 0.0721687836487032f;          // 1/sqrt(192)

    float m = s;
#pragma unroll
    for (int off = 2; off < 64; off <<= 1) m = fmaxf(m, __shfl_xor(m, off));
    float p = __expf(s - m);
    float l = p;
#pragma unroll
    for (int off = 2; off < 64; off <<= 1) l += __shfl_xor(l, off);
    const float inv = 1.f / l;

    float o0 = 0.f, o1 = 0.f;
#pragma unroll
    for (int tk = 0; tk < TOPK; ++tk) {
        const float pw = __shfl(p, tk * 2) * inv;
        const int  jj  = __shfl(j, tk * 2);
        const bf16* vp = kv + (size_t)jj * KLD + DIM + h * HD + lane * 2;
        float2 vf = __bfloat1622float2(*(const __hip_bfloat162*)vp);
        o0 += pw * vf.x;
        o1 += pw * vf.y;
    }
    __hip_bfloat162 res;
    res.x = __float2bfloat16(o0);
    res.y = __float2bfloat16(o1);
    *(__hip_bfloat162*)(o + (size_t)t * DIM + h * HD + lane * 2) = res;
}

// ---------------------------------------------------------------------------
extern "C" void kernel_launch(void* const* d_in, const int* in_sizes, int n_in,
                              void* d_out, int out_size, void* d_ws, size_t ws_size,
                              hipStream_t stream)
{
    const float* x    = (const float*)d_in[0];
    const float* Wqd  = (const float*)d_in[1];
    const float* Wqu  = (const float*)d_in[2];
    const float* Wqr  = (const float*)d_in[3];
    const float* Wkvd = (const float*)d_in[4];
    const float* Wku  = (const float*)d_in[5];
    const float* Wvu  = (const float*)d_in[6];
    const float* Wkr  = (const float*)d_in[7];
    const float* Wo   = (const float*)d_in[8];
    const int*   topk = (const int*)d_in[9];
    float* out = (float*)d_out;

    // Workspace pool, 40.25 MB peak (proven safe in round 2), phased aliasing:
    //  [ 0, 8M)   : WqT(0-3M)+WkvT(3-7M) during phases B2-C; o after attn
    //  [ 8,24M)   : WxT(8-12M)+WkrT(12-12.25M) phases A-B; kv in C-D; WoT in E
    //  [24,36M)   : xb (x as bf16) phases A-B; qq in C-D
    //  [36,40.25M): kr (36-36.25) + xw (36.25-40.25)
    const size_t MB = 1u << 20;
    char* ws = (char*)d_ws;
    bf16* WqT  = (bf16*)(ws + 0 * MB);            // 3072 x 512
    bf16* WkvT = (bf16*)(ws + 3 * MB);            // 4096 x 512
    bf16* o    = (bf16*)(ws + 0 * MB);            // 2048 x 2048
    bf16* WxT  = (bf16*)(ws + 8 * MB);            // 1024 x 2048
    bf16* WkrT = (bf16*)(ws + 12 * MB);           // 64 x 2048
    bf16* kv   = (bf16*)(ws + 8 * MB);            // 2048 x 4096
    bf16* WoT  = (bf16*)(ws + 8 * MB);            // 2048 x 2048
    bf16* xb   = (bf16*)(ws + 24 * MB);           // 2048 x 2048
    bf16* qq   = (bf16*)(ws + 24 * MB);           // 2048 x 3072
    bf16* kr   = (bf16*)(ws + 36 * MB);           // 2048 x 64
    bf16* xw   = (bf16*)(ws + 36 * MB + 256 * 1024); // 2048 x 1024

    dim3 blk(256);

    // ---- Phase A: convert x; transpose Wqd, Wkvd -> WxT stack; Wkr -> WkrT
    convert_kernel<<<(T_SEQ * DIM / 8 + 255) / 256, blk, 0, stream>>>(x, xb, T_SEQ * DIM / 8);
    {
        TPack p;
        p.d[0] = { Wqd,  WxT,                    DIM, LAT, (DIM/32)*(LAT/32), LAT/32 };
        p.d[1] = { Wkvd, WxT + (size_t)LAT*DIM,  DIM, LAT, (DIM/32)*(LAT/32), LAT/32 };
        p.d[2] = { Wkr,  WkrT,                   DIM, RD,  (DIM/32)*(RD/32),  RD/32  };
        p.n = 3;
        int tot = p.d[0].tiles + p.d[1].tiles + p.d[2].tiles;
        transpose_batch<<<tot, blk, 0, stream>>>(p);
    }

    // ---- Phase B: xw = xb @ WxT^T  (M=2048, N=1024, K=2048); kr GEMM
    gemm_bt<4, bf16><<<dim3(1024/128, T_SEQ/128), blk, 0, stream>>>(
        xb, WxT, xw, T_SEQ, 1024, DIM, DIM, DIM, 1024);
    gemm_bt<2, bf16><<<dim3(RD/64, T_SEQ/64), blk, 0, stream>>>(
        xb, WkrT, kr, T_SEQ, RD, DIM, DIM, DIM, RD);

    // ---- Phase B2: transpose Wqu,Wqr -> WqT stack; Wku,Wvu -> WkvT stack
    {
        TPack p;
        p.d[0] = { Wqu, WqT,                      LAT, DIM,  (LAT/32)*(DIM/32),  DIM/32 };
        p.d[1] = { Wqr, WqT + (size_t)DIM*LAT,    LAT, 1024, (LAT/32)*(1024/32), 1024/32 };
        p.d[2] = { Wku, WkvT,                     LAT, DIM,  (LAT/32)*(DIM/32),  DIM/32 };
        p.d[3] = { Wvu, WkvT + (size_t)DIM*LAT,   LAT, DIM,  (LAT/32)*(DIM/32),  DIM/32 };
        p.n = 4;
        int tot = p.d[0].tiles + p.d[1].tiles + p.d[2].tiles + p.d[3].tiles;
        transpose_batch<<<tot, blk, 0, stream>>>(p);
    }

    // ---- Phase C: qq = ql @ [Wqu|Wqr]  (N=3072, K=512);  kv = ckv @ [Wku|Wvu]
    gemm_bt<4, bf16><<<dim3(QLD/128, T_SEQ/128), blk, 0, stream>>>(
        xw, WqT, qq, T_SEQ, QLD, LAT, 1024, LAT, QLD);
    gemm_bt<4, bf16><<<dim3(KLD/128, T_SEQ/128), blk, 0, stream>>>(
        xw + LAT, WkvT, kv, T_SEQ, KLD, LAT, 1024, LAT, KLD);

    // ---- Phase D: RoPE (qr section of qq; kr), then sparse attention -> o
    rope_kernel<<<(T_SEQ * NH * 32 + 255) / 256, blk, 0, stream>>>(qq + DIM, NH, QLD);
    rope_kernel<<<(T_SEQ * 1 * 32 + 255) / 256, blk, 0, stream>>>(kr, 1, RD);
    attn_kernel<<<(NH * T_SEQ) / 4, blk, 0, stream>>>(qq, kv, kr, topk, o);

    // ---- Phase E: transpose Wo -> WoT (over dead kv); out = o @ Wo
    {
        TPack p;
        p.d[0] = { Wo, WoT, DIM, DIM, (DIM/32)*(DIM/32), DIM/32 };
        p.n = 1;
        transpose_batch<<<p.d[0].tiles, blk, 0, stream>>>(p);
    }
    gemm_bt<4, float><<<dim3(DIM/128, T_SEQ/128), blk, 0, stream>>>(
        o, WoT, out, T_SEQ, DIM, DIM, DIM, DIM, DIM);
}

// Round 4
// 373.420 us; speedup vs baseline: 1.5095x; 1.0626x over previous
//
#include <hip/hip_runtime.h>
#include <hip/hip_bf16.h>
#include <math.h>

typedef __hip_bfloat16 bf16;
typedef __attribute__((ext_vector_type(4))) float f32x4;
typedef __attribute__((ext_vector_type(2))) float f32x2;
typedef __attribute__((ext_vector_type(8))) short s16x8;

#define T_SEQ 2048
#define DIM   2048
#define NH    16
#define HD    128
#define LAT   512
#define RD    64
#define TOPK  32
#define QLD   3072   // qq row stride: [q (2048) | qr (1024)]
#define KLD   4096   // kv row stride: [k (2048) | v (2048)]

typedef const __attribute__((address_space(1))) void* gas_ptr;
typedef __attribute__((address_space(3))) void* las_ptr;

// ---------------------------------------------------------------------------
// m97-style GEMM: C(M,N) = A(M,K) @ BT(N,K)^T. A, BT bf16 row-major with
// leading dims lda/ldb; C (ldc) bf16 or fp32. Tile = FR*32 square, BK=32,
// global_load_lds width=16 staging, 2-barrier K-loop, 16x16x32 MFMA.
// ---------------------------------------------------------------------------
template<int FR, typename TC>
__global__ __launch_bounds__(256)
void gemm_bt(const bf16* __restrict__ A, const bf16* __restrict__ BT,
             TC* __restrict__ C, int M, int N, int K,
             int lda, int ldb, int ldc)
{
    constexpr int TILE = FR * 32;
    __shared__ bf16 aL[TILE * 32];
    __shared__ bf16 bL[TILE * 32];

    const int tid  = threadIdx.x;
    const int wave = tid >> 6;
    const int lane = tid & 63;
    const int quad = lane >> 4;
    const int l16  = lane & 15;

    const int tile_m = blockIdx.y * TILE;
    const int tile_n = blockIdx.x * TILE;
    const int wrow = (wave >> 1) * (FR * 16);
    const int wcol = (wave & 1) * (FR * 16);

    const int lrow = lane >> 2;
    const int lke  = (lane & 3) * 8;

    f32x4 acc[FR][FR] = {};

    for (int k0 = 0; k0 < K; k0 += 32) {
#pragma unroll
        for (int p = 0; p < FR / 2; ++p) {
            const int R = (wave * (FR / 2) + p) * 16;
            const bf16* src = A + (size_t)(tile_m + R + lrow) * lda + k0 + lke;
            __builtin_amdgcn_global_load_lds((gas_ptr)src, (las_ptr)(aL + R * 32), 16, 0, 0);
        }
#pragma unroll
        for (int p = 0; p < FR / 2; ++p) {
            const int R = (wave * (FR / 2) + p) * 16;
            const bf16* src = BT + (size_t)(tile_n + R + lrow) * ldb + k0 + lke;
            __builtin_amdgcn_global_load_lds((gas_ptr)src, (las_ptr)(bL + R * 32), 16, 0, 0);
        }
        __syncthreads();

        s16x8 af[FR], bfr[FR];
#pragma unroll
        for (int i = 0; i < FR; ++i)
            af[i] = *(const s16x8*)(&aL[(wrow + i * 16 + l16) * 32 + quad * 8]);
#pragma unroll
        for (int j = 0; j < FR; ++j)
            bfr[j] = *(const s16x8*)(&bL[(wcol + j * 16 + l16) * 32 + quad * 8]);

#pragma unroll
        for (int i = 0; i < FR; ++i)
#pragma unroll
            for (int j = 0; j < FR; ++j)
                acc[i][j] = __builtin_amdgcn_mfma_f32_16x16x32_bf16(
                    af[i], bfr[j], acc[i][j], 0, 0, 0);
        __syncthreads();
    }

    // D mapping: col = lane&15, row = (lane>>4)*4 + reg   [m89-verified]
#pragma unroll
    for (int i = 0; i < FR; ++i) {
#pragma unroll
        for (int j = 0; j < FR; ++j) {
            const int col = tile_n + wcol + j * 16 + l16;
#pragma unroll
            for (int r = 0; r < 4; ++r) {
                const int row = tile_m + wrow + i * 16 + quad * 4 + r;
                float vv = acc[i][j][r];
                if constexpr (__is_same(TC, float)) C[(size_t)row * ldc + col] = vv;
                else C[(size_t)row * ldc + col] = __float2bfloat16(vv);
            }
        }
    }
}

// ---------------------------------------------------------------------------
// Batched transpose+convert: src fp32 (R x C) -> dst bf16 (C x R).
// ---------------------------------------------------------------------------
struct TDesc { const float* src; bf16* dst; int R; int C; int tiles; int ctiles; };
struct TPack { TDesc d[4]; int n; };

__global__ __launch_bounds__(256)
void transpose_batch(TPack p)
{
    int b = blockIdx.x;
    int mi = 0;
    while (mi < p.n - 1 && b >= p.d[mi].tiles) { b -= p.d[mi].tiles; ++mi; }
    const TDesc d = p.d[mi];
    const int tr = b / d.ctiles, tc = b % d.ctiles;
    const int r0 = tr * 32, c0 = tc * 32;

    __shared__ float lds[32][33];
    const int tx = threadIdx.x & 31, ty = threadIdx.x >> 5;
#pragma unroll
    for (int i = 0; i < 4; ++i)
        lds[ty * 4 + i][tx] = d.src[(size_t)(r0 + ty * 4 + i) * d.C + c0 + tx];
    __syncthreads();
#pragma unroll
    for (int i = 0; i < 4; ++i)
        d.dst[(size_t)(c0 + ty * 4 + i) * d.R + r0 + tx] =
            __float2bfloat16(lds[tx][ty * 4 + i]);
}

// ---------------------------------------------------------------------------
// fp32 -> bf16 convert (x), 8 elems/thread
// ---------------------------------------------------------------------------
__global__ __launch_bounds__(256)
void convert_kernel(const float* __restrict__ src, bf16* __restrict__ dst, int n8)
{
    int i = blockIdx.x * blockDim.x + threadIdx.x;
    if (i >= n8) return;
    const float4 a = *(const float4*)(src + (size_t)i * 8);
    const float4 b = *(const float4*)(src + (size_t)i * 8 + 4);
    bf16 t[8];
    t[0] = __float2bfloat16(a.x); t[1] = __float2bfloat16(a.y);
    t[2] = __float2bfloat16(a.z); t[3] = __float2bfloat16(a.w);
    t[4] = __float2bfloat16(b.x); t[5] = __float2bfloat16(b.y);
    t[6] = __float2bfloat16(b.z); t[7] = __float2bfloat16(b.w);
    *(uint4*)(dst + (size_t)i * 8) = *(uint4*)t;
}

// ---------------------------------------------------------------------------
// Fused RoPE: qr section of qq (nvec=16 per row, ld=QLD) + kr (nvec=1, ld=RD)
// one dispatch. freqs: 10000^(-i/32), position = t.
// ---------------------------------------------------------------------------
__global__ __launch_bounds__(256)
void rope_all(bf16* qq, bf16* kr)
{
    int idx = blockIdx.x * blockDim.x + threadIdx.x;
    const int nq = T_SEQ * NH * 32;
    bf16* p;
    int i, t;
    if (idx < nq) {
        i = idx & 31;
        int rest = idx >> 5;
        int vec  = rest & (NH - 1);
        t = rest >> 4;
        p = qq + (size_t)t * QLD + DIM + vec * 64;
    } else {
        idx -= nq;
        if (idx >= T_SEQ * 32) return;
        i = idx & 31;
        t = idx >> 5;
        p = kr + (size_t)t * RD;
    }
    float x0 = (float)p[i];
    float x1 = (float)p[i + 32];
    float ang = (float)t * powf(10000.f, -(float)i / 32.f);
    float c = cosf(ang), s = sinf(ang);
    p[i]      = __float2bfloat16(x0 * c - x1 * s);
    p[i + 32] = __float2bfloat16(x1 * c + x0 * s);
}

// ---------------------------------------------------------------------------
// Top-k sparse attention, v2 (VALU-thinned).
// One wave per (h,t). Scores: 2 lanes/token, packed-f32 fma over 192 dims,
// pair-sum shfl_xor(1), wave softmax via xor strides 2..32.
// PV: p + row byte-offsets broadcast through LDS (ds_read_b128, not 64x
// ds_bpermute), deferred 1/l normalization, lane owns dims (2*lane, 2*lane+1).
// ---------------------------------------------------------------------------
__device__ __forceinline__ f32x2 bfp(unsigned u)
{
    f32x2 r;
    r.x = __builtin_bit_cast(float, u << 16);
    r.y = __builtin_bit_cast(float, u & 0xffff0000u);
    return r;
}

__device__ __forceinline__ f32x2 dot8_pk(const bf16* __restrict__ a,
                                         const bf16* __restrict__ b, f32x2 acc)
{
    uint4 ua = *(const uint4*)a;
    uint4 ub = *(const uint4*)b;
    acc = __builtin_elementwise_fma(bfp(ua.x), bfp(ub.x), acc);
    acc = __builtin_elementwise_fma(bfp(ua.y), bfp(ub.y), acc);
    acc = __builtin_elementwise_fma(bfp(ua.z), bfp(ub.z), acc);
    acc = __builtin_elementwise_fma(bfp(ua.w), bfp(ub.w), acc);
    return acc;
}

__global__ __launch_bounds__(256)
void attn_kernel(const bf16* __restrict__ qq, const bf16* __restrict__ kv,
                 const bf16* __restrict__ kr, const int* __restrict__ topk,
                 bf16* __restrict__ o)
{
    __shared__ float    pshare[4][32];
    __shared__ unsigned oshare[4][32];

    const int wv   = threadIdx.x >> 6;
    const int wid  = blockIdx.x * 4 + wv;
    const int lane = threadIdx.x & 63;
    const int h = wid >> 11;           // / T_SEQ
    const int t = wid & (T_SEQ - 1);
    const int tok  = lane >> 1;
    const int half = lane & 1;

    int j = topk[(size_t)t * TOPK + tok];
    j = (j < 0 || j >= T_SEQ) ? 0 : j;
    // byte offset of token row (both lanes of a pair write the same value)
    oshare[wv][tok] = (unsigned)j * (KLD * 2u);

    const bf16* qp  = qq + (size_t)t * QLD + h * HD;
    const bf16* qrp = qq + (size_t)t * QLD + DIM + h * RD;
    const bf16* kp  = kv + (size_t)j * KLD + h * HD;
    const bf16* krp = kr + (size_t)j * RD;

    f32x2 a2 = {0.f, 0.f};
    if (half == 0) {
#pragma unroll
        for (int c = 0; c < 12; ++c)            // q/k dims 0..95
            a2 = dot8_pk(qp + c * 8, kp + c * 8, a2);
    } else {
#pragma unroll
        for (int c = 12; c < 16; ++c)           // q/k dims 96..127
            a2 = dot8_pk(qp + c * 8, kp + c * 8, a2);
#pragma unroll
        for (int c = 0; c < 8; ++c)             // rope dims 0..63
            a2 = dot8_pk(qrp + c * 8, krp + c * 8, a2);
    }
    float s = a2.x + a2.y;
    s += __shfl_xor(s, 1);
    s *= 0.0721687836487032f;                   // 1/sqrt(192)

    float m = s;
#pragma unroll
    for (int off = 2; off < 64; off <<= 1) m = fmaxf(m, __shfl_xor(m, off));
    float p = __expf(s - m);
    float l = p;
#pragma unroll
    for (int off = 2; off < 64; off <<= 1) l += __shfl_xor(l, off);
    pshare[wv][tok] = p;                        // unnormalized; scale at end

    // broadcast p and offsets to all lanes via vector LDS reads
    f32x4 P[8];
    uint4 O[8];
#pragma unroll
    for (int r = 0; r < 8; ++r) {
        P[r] = *(const f32x4*)(&pshare[wv][r * 4]);
        O[r] = *(const uint4*)(&oshare[wv][r * 4]);
    }

    // PV: uniform SGPR base (kv + v-section + head slice); per-lane +lane*4B
    const char* vbase = (const char*)kv + (size_t)(DIM + h * HD) * 2;
    const unsigned lane4 = (unsigned)lane * 4u;
    f32x2 oa = {0.f, 0.f};
#pragma unroll
    for (int tk = 0; tk < TOPK; ++tk) {
        const unsigned off = ((const unsigned*)O)[tk] + lane4;
        const float    pw  = ((const float*)P)[tk];
        unsigned u = *(const unsigned*)(vbase + off);
        f32x2 pw2 = {pw, pw};
        oa = __builtin_elementwise_fma(bfp(u), pw2, oa);
    }
    const float inv = 1.f / l;
    __hip_bfloat162 res;
    res.x = __float2bfloat16(oa.x * inv);
    res.y = __float2bfloat16(oa.y * inv);
    *(__hip_bfloat162*)(o + (size_t)t * DIM + h * HD + lane * 2) = res;
}

// ---------------------------------------------------------------------------
extern "C" void kernel_launch(void* const* d_in, const int* in_sizes, int n_in,
                              void* d_out, int out_size, void* d_ws, size_t ws_size,
                              hipStream_t stream)
{
    const float* x    = (const float*)d_in[0];
    const float* Wqd  = (const float*)d_in[1];
    const float* Wqu  = (const float*)d_in[2];
    const float* Wqr  = (const float*)d_in[3];
    const float* Wkvd = (const float*)d_in[4];
    const float* Wku  = (const float*)d_in[5];
    const float* Wvu  = (const float*)d_in[6];
    const float* Wkr  = (const float*)d_in[7];
    const float* Wo   = (const float*)d_in[8];
    const int*   topk = (const int*)d_in[9];
    float* out = (float*)d_out;

    // Workspace pool, 40.25 MB peak, phased aliasing (see round-2 map).
    const size_t MB = 1u << 20;
    char* ws = (char*)d_ws;
    bf16* WqT  = (bf16*)(ws + 0 * MB);            // 3072 x 512
    bf16* WkvT = (bf16*)(ws + 3 * MB);            // 4096 x 512
    bf16* o    = (bf16*)(ws + 0 * MB);            // 2048 x 2048
    bf16* WxT  = (bf16*)(ws + 8 * MB);            // 1024 x 2048
    bf16* WkrT = (bf16*)(ws + 12 * MB);           // 64 x 2048
    bf16* kv   = (bf16*)(ws + 8 * MB);            // 2048 x 4096
    bf16* WoT  = (bf16*)(ws + 8 * MB);            // 2048 x 2048
    bf16* xb   = (bf16*)(ws + 24 * MB);           // 2048 x 2048
    bf16* qq   = (bf16*)(ws + 24 * MB);           // 2048 x 3072
    bf16* kr   = (bf16*)(ws + 36 * MB);           // 2048 x 64
    bf16* xw   = (bf16*)(ws + 36 * MB + 256 * 1024); // 2048 x 1024

    dim3 blk(256);

    // ---- Phase A: convert x; transpose Wqd, Wkvd, Wkr
    convert_kernel<<<(T_SEQ * DIM / 8 + 255) / 256, blk, 0, stream>>>(x, xb, T_SEQ * DIM / 8);
    {
        TPack p;
        p.d[0] = { Wqd,  WxT,                    DIM, LAT, (DIM/32)*(LAT/32), LAT/32 };
        p.d[1] = { Wkvd, WxT + (size_t)LAT*DIM,  DIM, LAT, (DIM/32)*(LAT/32), LAT/32 };
        p.d[2] = { Wkr,  WkrT,                   DIM, RD,  (DIM/32)*(RD/32),  RD/32  };
        p.n = 3;
        int tot = p.d[0].tiles + p.d[1].tiles + p.d[2].tiles;
        transpose_batch<<<tot, blk, 0, stream>>>(p);
    }

    // ---- Phase B: xw = xb @ WxT^T; kr = xb @ WkrT^T
    gemm_bt<4, bf16><<<dim3(1024/128, T_SEQ/128), blk, 0, stream>>>(
        xb, WxT, xw, T_SEQ, 1024, DIM, DIM, DIM, 1024);
    gemm_bt<2, bf16><<<dim3(RD/64, T_SEQ/64), blk, 0, stream>>>(
        xb, WkrT, kr, T_SEQ, RD, DIM, DIM, DIM, RD);

    // ---- Phase B2: transpose Wqu,Wqr,Wku,Wvu
    {
        TPack p;
        p.d[0] = { Wqu, WqT,                      LAT, DIM,  (LAT/32)*(DIM/32),  DIM/32 };
        p.d[1] = { Wqr, WqT + (size_t)DIM*LAT,    LAT, 1024, (LAT/32)*(1024/32), 1024/32 };
        p.d[2] = { Wku, WkvT,                     LAT, DIM,  (LAT/32)*(DIM/32),  DIM/32 };
        p.d[3] = { Wvu, WkvT + (size_t)DIM*LAT,   LAT, DIM,  (LAT/32)*(DIM/32),  DIM/32 };
        p.n = 4;
        int tot = p.d[0].tiles + p.d[1].tiles + p.d[2].tiles + p.d[3].tiles;
        transpose_batch<<<tot, blk, 0, stream>>>(p);
    }

    // ---- Phase C: qq = ql @ [Wqu|Wqr]; kv = ckv @ [Wku|Wvu]
    gemm_bt<4, bf16><<<dim3(QLD/128, T_SEQ/128), blk, 0, stream>>>(
        xw, WqT, qq, T_SEQ, QLD, LAT, 1024, LAT, QLD);
    gemm_bt<4, bf16><<<dim3(KLD/128, T_SEQ/128), blk, 0, stream>>>(
        xw + LAT, WkvT, kv, T_SEQ, KLD, LAT, 1024, LAT, KLD);

    // ---- Phase D: fused RoPE, then sparse attention -> o
    rope_all<<<(T_SEQ * (NH + 1) * 32 + 255) / 256, blk, 0, stream>>>(qq, kr);
    attn_kernel<<<(NH * T_SEQ) / 4, blk, 0, stream>>>(qq, kv, kr, topk, o);

    // ---- Phase E: transpose Wo; out = o @ WoT^T (fp32 out)
    {
        TPack p;
        p.d[0] = { Wo, WoT, DIM, DIM, (DIM/32)*(DIM/32), DIM/32 };
        p.n = 1;
        transpose_batch<<<p.d[0].tiles, blk, 0, stream>>>(p);
    }
    gemm_bt<4, float><<<dim3(DIM/128, T_SEQ/128), blk, 0, stream>>>(
        o, WoT, out, T_SEQ, DIM, DIM, DIM, DIM, DIM);
}

// Round 5
// 337.626 us; speedup vs baseline: 1.6695x; 1.1060x over previous
//
#include <hip/hip_runtime.h>
#include <hip/hip_bf16.h>
#include <math.h>

typedef __hip_bfloat16 bf16;
typedef __attribute__((ext_vector_type(4))) float f32x4;
typedef __attribute__((ext_vector_type(8))) short s16x8;

#define T_SEQ 2048
#define DIM   2048
#define NH    16
#define LAT   512
#define RD    64
#define TOPK  32

typedef const __attribute__((address_space(1))) void* gas_ptr;
typedef __attribute__((address_space(3))) void* las_ptr;

// ---------------------------------------------------------------------------
// m97-style GEMM: C = A(M,K) @ BT(N,K)^T, bf16 in, bf16/fp32 out, z-batched.
// Tile FR*32 square, BK=32, global_load_lds width-16 staging, 16x16x32 MFMA.
// Grid: (N/TILE, M/TILE, nz); aZ/bZ/cZ element strides per z.
// ---------------------------------------------------------------------------
template<int FR, typename TC>
__global__ __launch_bounds__(256)
void gemm_bt(const bf16* __restrict__ A0, const bf16* __restrict__ BT0,
             TC* __restrict__ C0, int K, int lda, int ldb, int ldc,
             size_t aZ, size_t bZ, size_t cZ)
{
    constexpr int TILE = FR * 32;
    __shared__ bf16 aL[TILE * 32];
    __shared__ bf16 bL[TILE * 32];

    const bf16* A  = A0  + (size_t)blockIdx.z * aZ;
    const bf16* BT = BT0 + (size_t)blockIdx.z * bZ;
    TC*         C  = C0  + (size_t)blockIdx.z * cZ;

    const int tid  = threadIdx.x;
    const int wave = tid >> 6;
    const int lane = tid & 63;
    const int quad = lane >> 4;
    const int l16  = lane & 15;

    const int tile_m = blockIdx.y * TILE;
    const int tile_n = blockIdx.x * TILE;
    const int wrow = (wave >> 1) * (FR * 16);
    const int wcol = (wave & 1) * (FR * 16);

    const int lrow = lane >> 2;
    const int lke  = (lane & 3) * 8;

    f32x4 acc[FR][FR] = {};

    for (int k0 = 0; k0 < K; k0 += 32) {
#pragma unroll
        for (int p = 0; p < FR / 2; ++p) {
            const int R = (wave * (FR / 2) + p) * 16;
            const bf16* src = A + (size_t)(tile_m + R + lrow) * lda + k0 + lke;
            __builtin_amdgcn_global_load_lds((gas_ptr)src, (las_ptr)(aL + R * 32), 16, 0, 0);
        }
#pragma unroll
        for (int p = 0; p < FR / 2; ++p) {
            const int R = (wave * (FR / 2) + p) * 16;
            const bf16* src = BT + (size_t)(tile_n + R + lrow) * ldb + k0 + lke;
            __builtin_amdgcn_global_load_lds((gas_ptr)src, (las_ptr)(bL + R * 32), 16, 0, 0);
        }
        __syncthreads();

        s16x8 af[FR], bfr[FR];
#pragma unroll
        for (int i = 0; i < FR; ++i)
            af[i] = *(const s16x8*)(&aL[(wrow + i * 16 + l16) * 32 + quad * 8]);
#pragma unroll
        for (int j = 0; j < FR; ++j)
            bfr[j] = *(const s16x8*)(&bL[(wcol + j * 16 + l16) * 32 + quad * 8]);

#pragma unroll
        for (int i = 0; i < FR; ++i)
#pragma unroll
            for (int j = 0; j < FR; ++j)
                acc[i][j] = __builtin_amdgcn_mfma_f32_16x16x32_bf16(
                    af[i], bfr[j], acc[i][j], 0, 0, 0);
        __syncthreads();
    }

    // D mapping: col = lane&15, row = (lane>>4)*4 + reg   [m89-verified]
#pragma unroll
    for (int i = 0; i < FR; ++i) {
#pragma unroll
        for (int j = 0; j < FR; ++j) {
            const int col = tile_n + wcol + j * 16 + l16;
#pragma unroll
            for (int r = 0; r < 4; ++r) {
                const int row = tile_m + wrow + i * 16 + quad * 4 + r;
                float vv = acc[i][j][r];
                if constexpr (__is_same(TC, float)) C[(size_t)row * ldc + col] = vv;
                else C[(size_t)row * ldc + col] = __float2bfloat16(vv);
            }
        }
    }
}

// ---------------------------------------------------------------------------
// Batched transpose+convert: fp32 (R x C) -> bf16 (C x R), 32x32 LDS tiles.
// ---------------------------------------------------------------------------
struct TDesc { const float* src; bf16* dst; int R; int C; int tiles; int ctiles; };
struct TPack { TDesc d[5]; int n; };

__global__ __launch_bounds__(256)
void transpose_batch(TPack p)
{
    int b = blockIdx.x;
    int mi = 0;
    while (mi < p.n - 1 && b >= p.d[mi].tiles) { b -= p.d[mi].tiles; ++mi; }
    const TDesc d = p.d[mi];
    const int tr = b / d.ctiles, tc = b % d.ctiles;
    const int r0 = tr * 32, c0 = tc * 32;

    __shared__ float lds[32][33];
    const int tx = threadIdx.x & 31, ty = threadIdx.x >> 5;
#pragma unroll
    for (int i = 0; i < 4; ++i)
        lds[ty * 4 + i][tx] = d.src[(size_t)(r0 + ty * 4 + i) * d.C + c0 + tx];
    __syncthreads();
#pragma unroll
    for (int i = 0; i < 4; ++i)
        d.dst[(size_t)(c0 + ty * 4 + i) * d.R + r0 + tx] =
            __float2bfloat16(lds[tx][ty * 4 + i]);
}

// ---------------------------------------------------------------------------
// Batched fp32 -> bf16 convert (no transpose), 8 elems/thread, 3 segments.
// ---------------------------------------------------------------------------
__global__ __launch_bounds__(256)
void convert3(const float* s0, bf16* d0, int n0,
              const float* s1, bf16* d1, int n1,
              const float* s2, bf16* d2, int n2)
{
    int i = blockIdx.x * blockDim.x + threadIdx.x;   // in 8-elem units
    const float* s; bf16* d;
    if (i < n0) { s = s0; d = d0; }
    else if (i < n0 + n1) { i -= n0; s = s1; d = d1; }
    else if (i < n0 + n1 + n2) { i -= n0 + n1; s = s2; d = d2; }
    else return;
    const float4 a = *(const float4*)(s + (size_t)i * 8);
    const float4 b = *(const float4*)(s + (size_t)i * 8 + 4);
    bf16 t[8];
    t[0] = __float2bfloat16(a.x); t[1] = __float2bfloat16(a.y);
    t[2] = __float2bfloat16(a.z); t[3] = __float2bfloat16(a.w);
    t[4] = __float2bfloat16(b.x); t[5] = __float2bfloat16(b.y);
    t[6] = __float2bfloat16(b.z); t[7] = __float2bfloat16(b.w);
    *(uint4*)(d + (size_t)i * 8) = *(uint4*)t;
}

// ---------------------------------------------------------------------------
// RoPE in-place: rows of `rows`, nvec 64-wide vectors per row (ld stride).
// Position = t0 + row. freqs 10000^(-i/32).
// ---------------------------------------------------------------------------
__global__ __launch_bounds__(256)
void rope_vec(bf16* buf, int nvec, int ld, int t0, int rows)
{
    int idx = blockIdx.x * blockDim.x + threadIdx.x;
    if (idx >= rows * nvec * 32) return;
    int i    = idx & 31;
    int rest = idx >> 5;
    int vec  = rest % nvec;
    int t    = rest / nvec;

    bf16* p = buf + (size_t)t * ld + vec * 64;
    float x0 = (float)p[i];
    float x1 = (float)p[i + 32];
    float ang = (float)(t0 + t) * powf(10000.f, -(float)i / 32.f);
    float c = cosf(ang), s = sinf(ang);
    p[i]      = __float2bfloat16(x0 * c - x1 * s);
    p[i + 32] = __float2bfloat16(x1 * c + x0 * s);
}

// ---------------------------------------------------------------------------
// MLA-absorbed sparse attention. One block (4 waves) per query t.
// Stages 32 ckv rows (1KB each) + kr + q~ row + qr row into LDS; computes
// S(16 heads x 32 tokens) via MFMA (A = q~ heads, B = ckv tokens), C-layout
// softmax (row=head), P -> A-frag via per-wave LDS round-trip, then
// U(16x512) = P @ CkvSel via MFMA (each wave owns 128 dims). LDS strides
// padded (520/72/40) to kill power-of-2 bank conflicts on b128 reads.
// ---------------------------------------------------------------------------
__global__ __launch_bounds__(256)
void attn_mla(const bf16* __restrict__ qt,   // [rows][8192] chunk
              const bf16* __restrict__ qr,   // [rows][1024] chunk (rope'd)
              const bf16* __restrict__ xw,   // [2048][1024], ckv = cols 512..1023
              const bf16* __restrict__ kr,   // [2048][64] (rope'd)
              const int*  __restrict__ topk, // [2048][32]
              bf16* __restrict__ U,          // [rows][8192]
              int t0)
{
    __shared__ short ckv_s[32 * 520];
    __shared__ short qt_s[16 * 520];
    __shared__ short kr_s[32 * 72];
    __shared__ short qr_s[16 * 72];
    __shared__ short P_s[4][16 * 40];
    __shared__ int   idx_s[32];

    const int tl   = blockIdx.x;
    const int tg   = t0 + tl;
    const int tid  = threadIdx.x;
    const int wv   = tid >> 6;
    const int lane = tid & 63;
    const int quad = lane >> 4;
    const int l16  = lane & 15;

    if (tid < 32) {
        int j = topk[(size_t)tg * TOPK + tid];
        idx_s[tid] = (j < 0 || j >= T_SEQ) ? 0 : j;
    }
    __syncthreads();

    // --- stage ckv rows: 8 per wave, one global_load_lds (1KB) per row
#pragma unroll
    for (int i = 0; i < 8; ++i) {
        const int row = wv * 8 + i;
        const int j = idx_s[row];
        __builtin_amdgcn_global_load_lds(
            (gas_ptr)(xw + (size_t)j * 1024 + 512 + lane * 8),
            (las_ptr)(ckv_s + row * 520), 16, 0, 0);
    }
    // --- stage q~ row: 4 segments (512 elems) per wave
#pragma unroll
    for (int i = 0; i < 4; ++i) {
        const int seg = wv * 4 + i;
        __builtin_amdgcn_global_load_lds(
            (gas_ptr)(qt + (size_t)tl * 8192 + seg * 512 + lane * 8),
            (las_ptr)(qt_s + seg * 520), 16, 0, 0);
    }
    // --- stage kr rows (plain load + ds_write; rows padded to 72)
    {
        const int row = tid >> 3, seg = tid & 7;
        const int j = idx_s[row];
        *(uint4*)(kr_s + row * 72 + seg * 8) =
            *(const uint4*)(kr + (size_t)j * RD + seg * 8);
    }
    // --- stage qr row (16 heads x 64)
    if (tid < 128) {
        const int head = tid >> 3, seg = tid & 7;
        *(uint4*)(qr_s + head * 72 + seg * 8) =
            *(const uint4*)(qr + (size_t)tl * 1024 + head * 64 + seg * 8);
    }
    __syncthreads();

    // --- scores: S[head][token], redundantly per wave (cheap, all-LDS)
    f32x4 sc[2] = {};
#pragma unroll
    for (int ks = 0; ks < 16; ++ks) {
        s16x8 a  = *(const s16x8*)(qt_s + l16 * 520 + ks * 32 + quad * 8);
        s16x8 b0 = *(const s16x8*)(ckv_s + l16 * 520 + ks * 32 + quad * 8);
        s16x8 b1 = *(const s16x8*)(ckv_s + (16 + l16) * 520 + ks * 32 + quad * 8);
        sc[0] = __builtin_amdgcn_mfma_f32_16x16x32_bf16(a, b0, sc[0], 0, 0, 0);
        sc[1] = __builtin_amdgcn_mfma_f32_16x16x32_bf16(a, b1, sc[1], 0, 0, 0);
    }
#pragma unroll
    for (int ks = 0; ks < 2; ++ks) {
        s16x8 a  = *(const s16x8*)(qr_s + l16 * 72 + ks * 32 + quad * 8);
        s16x8 b0 = *(const s16x8*)(kr_s + l16 * 72 + ks * 32 + quad * 8);
        s16x8 b1 = *(const s16x8*)(kr_s + (16 + l16) * 72 + ks * 32 + quad * 8);
        sc[0] = __builtin_amdgcn_mfma_f32_16x16x32_bf16(a, b0, sc[0], 0, 0, 0);
        sc[1] = __builtin_amdgcn_mfma_f32_16x16x32_bf16(a, b1, sc[1], 0, 0, 0);
    }

    // --- softmax over 32 tokens per head; C row = head = quad*4+r
    const float scale = 0.0721687836487032f;   // 1/sqrt(192)
    float inv[4];
    short* pw = P_s[wv];
#pragma unroll
    for (int r = 0; r < 4; ++r) {
        float s0 = sc[0][r] * scale, s1 = sc[1][r] * scale;
        float mx = fmaxf(s0, s1);
#pragma unroll
        for (int off = 1; off < 16; off <<= 1) mx = fmaxf(mx, __shfl_xor(mx, off));
        float p0 = __expf(s0 - mx), p1 = __expf(s1 - mx);
        float l = p0 + p1;
#pragma unroll
        for (int off = 1; off < 16; off <<= 1) l += __shfl_xor(l, off);
        inv[r] = 1.f / l;
        pw[(quad * 4 + r) * 40 + l16]      = __builtin_bit_cast(short, __float2bfloat16(p0));
        pw[(quad * 4 + r) * 40 + 16 + l16] = __builtin_bit_cast(short, __float2bfloat16(p1));
    }

    // --- PV: U = P(16x32) @ CkvSel(32x512); wave owns dims [wv*128, +128)
    s16x8 ap = *(const s16x8*)(pw + l16 * 40 + quad * 8);
#pragma unroll
    for (int tt = 0; tt < 8; ++tt) {
        const int n0 = wv * 128 + tt * 16;
        s16x8 b;
#pragma unroll
        for (int j = 0; j < 8; ++j)
            b[j] = ckv_s[(quad * 8 + j) * 520 + n0 + l16];
        f32x4 u = {};
        u = __builtin_amdgcn_mfma_f32_16x16x32_bf16(ap, b, u, 0, 0, 0);
#pragma unroll
        for (int r = 0; r < 4; ++r)
            U[(size_t)tl * 8192 + (quad * 4 + r) * 512 + n0 + l16] =
                __float2bfloat16(u[r] * inv[r]);
    }
}

// ---------------------------------------------------------------------------
extern "C" void kernel_launch(void* const* d_in, const int* in_sizes, int n_in,
                              void* d_out, int out_size, void* d_ws, size_t ws_size,
                              hipStream_t stream)
{
    const float* x    = (const float*)d_in[0];
    const float* Wqd  = (const float*)d_in[1];
    const float* Wqu  = (const float*)d_in[2];
    const float* Wqr  = (const float*)d_in[3];
    const float* Wkvd = (const float*)d_in[4];
    const float* Wku  = (const float*)d_in[5];
    const float* Wvu  = (const float*)d_in[6];
    const float* Wkr  = (const float*)d_in[7];
    const float* Wo   = (const float*)d_in[8];
    const int*   topk = (const int*)d_in[9];
    float* out = (float*)d_out;

    const size_t KB = 1024;
    char* ws = (char*)d_ws;
    const bool flat = ws_size >= (size_t)128000 * KB;
    const int  TCH  = flat ? 2048 : 512;      // t-chunk rows
    const int  NCH  = T_SEQ / TCH;

    // Offsets in KB. Chunked layout fits in 40.25 MB (proven-safe) via
    // phase aliasing; flat layout (~115.5 MB) has no aliasing.
    size_t oXB, oWxT, oWkrT, oWqub, oWkub, oWqrT, oWvuT, oWcombT, oXW, oKR,
           oQR, oO, oWoT, oQT, oU;
    if (flat) {
        oXB = 0;        oWxT = 8192;   oWkrT = 12288; oWqub = 12544;
        oWkub = 14592;  oWqrT = 16640; oWvuT = 17664; oWcombT = 19712;
        oXW = 27904;    oKR = 32000;   oQR = 32256;   oO = 36352;
        oWoT = 44544;   oQT = 52736;   oU = 85504;
    } else {
        oXB = 0;        oWcombT = 0;   oWoT = 0;       // phase-aliased [0,8M)
        oWvuT = 8192;   oQR = 10240;   oKR = 11264;   oXW = 11520;
        oO = 15616;     oWxT = 15616;  oWkrT = 19712; // WxT/WkrT die pre-o
        oQT = 23808;    oWqub = 23808; oWkub = 25856; // Wqub/Wkub die pre-qt
        oU = 32000;     oWqrT = 40192;
    }
    bf16* xb     = (bf16*)(ws + oXB * KB);
    bf16* WxT    = (bf16*)(ws + oWxT * KB);
    bf16* WkrT   = (bf16*)(ws + oWkrT * KB);
    bf16* Wqub   = (bf16*)(ws + oWqub * KB);
    bf16* Wkub   = (bf16*)(ws + oWkub * KB);
    bf16* WqrT   = (bf16*)(ws + oWqrT * KB);
    bf16* WvuT   = (bf16*)(ws + oWvuT * KB);
    bf16* WcombT = (bf16*)(ws + oWcombT * KB);
    bf16* xw     = (bf16*)(ws + oXW * KB);
    bf16* kr     = (bf16*)(ws + oKR * KB);
    bf16* qrC    = (bf16*)(ws + oQR * KB);
    bf16* o      = (bf16*)(ws + oO * KB);
    bf16* WoT    = (bf16*)(ws + oWoT * KB);
    bf16* qtC    = (bf16*)(ws + oQT * KB);
    bf16* uC     = (bf16*)(ws + oU * KB);

    dim3 blk(256);

    // Phase A: converts (x, Wqu, Wku) + transposes (Wqd,Wkvd,Wkr,Wqr,Wvu)
    {
        int n0 = T_SEQ * DIM / 8, n1 = LAT * DIM / 8, n2 = LAT * DIM / 8;
        convert3<<<(n0 + n1 + n2 + 255) / 256, blk, 0, stream>>>(
            x, xb, n0, Wqu, Wqub, n1, Wku, Wkub, n2);
        TPack p;
        p.d[0] = { Wqd,  WxT,                   DIM, LAT,  (DIM/32)*(LAT/32),  LAT/32 };
        p.d[1] = { Wkvd, WxT + (size_t)LAT*DIM, DIM, LAT,  (DIM/32)*(LAT/32),  LAT/32 };
        p.d[2] = { Wkr,  WkrT,                  DIM, RD,   (DIM/32)*(RD/32),   RD/32  };
        p.d[3] = { Wqr,  WqrT,                  LAT, 1024, (LAT/32)*(1024/32), 1024/32 };
        p.d[4] = { Wvu,  WvuT,                  LAT, DIM,  (LAT/32)*(DIM/32),  DIM/32 };
        p.n = 5;
        int tot = p.d[0].tiles + p.d[1].tiles + p.d[2].tiles + p.d[3].tiles + p.d[4].tiles;
        transpose_batch<<<tot, blk, 0, stream>>>(p);
    }

    // Phase B: xw = xb @ WxT^T -> [ql | ckv]; kr = xb @ WkrT^T
    gemm_bt<4, bf16><<<dim3(1024/128, T_SEQ/128, 1), blk, 0, stream>>>(
        xb, WxT, xw, DIM, DIM, DIM, 1024, 0, 0, 0);
    gemm_bt<2, bf16><<<dim3(RD/64, T_SEQ/64, 1), blk, 0, stream>>>(
        xb, WkrT, kr, DIM, DIM, DIM, RD, 0, 0, 0);

    // Phase C: WcombT_h = Wku_h @ Wqu_h^T  (z=16 heads; xb region now dead)
    gemm_bt<2, bf16><<<dim3(LAT/64, LAT/64, NH), blk, 0, stream>>>(
        Wkub, Wqub, WcombT, 128, DIM, DIM, LAT, 128, 128, (size_t)LAT*LAT);
    rope_vec<<<(T_SEQ * 32 + 255) / 256, blk, 0, stream>>>(kr, 1, RD, 0, T_SEQ);

    // Phase D: per t-chunk: qr GEMM + rope, q~ GEMM, attention, U-projection
    for (int c = 0; c < NCH; ++c) {
        const int t0 = c * TCH;
        bf16* qt = flat ? qtC + (size_t)t0 * 8192 : qtC;
        bf16* qr = flat ? qrC + (size_t)t0 * 1024 : qrC;
        bf16* U  = flat ? uC  + (size_t)t0 * 8192 : uC;

        gemm_bt<2, bf16><<<dim3(1024/64, TCH/64, 1), blk, 0, stream>>>(
            xw + (size_t)t0 * 1024, WqrT, qr, LAT, 1024, LAT, 1024, 0, 0, 0);
        rope_vec<<<(TCH * NH * 32 + 255) / 256, blk, 0, stream>>>(qr, NH, 1024, t0, TCH);
        gemm_bt<4, bf16><<<dim3(8192/128, TCH/128, 1), blk, 0, stream>>>(
            xw + (size_t)t0 * 1024, WcombT, qt, LAT, 1024, LAT, 8192, 0, 0, 0);
        attn_mla<<<TCH, blk, 0, stream>>>(qt, qr, xw, kr, topk, U, t0);
        gemm_bt<2, bf16><<<dim3(128/64, TCH/64, NH), blk, 0, stream>>>(
            U, WvuT, o + (size_t)t0 * DIM, LAT, 8192, LAT, DIM,
            512, (size_t)128 * LAT, 128);
    }

    // Phase E: transpose Wo (WcombT region dead); out = o @ WoT^T (fp32)
    {
        TPack p;
        p.d[0] = { Wo, WoT, DIM, DIM, (DIM/32)*(DIM/32), DIM/32 };
        p.n = 1;
        transpose_batch<<<p.d[0].tiles, blk, 0, stream>>>(p);
    }
    gemm_bt<4, float><<<dim3(DIM/128, T_SEQ/128, 1), blk, 0, stream>>>(
        o, WoT, out, DIM, DIM, DIM, DIM, 0, 0, 0);
}

// Round 6
// 292.314 us; speedup vs baseline: 1.9283x; 1.1550x over previous
//
#include <hip/hip_runtime.h>
#include <hip/hip_bf16.h>
#include <math.h>

typedef __hip_bfloat16 bf16;
typedef __attribute__((ext_vector_type(4))) float f32x4;
typedef __attribute__((ext_vector_type(8))) short s16x8;

#define T_SEQ 2048
#define DIM   2048
#define NH    16
#define LAT   512
#define RD    64
#define TOPK  32

typedef const __attribute__((address_space(1))) void* gas_ptr;
typedef __attribute__((address_space(3))) void* las_ptr;

// ---------------------------------------------------------------------------
// Grouped m97-style GEMM: up to 4 independent C = A(M,K) @ BT(N,K)^T jobs in
// one launch (pooled blocks -> co-resident waves overlap barrier drains).
// FR=4: 128x128 tile, 256 threads, BK=32, global_load_lds width-16 staging.
// flags: 1 = RoPE epilogue (rotate col pairs (c, c+32), position = t0+row),
//        2 = column guard (col < N; for N < 128 jobs, OOB B reads are
//            garbage-but-safe and masked at store).
// ---------------------------------------------------------------------------
struct GGroup {
    const bf16* A; const bf16* BT; bf16* C;
    int K, lda, ldb, ldc;
    int tx, ty, nz;          // tiles in n, m, z
    long aZ, bZ, cZ;         // element strides per z
    int tiles;               // tx*ty*nz
    int flags, N, t0;
};
struct GPack { GGroup g[4]; int n; };

__global__ __launch_bounds__(256)
void gemm_group(GPack gp)
{
    int b = blockIdx.x;
    int gi = 0;
    while (gi < gp.n - 1 && b >= gp.g[gi].tiles) { b -= gp.g[gi].tiles; ++gi; }
    const GGroup g = gp.g[gi];

    const int per_z = g.tx * g.ty;
    const int z   = b / per_z;
    const int rem = b - z * per_z;
    const int bx  = rem % g.tx;
    const int by  = rem / g.tx;

    const bf16* A  = g.A  + (size_t)z * g.aZ;
    const bf16* BT = g.BT + (size_t)z * g.bZ;
    bf16*       C  = g.C  + (size_t)z * g.cZ;

    __shared__ bf16 aL[128 * 32];
    __shared__ bf16 bL[128 * 32];

    const int tid  = threadIdx.x;
    const int wave = tid >> 6;
    const int lane = tid & 63;
    const int quad = lane >> 4;
    const int l16  = lane & 15;

    const int tile_m = by * 128;
    const int tile_n = bx * 128;
    const int wrow = (wave >> 1) * 64;
    const int wcol = (wave & 1) * 64;

    const int lrow = lane >> 2;
    const int lke  = (lane & 3) * 8;

    f32x4 acc[4][4] = {};

    for (int k0 = 0; k0 < g.K; k0 += 32) {
#pragma unroll
        for (int p = 0; p < 2; ++p) {
            const int R = (wave * 2 + p) * 16;
            const bf16* src = A + (size_t)(tile_m + R + lrow) * g.lda + k0 + lke;
            __builtin_amdgcn_global_load_lds((gas_ptr)src, (las_ptr)(aL + R * 32), 16, 0, 0);
        }
#pragma unroll
        for (int p = 0; p < 2; ++p) {
            const int R = (wave * 2 + p) * 16;
            const bf16* src = BT + (size_t)(tile_n + R + lrow) * g.ldb + k0 + lke;
            __builtin_amdgcn_global_load_lds((gas_ptr)src, (las_ptr)(bL + R * 32), 16, 0, 0);
        }
        __syncthreads();

        s16x8 af[4], bfr[4];
#pragma unroll
        for (int i = 0; i < 4; ++i)
            af[i] = *(const s16x8*)(&aL[(wrow + i * 16 + l16) * 32 + quad * 8]);
#pragma unroll
        for (int j = 0; j < 4; ++j)
            bfr[j] = *(const s16x8*)(&bL[(wcol + j * 16 + l16) * 32 + quad * 8]);

#pragma unroll
        for (int i = 0; i < 4; ++i)
#pragma unroll
            for (int j = 0; j < 4; ++j)
                acc[i][j] = __builtin_amdgcn_mfma_f32_16x16x32_bf16(
                    af[i], bfr[j], acc[i][j], 0, 0, 0);
        __syncthreads();
    }

    // D mapping: col = lane&15, row = (lane>>4)*4 + reg   [m89-verified]
    if (g.flags & 1) {
        // RoPE epilogue: tile_n and wcol are multiples of 64 for every rope
        // job, so pair (colL, colL+32) = (acc[i][jp], acc[i][jp+2]).
#pragma unroll
        for (int jp = 0; jp < 2; ++jp) {
            const int colL = tile_n + wcol + jp * 16 + l16;
            if ((g.flags & 2) && colL >= g.N) continue;
            const float fr = powf(10000.f, -(float)(jp * 16 + l16) / 32.f);
#pragma unroll
            for (int i = 0; i < 4; ++i) {
#pragma unroll
                for (int r = 0; r < 4; ++r) {
                    const int row = tile_m + wrow + i * 16 + quad * 4 + r;
                    float sv, cv;
                    sincosf((float)(g.t0 + row) * fr, &sv, &cv);
                    const float x0 = acc[i][jp][r];
                    const float x1 = acc[i][jp + 2][r];
                    C[(size_t)row * g.ldc + colL]      = __float2bfloat16(x0 * cv - x1 * sv);
                    C[(size_t)row * g.ldc + colL + 32] = __float2bfloat16(x1 * cv + x0 * sv);
                }
            }
        }
    } else {
#pragma unroll
        for (int j = 0; j < 4; ++j) {
            const int col = tile_n + wcol + j * 16 + l16;
            if ((g.flags & 2) && col >= g.N) continue;
#pragma unroll
            for (int i = 0; i < 4; ++i)
#pragma unroll
                for (int r = 0; r < 4; ++r) {
                    const int row = tile_m + wrow + i * 16 + quad * 4 + r;
                    C[(size_t)row * g.ldc + col] = __float2bfloat16(acc[i][j][r]);
                }
        }
    }
}

// ---------------------------------------------------------------------------
// 512-thread GEMM for the 256-block Wo shape: 128x128 tile, 8 waves of
// 32x64 -> 8 waves/CU at 1 block/CU (vs 4 with the 256t version). fp32 out.
// ---------------------------------------------------------------------------
__global__ __launch_bounds__(512)
void gemm_wide(const bf16* __restrict__ A, const bf16* __restrict__ BT,
               float* __restrict__ C, int K, int lda, int ldb, int ldc)
{
    __shared__ bf16 aL[128 * 32];
    __shared__ bf16 bL[128 * 32];

    const int tid  = threadIdx.x;
    const int wv   = tid >> 6;          // 0..7
    const int lane = tid & 63;
    const int quad = lane >> 4;
    const int l16  = lane & 15;

    const int tile_m = blockIdx.y * 128;
    const int tile_n = blockIdx.x * 128;
    const int wrow = (wv >> 1) * 32;    // 0,32,64,96
    const int wcol = (wv & 1) * 64;     // 0,64

    const int lrow = lane >> 2;
    const int lke  = (lane & 3) * 8;

    f32x4 acc[2][4] = {};

    for (int k0 = 0; k0 < K; k0 += 32) {
        {
            const int R = wv * 16;
            const bf16* srcA = A + (size_t)(tile_m + R + lrow) * lda + k0 + lke;
            __builtin_amdgcn_global_load_lds((gas_ptr)srcA, (las_ptr)(aL + R * 32), 16, 0, 0);
            const bf16* srcB = BT + (size_t)(tile_n + R + lrow) * ldb + k0 + lke;
            __builtin_amdgcn_global_load_lds((gas_ptr)srcB, (las_ptr)(bL + R * 32), 16, 0, 0);
        }
        __syncthreads();

        s16x8 af[2], bfr[4];
#pragma unroll
        for (int i = 0; i < 2; ++i)
            af[i] = *(const s16x8*)(&aL[(wrow + i * 16 + l16) * 32 + quad * 8]);
#pragma unroll
        for (int j = 0; j < 4; ++j)
            bfr[j] = *(const s16x8*)(&bL[(wcol + j * 16 + l16) * 32 + quad * 8]);

#pragma unroll
        for (int i = 0; i < 2; ++i)
#pragma unroll
            for (int j = 0; j < 4; ++j)
                acc[i][j] = __builtin_amdgcn_mfma_f32_16x16x32_bf16(
                    af[i], bfr[j], acc[i][j], 0, 0, 0);
        __syncthreads();
    }

#pragma unroll
    for (int i = 0; i < 2; ++i)
#pragma unroll
        for (int j = 0; j < 4; ++j) {
            const int col = tile_n + wcol + j * 16 + l16;
#pragma unroll
            for (int r = 0; r < 4; ++r) {
                const int row = tile_m + wrow + i * 16 + quad * 4 + r;
                C[(size_t)row * ldc + col] = acc[i][j][r];
            }
        }
}

// ---------------------------------------------------------------------------
// Batched transpose+convert: fp32 (R x C) -> bf16 (C x R), 32x32 LDS tiles.
// ---------------------------------------------------------------------------
struct TDesc { const float* src; bf16* dst; int R; int C; int tiles; int ctiles; };
struct TPack { TDesc d[6]; int n; };

__global__ __launch_bounds__(256)
void transpose_batch(TPack p)
{
    int b = blockIdx.x;
    int mi = 0;
    while (mi < p.n - 1 && b >= p.d[mi].tiles) { b -= p.d[mi].tiles; ++mi; }
    const TDesc d = p.d[mi];
    const int tr = b / d.ctiles, tc = b % d.ctiles;
    const int r0 = tr * 32, c0 = tc * 32;

    __shared__ float lds[32][33];
    const int tx = threadIdx.x & 31, ty = threadIdx.x >> 5;
#pragma unroll
    for (int i = 0; i < 4; ++i)
        lds[ty * 4 + i][tx] = d.src[(size_t)(r0 + ty * 4 + i) * d.C + c0 + tx];
    __syncthreads();
#pragma unroll
    for (int i = 0; i < 4; ++i)
        d.dst[(size_t)(c0 + ty * 4 + i) * d.R + r0 + tx] =
            __float2bfloat16(lds[tx][ty * 4 + i]);
}

// ---------------------------------------------------------------------------
// Batched fp32 -> bf16 convert (no transpose), 8 elems/thread, 3 segments.
// ---------------------------------------------------------------------------
__global__ __launch_bounds__(256)
void convert3(const float* s0, bf16* d0, int n0,
              const float* s1, bf16* d1, int n1,
              const float* s2, bf16* d2, int n2)
{
    int i = blockIdx.x * blockDim.x + threadIdx.x;   // 8-elem units
    const float* s; bf16* d;
    if (i < n0) { s = s0; d = d0; }
    else if (i < n0 + n1) { i -= n0; s = s1; d = d1; }
    else if (i < n0 + n1 + n2) { i -= n0 + n1; s = s2; d = d2; }
    else return;
    const float4 a = *(const float4*)(s + (size_t)i * 8);
    const float4 b = *(const float4*)(s + (size_t)i * 8 + 4);
    bf16 t[8];
    t[0] = __float2bfloat16(a.x); t[1] = __float2bfloat16(a.y);
    t[2] = __float2bfloat16(a.z); t[3] = __float2bfloat16(a.w);
    t[4] = __float2bfloat16(b.x); t[5] = __float2bfloat16(b.y);
    t[6] = __float2bfloat16(b.z); t[7] = __float2bfloat16(b.w);
    *(uint4*)(d + (size_t)i * 8) = *(uint4*)t;
}

// ---------------------------------------------------------------------------
// MLA-absorbed sparse attention (round-5 proven). One block per query t.
// ---------------------------------------------------------------------------
__global__ __launch_bounds__(256)
void attn_mla(const bf16* __restrict__ qt,   // [rows][8192] chunk
              const bf16* __restrict__ qr,   // [rows][1024] chunk (rope'd)
              const bf16* __restrict__ xw,   // [2048][1024], ckv = cols 512..1023
              const bf16* __restrict__ kr,   // [2048][64] (rope'd)
              const int*  __restrict__ topk, // [2048][32]
              bf16* __restrict__ U,          // [rows][8192]
              int t0)
{
    __shared__ short ckv_s[32 * 520];
    __shared__ short qt_s[16 * 520];
    __shared__ short kr_s[32 * 72];
    __shared__ short qr_s[16 * 72];
    __shared__ short P_s[4][16 * 40];
    __shared__ int   idx_s[32];

    const int tl   = blockIdx.x;
    const int tg   = t0 + tl;
    const int tid  = threadIdx.x;
    const int wv   = tid >> 6;
    const int lane = tid & 63;
    const int quad = lane >> 4;
    const int l16  = lane & 15;

    if (tid < 32) {
        int j = topk[(size_t)tg * TOPK + tid];
        idx_s[tid] = (j < 0 || j >= T_SEQ) ? 0 : j;
    }
    __syncthreads();

#pragma unroll
    for (int i = 0; i < 8; ++i) {
        const int row = wv * 8 + i;
        const int j = idx_s[row];
        __builtin_amdgcn_global_load_lds(
            (gas_ptr)(xw + (size_t)j * 1024 + 512 + lane * 8),
            (las_ptr)(ckv_s + row * 520), 16, 0, 0);
    }
#pragma unroll
    for (int i = 0; i < 4; ++i) {
        const int seg = wv * 4 + i;
        __builtin_amdgcn_global_load_lds(
            (gas_ptr)(qt + (size_t)tl * 8192 + seg * 512 + lane * 8),
            (las_ptr)(qt_s + seg * 520), 16, 0, 0);
    }
    {
        const int row = tid >> 3, seg = tid & 7;
        const int j = idx_s[row];
        *(uint4*)(kr_s + row * 72 + seg * 8) =
            *(const uint4*)(kr + (size_t)j * RD + seg * 8);
    }
    if (tid < 128) {
        const int head = tid >> 3, seg = tid & 7;
        *(uint4*)(qr_s + head * 72 + seg * 8) =
            *(const uint4*)(qr + (size_t)tl * 1024 + head * 64 + seg * 8);
    }
    __syncthreads();

    f32x4 sc[2] = {};
#pragma unroll
    for (int ks = 0; ks < 16; ++ks) {
        s16x8 a  = *(const s16x8*)(qt_s + l16 * 520 + ks * 32 + quad * 8);
        s16x8 b0 = *(const s16x8*)(ckv_s + l16 * 520 + ks * 32 + quad * 8);
        s16x8 b1 = *(const s16x8*)(ckv_s + (16 + l16) * 520 + ks * 32 + quad * 8);
        sc[0] = __builtin_amdgcn_mfma_f32_16x16x32_bf16(a, b0, sc[0], 0, 0, 0);
        sc[1] = __builtin_amdgcn_mfma_f32_16x16x32_bf16(a, b1, sc[1], 0, 0, 0);
    }
#pragma unroll
    for (int ks = 0; ks < 2; ++ks) {
        s16x8 a  = *(const s16x8*)(qr_s + l16 * 72 + ks * 32 + quad * 8);
        s16x8 b0 = *(const s16x8*)(kr_s + l16 * 72 + ks * 32 + quad * 8);
        s16x8 b1 = *(const s16x8*)(kr_s + (16 + l16) * 72 + ks * 32 + quad * 8);
        sc[0] = __builtin_amdgcn_mfma_f32_16x16x32_bf16(a, b0, sc[0], 0, 0, 0);
        sc[1] = __builtin_amdgcn_mfma_f32_16x16x32_bf16(a, b1, sc[1], 0, 0, 0);
    }

    const float scale = 0.0721687836487032f;   // 1/sqrt(192)
    float inv[4];
    short* pw = P_s[wv];
#pragma unroll
    for (int r = 0; r < 4; ++r) {
        float s0 = sc[0][r] * scale, s1 = sc[1][r] * scale;
        float mx = fmaxf(s0, s1);
#pragma unroll
        for (int off = 1; off < 16; off <<= 1) mx = fmaxf(mx, __shfl_xor(mx, off));
        float p0 = __expf(s0 - mx), p1 = __expf(s1 - mx);
        float l = p0 + p1;
#pragma unroll
        for (int off = 1; off < 16; off <<= 1) l += __shfl_xor(l, off);
        inv[r] = 1.f / l;
        pw[(quad * 4 + r) * 40 + l16]      = __builtin_bit_cast(short, __float2bfloat16(p0));
        pw[(quad * 4 + r) * 40 + 16 + l16] = __builtin_bit_cast(short, __float2bfloat16(p1));
    }

    s16x8 ap = *(const s16x8*)(pw + l16 * 40 + quad * 8);
#pragma unroll
    for (int tt = 0; tt < 8; ++tt) {
        const int n0 = wv * 128 + tt * 16;
        s16x8 b;
#pragma unroll
        for (int j = 0; j < 8; ++j)
            b[j] = ckv_s[(quad * 8 + j) * 520 + n0 + l16];
        f32x4 u = {};
        u = __builtin_amdgcn_mfma_f32_16x16x32_bf16(ap, b, u, 0, 0, 0);
#pragma unroll
        for (int r = 0; r < 4; ++r)
            U[(size_t)tl * 8192 + (quad * 4 + r) * 512 + n0 + l16] =
                __float2bfloat16(u[r] * inv[r]);
    }
}

// ---------------------------------------------------------------------------
extern "C" void kernel_launch(void* const* d_in, const int* in_sizes, int n_in,
                              void* d_out, int out_size, void* d_ws, size_t ws_size,
                              hipStream_t stream)
{
    const float* x    = (const float*)d_in[0];
    const float* Wqd  = (const float*)d_in[1];
    const float* Wqu  = (const float*)d_in[2];
    const float* Wqr  = (const float*)d_in[3];
    const float* Wkvd = (const float*)d_in[4];
    const float* Wku  = (const float*)d_in[5];
    const float* Wvu  = (const float*)d_in[6];
    const float* Wkr  = (const float*)d_in[7];
    const float* Wo   = (const float*)d_in[8];
    const int*   topk = (const int*)d_in[9];
    float* out = (float*)d_out;

    const size_t KB = 1024;
    char* ws = (char*)d_ws;
    const bool flat = ws_size >= (size_t)128000 * KB;
    const int  TCH  = flat ? 2048 : 512;
    const int  NCH  = T_SEQ / TCH;

    size_t oXB, oWxT, oWkrT, oWqub, oWkub, oWqrT, oWvuT, oWcombT, oXW, oKR,
           oQR, oO, oWoT, oQT, oU;
    if (flat) {
        oXB = 0;        oWxT = 8192;   oWkrT = 12288; oWqub = 12544;
        oWkub = 14592;  oWqrT = 16640; oWvuT = 17664; oWcombT = 19712;
        oXW = 27904;    oKR = 32000;   oQR = 32256;   oO = 36352;
        oWoT = 44544;   oQT = 52736;   oU = 85504;
    } else {
        oXB = 0;        oWcombT = 0;   oWoT = 0;       // phase-aliased [0,8M)
        oWvuT = 8192;   oQR = 10240;   oKR = 11264;   oXW = 11520;
        oO = 15616;     oWxT = 15616;  oWkrT = 19712;
        oQT = 23808;    oWqub = 23808; oWkub = 25856;
        oU = 32000;     oWqrT = 40192;
    }
    bf16* xb     = (bf16*)(ws + oXB * KB);
    bf16* WxT    = (bf16*)(ws + oWxT * KB);
    bf16* WkrT   = (bf16*)(ws + oWkrT * KB);
    bf16* Wqub   = (bf16*)(ws + oWqub * KB);
    bf16* Wkub   = (bf16*)(ws + oWkub * KB);
    bf16* WqrT   = (bf16*)(ws + oWqrT * KB);
    bf16* WvuT   = (bf16*)(ws + oWvuT * KB);
    bf16* WcombT = (bf16*)(ws + oWcombT * KB);
    bf16* xw     = (bf16*)(ws + oXW * KB);
    bf16* kr     = (bf16*)(ws + oKR * KB);
    bf16* qrC    = (bf16*)(ws + oQR * KB);
    bf16* o      = (bf16*)(ws + oO * KB);
    bf16* WoT    = (bf16*)(ws + oWoT * KB);
    bf16* qtC    = (bf16*)(ws + oQT * KB);
    bf16* uC     = (bf16*)(ws + oU * KB);

    dim3 blk(256);

    // Phase A: converts (x, Wqu, Wku) + transposes (Wqd,Wkvd,Wkr,Wqr,Wvu[,Wo])
    {
        int n0 = T_SEQ * DIM / 8, n1 = LAT * DIM / 8, n2 = LAT * DIM / 8;
        convert3<<<(n0 + n1 + n2 + 255) / 256, blk, 0, stream>>>(
            x, xb, n0, Wqu, Wqub, n1, Wku, Wkub, n2);
        TPack p;
        p.d[0] = { Wqd,  WxT,                   DIM, LAT,  (DIM/32)*(LAT/32),  LAT/32 };
        p.d[1] = { Wkvd, WxT + (size_t)LAT*DIM, DIM, LAT,  (DIM/32)*(LAT/32),  LAT/32 };
        p.d[2] = { Wkr,  WkrT,                  DIM, RD,   (DIM/32)*(RD/32),   RD/32  };
        p.d[3] = { Wqr,  WqrT,                  LAT, 1024, (LAT/32)*(1024/32), 1024/32 };
        p.d[4] = { Wvu,  WvuT,                  LAT, DIM,  (LAT/32)*(DIM/32),  DIM/32 };
        p.n = 5;
        int tot = p.d[0].tiles + p.d[1].tiles + p.d[2].tiles + p.d[3].tiles + p.d[4].tiles;
        if (flat) {   // WoT region is dedicated in flat mode: transpose early
            p.d[5] = { Wo, WoT, DIM, DIM, (DIM/32)*(DIM/32), DIM/32 };
            p.n = 6; tot += p.d[5].tiles;
        }
        transpose_batch<<<tot, blk, 0, stream>>>(p);
    }

    // Phase B (grouped): xw = xb@WxT^T | WcombT_h = Wku_h@Wqu_h^T (z=16) |
    //                    kr = xb@WkrT^T (N=64, guarded, rope fused)
    {
        GPack gp;
        gp.g[0] = { xb,   WxT,  xw,     DIM, DIM, DIM, 1024, 1024/128, T_SEQ/128, 1,
                    0, 0, 0, (1024/128)*(T_SEQ/128), 0, 0, 0 };
        gp.g[1] = { Wkub, Wqub, WcombT, 128, DIM, DIM, LAT,  LAT/128,  LAT/128,  NH,
                    128, 128, (long)LAT*LAT, (LAT/128)*(LAT/128)*NH, 0, 0, 0 };
        gp.g[2] = { xb,   WkrT, kr,     DIM, DIM, DIM, RD,   1,        T_SEQ/128, 1,
                    0, 0, 0, T_SEQ/128, 3 /*rope|guard*/, RD, 0 };
        gp.n = 3;
        int tot = gp.g[0].tiles + gp.g[1].tiles + gp.g[2].tiles;
        gemm_group<<<tot, blk, 0, stream>>>(gp);
    }

    // Phase C/D per chunk: [qt | qr(+rope)] grouped, attention, U-projection
    for (int c = 0; c < NCH; ++c) {
        const int t0 = c * TCH;
        bf16* qt = flat ? qtC + (size_t)t0 * 8192 : qtC;
        bf16* qr = flat ? qrC + (size_t)t0 * 1024 : qrC;
        bf16* U  = flat ? uC  + (size_t)t0 * 8192 : uC;
        const bf16* xwc = xw + (size_t)t0 * 1024;

        {
            GPack gp;
            gp.g[0] = { xwc, WcombT, qt, LAT, 1024, LAT, 8192, 8192/128, TCH/128, 1,
                        0, 0, 0, (8192/128)*(TCH/128), 0, 0, 0 };
            gp.g[1] = { xwc, WqrT,   qr, LAT, 1024, LAT, 1024, 1024/128, TCH/128, 1,
                        0, 0, 0, (1024/128)*(TCH/128), 1 /*rope*/, 1024, t0 };
            gp.n = 2;
            gemm_group<<<gp.g[0].tiles + gp.g[1].tiles, blk, 0, stream>>>(gp);
        }
        attn_mla<<<TCH, blk, 0, stream>>>(qt, qr, xw, kr, topk, U, t0);
        {
            GPack gp;
            gp.g[0] = { U, WvuT, o + (size_t)t0 * DIM, LAT, 8192, LAT, DIM,
                        1, TCH/128, NH, 512, (long)128*LAT, 128,
                        (TCH/128)*NH, 0, 0, 0 };
            gp.n = 1;
            gemm_group<<<gp.g[0].tiles, blk, 0, stream>>>(gp);
        }
    }

    // Phase E: out = o @ WoT^T (fp32), 512-thread 8-wave blocks
    if (!flat) {   // chunked mode: WoT aliases WcombT region; transpose late
        TPack p;
        p.d[0] = { Wo, WoT, DIM, DIM, (DIM/32)*(DIM/32), DIM/32 };
        p.n = 1;
        transpose_batch<<<p.d[0].tiles, blk, 0, stream>>>(p);
    }
    gemm_wide<<<dim3(DIM/128, T_SEQ/128), dim3(512), 0, stream>>>(
        o, WoT, out, DIM, DIM, DIM, DIM);
}

// Round 7
// 283.100 us; speedup vs baseline: 1.9910x; 1.0325x over previous
//
#include <hip/hip_runtime.h>
#include <hip/hip_bf16.h>
#include <math.h>

typedef __hip_bfloat16 bf16;
typedef __attribute__((ext_vector_type(4))) float f32x4;
typedef __attribute__((ext_vector_type(8))) short s16x8;

#define T_SEQ 2048
#define DIM   2048
#define NH    16
#define LAT   512
#define RD    64
#define TOPK  32

typedef const __attribute__((address_space(1))) void* gas_ptr;
typedef __attribute__((address_space(3))) void* las_ptr;

// ---------------------------------------------------------------------------
// Grouped GEMM descriptors (shared by both tile shapes).
// flags: 1 = RoPE epilogue (rotate col pairs (c, c+32), position = t0+row),
//        2 = column guard (col < N).
// ---------------------------------------------------------------------------
struct GGroup {
    const bf16* A; const bf16* BT; bf16* C;
    int K, lda, ldb, ldc;
    int tx, ty, nz;          // tiles in n, m, z
    long aZ, bZ, cZ;         // element strides per z
    int tiles;               // tx*ty*nz
    int flags, N, t0;
};
struct GPack { GGroup g[4]; int n; };

// ---------------------------------------------------------------------------
// 128x128-tile grouped GEMM: 4 waves, wave = 64x64 (4x4 frags). m97 staging.
// ---------------------------------------------------------------------------
__global__ __launch_bounds__(256)
void gemm_group(GPack gp)
{
    int b = blockIdx.x;
    int gi = 0;
    while (gi < gp.n - 1 && b >= gp.g[gi].tiles) { b -= gp.g[gi].tiles; ++gi; }
    const GGroup g = gp.g[gi];

    const int per_z = g.tx * g.ty;
    const int z   = b / per_z;
    const int rem = b - z * per_z;
    const int bx  = rem % g.tx;
    const int by  = rem / g.tx;

    const bf16* A  = g.A  + (size_t)z * g.aZ;
    const bf16* BT = g.BT + (size_t)z * g.bZ;
    bf16*       C  = g.C  + (size_t)z * g.cZ;

    __shared__ bf16 aL[128 * 32];
    __shared__ bf16 bL[128 * 32];

    const int tid  = threadIdx.x;
    const int wave = tid >> 6;
    const int lane = tid & 63;
    const int quad = lane >> 4;
    const int l16  = lane & 15;

    const int tile_m = by * 128;
    const int tile_n = bx * 128;
    const int wrow = (wave >> 1) * 64;
    const int wcol = (wave & 1) * 64;

    const int lrow = lane >> 2;
    const int lke  = (lane & 3) * 8;

    f32x4 acc[4][4] = {};

    for (int k0 = 0; k0 < g.K; k0 += 32) {
#pragma unroll
        for (int p = 0; p < 2; ++p) {
            const int R = (wave * 2 + p) * 16;
            const bf16* src = A + (size_t)(tile_m + R + lrow) * g.lda + k0 + lke;
            __builtin_amdgcn_global_load_lds((gas_ptr)src, (las_ptr)(aL + R * 32), 16, 0, 0);
        }
#pragma unroll
        for (int p = 0; p < 2; ++p) {
            const int R = (wave * 2 + p) * 16;
            const bf16* src = BT + (size_t)(tile_n + R + lrow) * g.ldb + k0 + lke;
            __builtin_amdgcn_global_load_lds((gas_ptr)src, (las_ptr)(bL + R * 32), 16, 0, 0);
        }
        __syncthreads();

        s16x8 af[4], bfr[4];
#pragma unroll
        for (int i = 0; i < 4; ++i)
            af[i] = *(const s16x8*)(&aL[(wrow + i * 16 + l16) * 32 + quad * 8]);
#pragma unroll
        for (int j = 0; j < 4; ++j)
            bfr[j] = *(const s16x8*)(&bL[(wcol + j * 16 + l16) * 32 + quad * 8]);

#pragma unroll
        for (int i = 0; i < 4; ++i)
#pragma unroll
            for (int j = 0; j < 4; ++j)
                acc[i][j] = __builtin_amdgcn_mfma_f32_16x16x32_bf16(
                    af[i], bfr[j], acc[i][j], 0, 0, 0);
        __syncthreads();
    }

    // D mapping: col = lane&15, row = (lane>>4)*4 + reg   [m89-verified]
    if (g.flags & 1) {
#pragma unroll
        for (int jp = 0; jp < 2; ++jp) {
            const int colL = tile_n + wcol + jp * 16 + l16;
            if ((g.flags & 2) && colL >= g.N) continue;
            const float fr = powf(10000.f, -(float)(jp * 16 + l16) / 32.f);
#pragma unroll
            for (int i = 0; i < 4; ++i) {
#pragma unroll
                for (int r = 0; r < 4; ++r) {
                    const int row = tile_m + wrow + i * 16 + quad * 4 + r;
                    float sv, cv;
                    sincosf((float)(g.t0 + row) * fr, &sv, &cv);
                    const float x0 = acc[i][jp][r];
                    const float x1 = acc[i][jp + 2][r];
                    C[(size_t)row * g.ldc + colL]      = __float2bfloat16(x0 * cv - x1 * sv);
                    C[(size_t)row * g.ldc + colL + 32] = __float2bfloat16(x1 * cv + x0 * sv);
                }
            }
        }
    } else {
#pragma unroll
        for (int j = 0; j < 4; ++j) {
            const int col = tile_n + wcol + j * 16 + l16;
            if ((g.flags & 2) && col >= g.N) continue;
#pragma unroll
            for (int i = 0; i < 4; ++i)
#pragma unroll
                for (int r = 0; r < 4; ++r) {
                    const int row = tile_m + wrow + i * 16 + quad * 4 + r;
                    C[(size_t)row * g.ldc + col] = __float2bfloat16(acc[i][j][r]);
                }
        }
    }
}

// ---------------------------------------------------------------------------
// 128x64-tile grouped GEMM: 4 waves, wave = 32 rows x 64 cols (2x4 frags).
// 2x the blocks of the 128-tile for skinny-N jobs -> restores occupancy.
// Rope pairing (c, c+32) stays intra-wave: acc[i][jp] with acc[i][jp+2].
// ---------------------------------------------------------------------------
__global__ __launch_bounds__(256)
void gemm_group64(GPack gp)
{
    int b = blockIdx.x;
    int gi = 0;
    while (gi < gp.n - 1 && b >= gp.g[gi].tiles) { b -= gp.g[gi].tiles; ++gi; }
    const GGroup g = gp.g[gi];

    const int per_z = g.tx * g.ty;
    const int z   = b / per_z;
    const int rem = b - z * per_z;
    const int bx  = rem % g.tx;
    const int by  = rem / g.tx;

    const bf16* A  = g.A  + (size_t)z * g.aZ;
    const bf16* BT = g.BT + (size_t)z * g.bZ;
    bf16*       C  = g.C  + (size_t)z * g.cZ;

    __shared__ bf16 aL[128 * 32];
    __shared__ bf16 bL[64 * 32];

    const int tid  = threadIdx.x;
    const int wave = tid >> 6;
    const int lane = tid & 63;
    const int quad = lane >> 4;
    const int l16  = lane & 15;

    const int tile_m = by * 128;
    const int tile_n = bx * 64;
    const int wrow = wave * 32;

    const int lrow = lane >> 2;
    const int lke  = (lane & 3) * 8;

    f32x4 acc[2][4] = {};

    for (int k0 = 0; k0 < g.K; k0 += 32) {
#pragma unroll
        for (int p = 0; p < 2; ++p) {
            const int R = (wave * 2 + p) * 16;
            const bf16* src = A + (size_t)(tile_m + R + lrow) * g.lda + k0 + lke;
            __builtin_amdgcn_global_load_lds((gas_ptr)src, (las_ptr)(aL + R * 32), 16, 0, 0);
        }
        {
            const int R = wave * 16;
            const bf16* src = BT + (size_t)(tile_n + R + lrow) * g.ldb + k0 + lke;
            __builtin_amdgcn_global_load_lds((gas_ptr)src, (las_ptr)(bL + R * 32), 16, 0, 0);
        }
        __syncthreads();

        s16x8 af[2], bfr[4];
#pragma unroll
        for (int i = 0; i < 2; ++i)
            af[i] = *(const s16x8*)(&aL[(wrow + i * 16 + l16) * 32 + quad * 8]);
#pragma unroll
        for (int j = 0; j < 4; ++j)
            bfr[j] = *(const s16x8*)(&bL[(j * 16 + l16) * 32 + quad * 8]);

#pragma unroll
        for (int i = 0; i < 2; ++i)
#pragma unroll
            for (int j = 0; j < 4; ++j)
                acc[i][j] = __builtin_amdgcn_mfma_f32_16x16x32_bf16(
                    af[i], bfr[j], acc[i][j], 0, 0, 0);
        __syncthreads();
    }

    if (g.flags & 1) {
#pragma unroll
        for (int jp = 0; jp < 2; ++jp) {
            const int colL = tile_n + jp * 16 + l16;
            if ((g.flags & 2) && colL >= g.N) continue;
            const float fr = powf(10000.f, -(float)(jp * 16 + l16) / 32.f);
#pragma unroll
            for (int i = 0; i < 2; ++i) {
#pragma unroll
                for (int r = 0; r < 4; ++r) {
                    const int row = tile_m + wrow + i * 16 + quad * 4 + r;
                    float sv, cv;
                    sincosf((float)(g.t0 + row) * fr, &sv, &cv);
                    const float x0 = acc[i][jp][r];
                    const float x1 = acc[i][jp + 2][r];
                    C[(size_t)row * g.ldc + colL]      = __float2bfloat16(x0 * cv - x1 * sv);
                    C[(size_t)row * g.ldc + colL + 32] = __float2bfloat16(x1 * cv + x0 * sv);
                }
            }
        }
    } else {
#pragma unroll
        for (int j = 0; j < 4; ++j) {
            const int col = tile_n + j * 16 + l16;
            if ((g.flags & 2) && col >= g.N) continue;
#pragma unroll
            for (int i = 0; i < 2; ++i)
#pragma unroll
                for (int r = 0; r < 4; ++r) {
                    const int row = tile_m + wrow + i * 16 + quad * 4 + r;
                    C[(size_t)row * g.ldc + col] = __float2bfloat16(acc[i][j][r]);
                }
        }
    }
}

// ---------------------------------------------------------------------------
// 512-thread GEMM for the 256-block Wo shape: 128x128 tile, 8 waves of
// 32x64 -> 8 waves/CU at 1 block/CU. fp32 out.
// ---------------------------------------------------------------------------
__global__ __launch_bounds__(512)
void gemm_wide(const bf16* __restrict__ A, const bf16* __restrict__ BT,
               float* __restrict__ C, int K, int lda, int ldb, int ldc)
{
    __shared__ bf16 aL[128 * 32];
    __shared__ bf16 bL[128 * 32];

    const int tid  = threadIdx.x;
    const int wv   = tid >> 6;          // 0..7
    const int lane = tid & 63;
    const int quad = lane >> 4;
    const int l16  = lane & 15;

    const int tile_m = blockIdx.y * 128;
    const int tile_n = blockIdx.x * 128;
    const int wrow = (wv >> 1) * 32;
    const int wcol = (wv & 1) * 64;

    const int lrow = lane >> 2;
    const int lke  = (lane & 3) * 8;

    f32x4 acc[2][4] = {};

    for (int k0 = 0; k0 < K; k0 += 32) {
        {
            const int R = wv * 16;
            const bf16* srcA = A + (size_t)(tile_m + R + lrow) * lda + k0 + lke;
            __builtin_amdgcn_global_load_lds((gas_ptr)srcA, (las_ptr)(aL + R * 32), 16, 0, 0);
            const bf16* srcB = BT + (size_t)(tile_n + R + lrow) * ldb + k0 + lke;
            __builtin_amdgcn_global_load_lds((gas_ptr)srcB, (las_ptr)(bL + R * 32), 16, 0, 0);
        }
        __syncthreads();

        s16x8 af[2], bfr[4];
#pragma unroll
        for (int i = 0; i < 2; ++i)
            af[i] = *(const s16x8*)(&aL[(wrow + i * 16 + l16) * 32 + quad * 8]);
#pragma unroll
        for (int j = 0; j < 4; ++j)
            bfr[j] = *(const s16x8*)(&bL[(wcol + j * 16 + l16) * 32 + quad * 8]);

#pragma unroll
        for (int i = 0; i < 2; ++i)
#pragma unroll
            for (int j = 0; j < 4; ++j)
                acc[i][j] = __builtin_amdgcn_mfma_f32_16x16x32_bf16(
                    af[i], bfr[j], acc[i][j], 0, 0, 0);
        __syncthreads();
    }

#pragma unroll
    for (int i = 0; i < 2; ++i)
#pragma unroll
        for (int j = 0; j < 4; ++j) {
            const int col = tile_n + wcol + j * 16 + l16;
#pragma unroll
            for (int r = 0; r < 4; ++r) {
                const int row = tile_m + wrow + i * 16 + quad * 4 + r;
                C[(size_t)row * ldc + col] = acc[i][j][r];
            }
        }
}

// ---------------------------------------------------------------------------
// Batched transpose+convert: fp32 (R x C) -> bf16 (C x R), 32x32 LDS tiles.
// ---------------------------------------------------------------------------
struct TDesc { const float* src; bf16* dst; int R; int C; int tiles; int ctiles; };
struct TPack { TDesc d[6]; int n; };

__global__ __launch_bounds__(256)
void transpose_batch(TPack p)
{
    int b = blockIdx.x;
    int mi = 0;
    while (mi < p.n - 1 && b >= p.d[mi].tiles) { b -= p.d[mi].tiles; ++mi; }
    const TDesc d = p.d[mi];
    const int tr = b / d.ctiles, tc = b % d.ctiles;
    const int r0 = tr * 32, c0 = tc * 32;

    __shared__ float lds[32][33];
    const int tx = threadIdx.x & 31, ty = threadIdx.x >> 5;
#pragma unroll
    for (int i = 0; i < 4; ++i)
        lds[ty * 4 + i][tx] = d.src[(size_t)(r0 + ty * 4 + i) * d.C + c0 + tx];
    __syncthreads();
#pragma unroll
    for (int i = 0; i < 4; ++i)
        d.dst[(size_t)(c0 + ty * 4 + i) * d.R + r0 + tx] =
            __float2bfloat16(lds[tx][ty * 4 + i]);
}

// ---------------------------------------------------------------------------
// Batched fp32 -> bf16 convert (no transpose), 8 elems/thread, 3 segments.
// ---------------------------------------------------------------------------
__global__ __launch_bounds__(256)
void convert3(const float* s0, bf16* d0, int n0,
              const float* s1, bf16* d1, int n1,
              const float* s2, bf16* d2, int n2)
{
    int i = blockIdx.x * blockDim.x + threadIdx.x;   // 8-elem units
    const float* s; bf16* d;
    if (i < n0) { s = s0; d = d0; }
    else if (i < n0 + n1) { i -= n0; s = s1; d = d1; }
    else if (i < n0 + n1 + n2) { i -= n0 + n1; s = s2; d = d2; }
    else return;
    const float4 a = *(const float4*)(s + (size_t)i * 8);
    const float4 b = *(const float4*)(s + (size_t)i * 8 + 4);
    bf16 t[8];
    t[0] = __float2bfloat16(a.x); t[1] = __float2bfloat16(a.y);
    t[2] = __float2bfloat16(a.z); t[3] = __float2bfloat16(a.w);
    t[4] = __float2bfloat16(b.x); t[5] = __float2bfloat16(b.y);
    t[6] = __float2bfloat16(b.z); t[7] = __float2bfloat16(b.w);
    *(uint4*)(d + (size_t)i * 8) = *(uint4*)t;
}

// ---------------------------------------------------------------------------
// MLA-absorbed sparse attention (round-5 proven). One block per query t.
// ---------------------------------------------------------------------------
__global__ __launch_bounds__(256)
void attn_mla(const bf16* __restrict__ qt,   // [rows][8192] chunk
              const bf16* __restrict__ qr,   // [rows][1024] chunk (rope'd)
              const bf16* __restrict__ xw,   // [2048][1024], ckv = cols 512..1023
              const bf16* __restrict__ kr,   // [2048][64] (rope'd)
              const int*  __restrict__ topk, // [2048][32]
              bf16* __restrict__ U,          // [rows][8192]
              int t0)
{
    __shared__ short ckv_s[32 * 520];
    __shared__ short qt_s[16 * 520];
    __shared__ short kr_s[32 * 72];
    __shared__ short qr_s[16 * 72];
    __shared__ short P_s[4][16 * 40];
    __shared__ int   idx_s[32];

    const int tl   = blockIdx.x;
    const int tg   = t0 + tl;
    const int tid  = threadIdx.x;
    const int wv   = tid >> 6;
    const int lane = tid & 63;
    const int quad = lane >> 4;
    const int l16  = lane & 15;

    if (tid < 32) {
        int j = topk[(size_t)tg * TOPK + tid];
        idx_s[tid] = (j < 0 || j >= T_SEQ) ? 0 : j;
    }
    __syncthreads();

#pragma unroll
    for (int i = 0; i < 8; ++i) {
        const int row = wv * 8 + i;
        const int j = idx_s[row];
        __builtin_amdgcn_global_load_lds(
            (gas_ptr)(xw + (size_t)j * 1024 + 512 + lane * 8),
            (las_ptr)(ckv_s + row * 520), 16, 0, 0);
    }
#pragma unroll
    for (int i = 0; i < 4; ++i) {
        const int seg = wv * 4 + i;
        __builtin_amdgcn_global_load_lds(
            (gas_ptr)(qt + (size_t)tl * 8192 + seg * 512 + lane * 8),
            (las_ptr)(qt_s + seg * 520), 16, 0, 0);
    }
    {
        const int row = tid >> 3, seg = tid & 7;
        const int j = idx_s[row];
        *(uint4*)(kr_s + row * 72 + seg * 8) =
            *(const uint4*)(kr + (size_t)j * RD + seg * 8);
    }
    if (tid < 128) {
        const int head = tid >> 3, seg = tid & 7;
        *(uint4*)(qr_s + head * 72 + seg * 8) =
            *(const uint4*)(qr + (size_t)tl * 1024 + head * 64 + seg * 8);
    }
    __syncthreads();

    f32x4 sc[2] = {};
#pragma unroll
    for (int ks = 0; ks < 16; ++ks) {
        s16x8 a  = *(const s16x8*)(qt_s + l16 * 520 + ks * 32 + quad * 8);
        s16x8 b0 = *(const s16x8*)(ckv_s + l16 * 520 + ks * 32 + quad * 8);
        s16x8 b1 = *(const s16x8*)(ckv_s + (16 + l16) * 520 + ks * 32 + quad * 8);
        sc[0] = __builtin_amdgcn_mfma_f32_16x16x32_bf16(a, b0, sc[0], 0, 0, 0);
        sc[1] = __builtin_amdgcn_mfma_f32_16x16x32_bf16(a, b1, sc[1], 0, 0, 0);
    }
#pragma unroll
    for (int ks = 0; ks < 2; ++ks) {
        s16x8 a  = *(const s16x8*)(qr_s + l16 * 72 + ks * 32 + quad * 8);
        s16x8 b0 = *(const s16x8*)(kr_s + l16 * 72 + ks * 32 + quad * 8);
        s16x8 b1 = *(const s16x8*)(kr_s + (16 + l16) * 72 + ks * 32 + quad * 8);
        sc[0] = __builtin_amdgcn_mfma_f32_16x16x32_bf16(a, b0, sc[0], 0, 0, 0);
        sc[1] = __builtin_amdgcn_mfma_f32_16x16x32_bf16(a, b1, sc[1], 0, 0, 0);
    }

    const float scale = 0.0721687836487032f;   // 1/sqrt(192)
    float inv[4];
    short* pw = P_s[wv];
#pragma unroll
    for (int r = 0; r < 4; ++r) {
        float s0 = sc[0][r] * scale, s1 = sc[1][r] * scale;
        float mx = fmaxf(s0, s1);
#pragma unroll
        for (int off = 1; off < 16; off <<= 1) mx = fmaxf(mx, __shfl_xor(mx, off));
        float p0 = __expf(s0 - mx), p1 = __expf(s1 - mx);
        float l = p0 + p1;
#pragma unroll
        for (int off = 1; off < 16; off <<= 1) l += __shfl_xor(l, off);
        inv[r] = 1.f / l;
        pw[(quad * 4 + r) * 40 + l16]      = __builtin_bit_cast(short, __float2bfloat16(p0));
        pw[(quad * 4 + r) * 40 + 16 + l16] = __builtin_bit_cast(short, __float2bfloat16(p1));
    }

    s16x8 ap = *(const s16x8*)(pw + l16 * 40 + quad * 8);
#pragma unroll
    for (int tt = 0; tt < 8; ++tt) {
        const int n0 = wv * 128 + tt * 16;
        s16x8 b;
#pragma unroll
        for (int j = 0; j < 8; ++j)
            b[j] = ckv_s[(quad * 8 + j) * 520 + n0 + l16];
        f32x4 u = {};
        u = __builtin_amdgcn_mfma_f32_16x16x32_bf16(ap, b, u, 0, 0, 0);
#pragma unroll
        for (int r = 0; r < 4; ++r)
            U[(size_t)tl * 8192 + (quad * 4 + r) * 512 + n0 + l16] =
                __float2bfloat16(u[r] * inv[r]);
    }
}

// ---------------------------------------------------------------------------
extern "C" void kernel_launch(void* const* d_in, const int* in_sizes, int n_in,
                              void* d_out, int out_size, void* d_ws, size_t ws_size,
                              hipStream_t stream)
{
    const float* x    = (const float*)d_in[0];
    const float* Wqd  = (const float*)d_in[1];
    const float* Wqu  = (const float*)d_in[2];
    const float* Wqr  = (const float*)d_in[3];
    const float* Wkvd = (const float*)d_in[4];
    const float* Wku  = (const float*)d_in[5];
    const float* Wvu  = (const float*)d_in[6];
    const float* Wkr  = (const float*)d_in[7];
    const float* Wo   = (const float*)d_in[8];
    const int*   topk = (const int*)d_in[9];
    float* out = (float*)d_out;

    const size_t KB = 1024;
    char* ws = (char*)d_ws;
    const bool flat = ws_size >= (size_t)128000 * KB;
    const int  TCH  = flat ? 2048 : 512;
    const int  NCH  = T_SEQ / TCH;

    size_t oXB, oWxT, oWkrT, oWqub, oWkub, oWqrT, oWvuT, oWcombT, oXW, oKR,
           oQR, oO, oWoT, oQT, oU;
    if (flat) {
        oXB = 0;        oWxT = 8192;   oWkrT = 12288; oWqub = 12544;
        oWkub = 14592;  oWqrT = 16640; oWvuT = 17664; oWcombT = 19712;
        oXW = 27904;    oKR = 32000;   oQR = 32256;   oO = 36352;
        oWoT = 44544;   oQT = 52736;   oU = 85504;
    } else {
        oXB = 0;        oWcombT = 0;   oWoT = 0;       // phase-aliased [0,8M)
        oWvuT = 8192;   oQR = 10240;   oKR = 11264;   oXW = 11520;
        oO = 15616;     oWxT = 15616;  oWkrT = 19712;
        oQT = 23808;    oWqub = 23808; oWkub = 25856;
        oU = 32000;     oWqrT = 40192;
    }
    bf16* xb     = (bf16*)(ws + oXB * KB);
    bf16* WxT    = (bf16*)(ws + oWxT * KB);
    bf16* WkrT   = (bf16*)(ws + oWkrT * KB);
    bf16* Wqub   = (bf16*)(ws + oWqub * KB);
    bf16* Wkub   = (bf16*)(ws + oWkub * KB);
    bf16* WqrT   = (bf16*)(ws + oWqrT * KB);
    bf16* WvuT   = (bf16*)(ws + oWvuT * KB);
    bf16* WcombT = (bf16*)(ws + oWcombT * KB);
    bf16* xw     = (bf16*)(ws + oXW * KB);
    bf16* kr     = (bf16*)(ws + oKR * KB);
    bf16* qrC    = (bf16*)(ws + oQR * KB);
    bf16* o      = (bf16*)(ws + oO * KB);
    bf16* WoT    = (bf16*)(ws + oWoT * KB);
    bf16* qtC    = (bf16*)(ws + oQT * KB);
    bf16* uC     = (bf16*)(ws + oU * KB);

    dim3 blk(256);

    // Phase A: converts (x, Wqu, Wku) + transposes (Wqd,Wkvd,Wkr,Wqr,Wvu[,Wo])
    {
        int n0 = T_SEQ * DIM / 8, n1 = LAT * DIM / 8, n2 = LAT * DIM / 8;
        convert3<<<(n0 + n1 + n2 + 255) / 256, blk, 0, stream>>>(
            x, xb, n0, Wqu, Wqub, n1, Wku, Wkub, n2);
        TPack p;
        p.d[0] = { Wqd,  WxT,                   DIM, LAT,  (DIM/32)*(LAT/32),  LAT/32 };
        p.d[1] = { Wkvd, WxT + (size_t)LAT*DIM, DIM, LAT,  (DIM/32)*(LAT/32),  LAT/32 };
        p.d[2] = { Wkr,  WkrT,                  DIM, RD,   (DIM/32)*(RD/32),   RD/32  };
        p.d[3] = { Wqr,  WqrT,                  LAT, 1024, (LAT/32)*(1024/32), 1024/32 };
        p.d[4] = { Wvu,  WvuT,                  LAT, DIM,  (LAT/32)*(DIM/32),  DIM/32 };
        p.n = 5;
        int tot = p.d[0].tiles + p.d[1].tiles + p.d[2].tiles + p.d[3].tiles + p.d[4].tiles;
        if (flat) {
            p.d[5] = { Wo, WoT, DIM, DIM, (DIM/32)*(DIM/32), DIM/32 };
            p.n = 6; tot += p.d[5].tiles;
        }
        transpose_batch<<<tot, blk, 0, stream>>>(p);
    }

    // Phase B (grouped, 128x64 tiles -> 784 blocks ~3/CU):
    //   xw = xb@WxT^T (256) | WcombT_h = Wku_h@Wqu_h^T (512) | kr (16, rope)
    {
        GPack gp;
        gp.g[0] = { xb,   WxT,  xw,     DIM, DIM, DIM, 1024, 1024/64, T_SEQ/128, 1,
                    0, 0, 0, (1024/64)*(T_SEQ/128), 0, 1024, 0 };
        gp.g[1] = { Wkub, Wqub, WcombT, 128, DIM, DIM, LAT,  LAT/64,  LAT/128,  NH,
                    128, 128, (long)LAT*LAT, (LAT/64)*(LAT/128)*NH, 0, LAT, 0 };
        gp.g[2] = { xb,   WkrT, kr,     DIM, DIM, DIM, RD,   1,       T_SEQ/128, 1,
                    0, 0, 0, T_SEQ/128, 1 /*rope*/, RD, 0 };
        gp.n = 3;
        int tot = gp.g[0].tiles + gp.g[1].tiles + gp.g[2].tiles;
        gemm_group64<<<tot, blk, 0, stream>>>(gp);
    }

    // Phase C/D per chunk: [qt | qr(+rope)] grouped (128-tiles), attention,
    // U-projection (64-tiles, 2 col-tiles per head)
    for (int c = 0; c < NCH; ++c) {
        const int t0 = c * TCH;
        bf16* qt = flat ? qtC + (size_t)t0 * 8192 : qtC;
        bf16* qr = flat ? qrC + (size_t)t0 * 1024 : qrC;
        bf16* U  = flat ? uC  + (size_t)t0 * 8192 : uC;
        const bf16* xwc = xw + (size_t)t0 * 1024;

        {
            GPack gp;
            gp.g[0] = { xwc, WcombT, qt, LAT, 1024, LAT, 8192, 8192/128, TCH/128, 1,
                        0, 0, 0, (8192/128)*(TCH/128), 0, 8192, 0 };
            gp.g[1] = { xwc, WqrT,   qr, LAT, 1024, LAT, 1024, 1024/128, TCH/128, 1,
                        0, 0, 0, (1024/128)*(TCH/128), 1 /*rope*/, 1024, t0 };
            gp.n = 2;
            gemm_group<<<gp.g[0].tiles + gp.g[1].tiles, blk, 0, stream>>>(gp);
        }
        attn_mla<<<TCH, blk, 0, stream>>>(qt, qr, xw, kr, topk, U, t0);
        {
            GPack gp;
            gp.g[0] = { U, WvuT, o + (size_t)t0 * DIM, LAT, 8192, LAT, DIM,
                        2, TCH/128, NH, 512, (long)128*LAT, 128,
                        2*(TCH/128)*NH, 0, 128, 0 };
            gp.n = 1;
            gemm_group64<<<gp.g[0].tiles, blk, 0, stream>>>(gp);
        }
    }

    // Phase E: out = o @ WoT^T (fp32), 512-thread 8-wave blocks
    if (!flat) {
        TPack p;
        p.d[0] = { Wo, WoT, DIM, DIM, (DIM/32)*(DIM/32), DIM/32 };
        p.n = 1;
        transpose_batch<<<p.d[0].tiles, blk, 0, stream>>>(p);
    }
    gemm_wide<<<dim3(DIM/128, T_SEQ/128), dim3(512), 0, stream>>>(
        o, WoT, out, DIM, DIM, DIM, DIM);
}

// Round 8
// 280.713 us; speedup vs baseline: 2.0080x; 1.0085x over previous
//
#include <hip/hip_runtime.h>
#include <hip/hip_bf16.h>
#include <math.h>

typedef __hip_bfloat16 bf16;
typedef __attribute__((ext_vector_type(4))) float f32x4;
typedef __attribute__((ext_vector_type(8))) short s16x8;

#define T_SEQ 2048
#define DIM   2048
#define NH    16
#define LAT   512
#define RD    64
#define TOPK  32

typedef const __attribute__((address_space(1))) void* gas_ptr;
typedef __attribute__((address_space(3))) void* las_ptr;

// ---------------------------------------------------------------------------
// Grouped GEMM descriptors.
// flags: 1 = RoPE epilogue (rotate col pairs (c, c+32), position = t0+row),
//        2 = column guard (col < N), 4 = fp32 output (C reinterpreted float*).
// ---------------------------------------------------------------------------
struct GGroup {
    const bf16* A; const bf16* BT; bf16* C;
    int K, lda, ldb, ldc;
    int tx, ty, nz;          // tiles in n, m, z
    long aZ, bZ, cZ;         // element strides per z
    int tiles;               // tx*ty*nz
    int flags, N, t0;
};
struct GPack { GGroup g[4]; int n; };

// ---------------------------------------------------------------------------
// 128x128-tile grouped GEMM, BK=64: 4 waves, wave = 64x64 (4x4 frags).
// Staging: 1KB global_load_lds instrs (8 rows x 128B), 4 per wave per operand;
// two K=32 MFMA sub-steps per barrier -> 32 MFMA/wave/iter.
// ---------------------------------------------------------------------------
__global__ __launch_bounds__(256)
void gemm_group(GPack gp)
{
    int b = blockIdx.x;
    int gi = 0;
    while (gi < gp.n - 1 && b >= gp.g[gi].tiles) { b -= gp.g[gi].tiles; ++gi; }
    const GGroup g = gp.g[gi];

    const int per_z = g.tx * g.ty;
    const int z   = b / per_z;
    const int rem = b - z * per_z;
    const int bx  = rem % g.tx;
    const int by  = rem / g.tx;

    const bf16* A  = g.A  + (size_t)z * g.aZ;
    const bf16* BT = g.BT + (size_t)z * g.bZ;
    bf16*       C  = g.C  + (size_t)z * g.cZ;

    __shared__ bf16 aL[128 * 64];
    __shared__ bf16 bL[128 * 64];

    const int tid  = threadIdx.x;
    const int wave = tid >> 6;
    const int lane = tid & 63;
    const int quad = lane >> 4;
    const int l16  = lane & 15;

    const int tile_m = by * 128;
    const int tile_n = bx * 128;
    const int wrow = (wave >> 1) * 64;
    const int wcol = (wave & 1) * 64;

    const int lrow = lane >> 3;          // 0..7
    const int lke  = (lane & 7) * 8;     // 0..56

    f32x4 acc[4][4] = {};

    for (int k0 = 0; k0 < g.K; k0 += 64) {
#pragma unroll
        for (int p = 0; p < 4; ++p) {
            const int R = (wave * 4 + p) * 8;
            const bf16* src = A + (size_t)(tile_m + R + lrow) * g.lda + k0 + lke;
            __builtin_amdgcn_global_load_lds((gas_ptr)src, (las_ptr)(aL + R * 64), 16, 0, 0);
        }
#pragma unroll
        for (int p = 0; p < 4; ++p) {
            const int R = (wave * 4 + p) * 8;
            const bf16* src = BT + (size_t)(tile_n + R + lrow) * g.ldb + k0 + lke;
            __builtin_amdgcn_global_load_lds((gas_ptr)src, (las_ptr)(bL + R * 64), 16, 0, 0);
        }
        __syncthreads();

#pragma unroll
        for (int ks = 0; ks < 2; ++ks) {
            s16x8 af[4], bfr[4];
#pragma unroll
            for (int i = 0; i < 4; ++i)
                af[i] = *(const s16x8*)(&aL[(wrow + i * 16 + l16) * 64 + ks * 32 + quad * 8]);
#pragma unroll
            for (int j = 0; j < 4; ++j)
                bfr[j] = *(const s16x8*)(&bL[(wcol + j * 16 + l16) * 64 + ks * 32 + quad * 8]);

#pragma unroll
            for (int i = 0; i < 4; ++i)
#pragma unroll
                for (int j = 0; j < 4; ++j)
                    acc[i][j] = __builtin_amdgcn_mfma_f32_16x16x32_bf16(
                        af[i], bfr[j], acc[i][j], 0, 0, 0);
        }
        __syncthreads();
    }

    // D mapping: col = lane&15, row = (lane>>4)*4 + reg   [m89-verified]
    if (g.flags & 1) {
#pragma unroll
        for (int jp = 0; jp < 2; ++jp) {
            const int colL = tile_n + wcol + jp * 16 + l16;
            if ((g.flags & 2) && colL >= g.N) continue;
            const float fr = powf(10000.f, -(float)(jp * 16 + l16) / 32.f);
#pragma unroll
            for (int i = 0; i < 4; ++i) {
#pragma unroll
                for (int r = 0; r < 4; ++r) {
                    const int row = tile_m + wrow + i * 16 + quad * 4 + r;
                    float sv, cv;
                    sincosf((float)(g.t0 + row) * fr, &sv, &cv);
                    const float x0 = acc[i][jp][r];
                    const float x1 = acc[i][jp + 2][r];
                    C[(size_t)row * g.ldc + colL]      = __float2bfloat16(x0 * cv - x1 * sv);
                    C[(size_t)row * g.ldc + colL + 32] = __float2bfloat16(x1 * cv + x0 * sv);
                }
            }
        }
    } else {
#pragma unroll
        for (int j = 0; j < 4; ++j) {
            const int col = tile_n + wcol + j * 16 + l16;
            if ((g.flags & 2) && col >= g.N) continue;
#pragma unroll
            for (int i = 0; i < 4; ++i)
#pragma unroll
                for (int r = 0; r < 4; ++r) {
                    const int row = tile_m + wrow + i * 16 + quad * 4 + r;
                    C[(size_t)row * g.ldc + col] = __float2bfloat16(acc[i][j][r]);
                }
        }
    }
}

// ---------------------------------------------------------------------------
// 128x64-tile grouped GEMM, BK=64: 4 waves, wave = 32 rows x 64 cols (2x4).
// 2x blocks of the 128-tile for skinny-N jobs; fp32-out flag for Wo.
// ---------------------------------------------------------------------------
__global__ __launch_bounds__(256)
void gemm_group64(GPack gp)
{
    int b = blockIdx.x;
    int gi = 0;
    while (gi < gp.n - 1 && b >= gp.g[gi].tiles) { b -= gp.g[gi].tiles; ++gi; }
    const GGroup g = gp.g[gi];

    const int per_z = g.tx * g.ty;
    const int z   = b / per_z;
    const int rem = b - z * per_z;
    const int bx  = rem % g.tx;
    const int by  = rem / g.tx;

    const bf16* A  = g.A  + (size_t)z * g.aZ;
    const bf16* BT = g.BT + (size_t)z * g.bZ;
    bf16*       C  = g.C  + (size_t)z * g.cZ;

    __shared__ bf16 aL[128 * 64];
    __shared__ bf16 bL[64 * 64];

    const int tid  = threadIdx.x;
    const int wave = tid >> 6;
    const int lane = tid & 63;
    const int quad = lane >> 4;
    const int l16  = lane & 15;

    const int tile_m = by * 128;
    const int tile_n = bx * 64;
    const int wrow = wave * 32;

    const int lrow = lane >> 3;
    const int lke  = (lane & 7) * 8;

    f32x4 acc[2][4] = {};

    for (int k0 = 0; k0 < g.K; k0 += 64) {
#pragma unroll
        for (int p = 0; p < 4; ++p) {
            const int R = (wave * 4 + p) * 8;
            const bf16* src = A + (size_t)(tile_m + R + lrow) * g.lda + k0 + lke;
            __builtin_amdgcn_global_load_lds((gas_ptr)src, (las_ptr)(aL + R * 64), 16, 0, 0);
        }
#pragma unroll
        for (int p = 0; p < 2; ++p) {
            const int R = (wave * 2 + p) * 8;
            const bf16* src = BT + (size_t)(tile_n + R + lrow) * g.ldb + k0 + lke;
            __builtin_amdgcn_global_load_lds((gas_ptr)src, (las_ptr)(bL + R * 64), 16, 0, 0);
        }
        __syncthreads();

#pragma unroll
        for (int ks = 0; ks < 2; ++ks) {
            s16x8 af[2], bfr[4];
#pragma unroll
            for (int i = 0; i < 2; ++i)
                af[i] = *(const s16x8*)(&aL[(wrow + i * 16 + l16) * 64 + ks * 32 + quad * 8]);
#pragma unroll
            for (int j = 0; j < 4; ++j)
                bfr[j] = *(const s16x8*)(&bL[(j * 16 + l16) * 64 + ks * 32 + quad * 8]);

#pragma unroll
            for (int i = 0; i < 2; ++i)
#pragma unroll
                for (int j = 0; j < 4; ++j)
                    acc[i][j] = __builtin_amdgcn_mfma_f32_16x16x32_bf16(
                        af[i], bfr[j], acc[i][j], 0, 0, 0);
        }
        __syncthreads();
    }

    if (g.flags & 1) {
#pragma unroll
        for (int jp = 0; jp < 2; ++jp) {
            const int colL = tile_n + jp * 16 + l16;
            if ((g.flags & 2) && colL >= g.N) continue;
            const float fr = powf(10000.f, -(float)(jp * 16 + l16) / 32.f);
#pragma unroll
            for (int i = 0; i < 2; ++i) {
#pragma unroll
                for (int r = 0; r < 4; ++r) {
                    const int row = tile_m + wrow + i * 16 + quad * 4 + r;
                    float sv, cv;
                    sincosf((float)(g.t0 + row) * fr, &sv, &cv);
                    const float x0 = acc[i][jp][r];
                    const float x1 = acc[i][jp + 2][r];
                    C[(size_t)row * g.ldc + colL]      = __float2bfloat16(x0 * cv - x1 * sv);
                    C[(size_t)row * g.ldc + colL + 32] = __float2bfloat16(x1 * cv + x0 * sv);
                }
            }
        }
    } else if (g.flags & 4) {
        float* Cf = (float*)C;
#pragma unroll
        for (int j = 0; j < 4; ++j) {
            const int col = tile_n + j * 16 + l16;
#pragma unroll
            for (int i = 0; i < 2; ++i)
#pragma unroll
                for (int r = 0; r < 4; ++r) {
                    const int row = tile_m + wrow + i * 16 + quad * 4 + r;
                    Cf[(size_t)row * g.ldc + col] = acc[i][j][r];
                }
        }
    } else {
#pragma unroll
        for (int j = 0; j < 4; ++j) {
            const int col = tile_n + j * 16 + l16;
            if ((g.flags & 2) && col >= g.N) continue;
#pragma unroll
            for (int i = 0; i < 2; ++i)
#pragma unroll
                for (int r = 0; r < 4; ++r) {
                    const int row = tile_m + wrow + i * 16 + quad * 4 + r;
                    C[(size_t)row * g.ldc + col] = __float2bfloat16(acc[i][j][r]);
                }
        }
    }
}

// ---------------------------------------------------------------------------
// Batched transpose+convert: fp32 (R x C) -> bf16 (C x R), 32x32 LDS tiles.
// ---------------------------------------------------------------------------
struct TDesc { const float* src; bf16* dst; int R; int C; int tiles; int ctiles; };
struct TPack { TDesc d[6]; int n; };

__global__ __launch_bounds__(256)
void transpose_batch(TPack p)
{
    int b = blockIdx.x;
    int mi = 0;
    while (mi < p.n - 1 && b >= p.d[mi].tiles) { b -= p.d[mi].tiles; ++mi; }
    const TDesc d = p.d[mi];
    const int tr = b / d.ctiles, tc = b % d.ctiles;
    const int r0 = tr * 32, c0 = tc * 32;

    __shared__ float lds[32][33];
    const int tx = threadIdx.x & 31, ty = threadIdx.x >> 5;
#pragma unroll
    for (int i = 0; i < 4; ++i)
        lds[ty * 4 + i][tx] = d.src[(size_t)(r0 + ty * 4 + i) * d.C + c0 + tx];
    __syncthreads();
#pragma unroll
    for (int i = 0; i < 4; ++i)
        d.dst[(size_t)(c0 + ty * 4 + i) * d.R + r0 + tx] =
            __float2bfloat16(lds[tx][ty * 4 + i]);
}

// ---------------------------------------------------------------------------
// Batched fp32 -> bf16 convert (no transpose), 8 elems/thread, 3 segments.
// ---------------------------------------------------------------------------
__global__ __launch_bounds__(256)
void convert3(const float* s0, bf16* d0, int n0,
              const float* s1, bf16* d1, int n1,
              const float* s2, bf16* d2, int n2)
{
    int i = blockIdx.x * blockDim.x + threadIdx.x;   // 8-elem units
    const float* s; bf16* d;
    if (i < n0) { s = s0; d = d0; }
    else if (i < n0 + n1) { i -= n0; s = s1; d = d1; }
    else if (i < n0 + n1 + n2) { i -= n0 + n1; s = s2; d = d2; }
    else return;
    const float4 a = *(const float4*)(s + (size_t)i * 8);
    const float4 b = *(const float4*)(s + (size_t)i * 8 + 4);
    bf16 t[8];
    t[0] = __float2bfloat16(a.x); t[1] = __float2bfloat16(a.y);
    t[2] = __float2bfloat16(a.z); t[3] = __float2bfloat16(a.w);
    t[4] = __float2bfloat16(b.x); t[5] = __float2bfloat16(b.y);
    t[6] = __float2bfloat16(b.z); t[7] = __float2bfloat16(b.w);
    *(uint4*)(d + (size_t)i * 8) = *(uint4*)t;
}

// ---------------------------------------------------------------------------
// MLA-absorbed sparse attention (round-5 proven). One block per query t.
// ---------------------------------------------------------------------------
__global__ __launch_bounds__(256)
void attn_mla(const bf16* __restrict__ qt,   // [rows][8192] chunk
              const bf16* __restrict__ qr,   // [rows][1024] chunk (rope'd)
              const bf16* __restrict__ xw,   // [2048][1024], ckv = cols 512..1023
              const bf16* __restrict__ kr,   // [2048][64] (rope'd)
              const int*  __restrict__ topk, // [2048][32]
              bf16* __restrict__ U,          // [rows][8192]
              int t0)
{
    __shared__ short ckv_s[32 * 520];
    __shared__ short qt_s[16 * 520];
    __shared__ short kr_s[32 * 72];
    __shared__ short qr_s[16 * 72];
    __shared__ short P_s[4][16 * 40];
    __shared__ int   idx_s[32];

    const int tl   = blockIdx.x;
    const int tg   = t0 + tl;
    const int tid  = threadIdx.x;
    const int wv   = tid >> 6;
    const int lane = tid & 63;
    const int quad = lane >> 4;
    const int l16  = lane & 15;

    if (tid < 32) {
        int j = topk[(size_t)tg * TOPK + tid];
        idx_s[tid] = (j < 0 || j >= T_SEQ) ? 0 : j;
    }
    __syncthreads();

#pragma unroll
    for (int i = 0; i < 8; ++i) {
        const int row = wv * 8 + i;
        const int j = idx_s[row];
        __builtin_amdgcn_global_load_lds(
            (gas_ptr)(xw + (size_t)j * 1024 + 512 + lane * 8),
            (las_ptr)(ckv_s + row * 520), 16, 0, 0);
    }
#pragma unroll
    for (int i = 0; i < 4; ++i) {
        const int seg = wv * 4 + i;
        __builtin_amdgcn_global_load_lds(
            (gas_ptr)(qt + (size_t)tl * 8192 + seg * 512 + lane * 8),
            (las_ptr)(qt_s + seg * 520), 16, 0, 0);
    }
    {
        const int row = tid >> 3, seg = tid & 7;
        const int j = idx_s[row];
        *(uint4*)(kr_s + row * 72 + seg * 8) =
            *(const uint4*)(kr + (size_t)j * RD + seg * 8);
    }
    if (tid < 128) {
        const int head = tid >> 3, seg = tid & 7;
        *(uint4*)(qr_s + head * 72 + seg * 8) =
            *(const uint4*)(qr + (size_t)tl * 1024 + head * 64 + seg * 8);
    }
    __syncthreads();

    f32x4 sc[2] = {};
#pragma unroll
    for (int ks = 0; ks < 16; ++ks) {
        s16x8 a  = *(const s16x8*)(qt_s + l16 * 520 + ks * 32 + quad * 8);
        s16x8 b0 = *(const s16x8*)(ckv_s + l16 * 520 + ks * 32 + quad * 8);
        s16x8 b1 = *(const s16x8*)(ckv_s + (16 + l16) * 520 + ks * 32 + quad * 8);
        sc[0] = __builtin_amdgcn_mfma_f32_16x16x32_bf16(a, b0, sc[0], 0, 0, 0);
        sc[1] = __builtin_amdgcn_mfma_f32_16x16x32_bf16(a, b1, sc[1], 0, 0, 0);
    }
#pragma unroll
    for (int ks = 0; ks < 2; ++ks) {
        s16x8 a  = *(const s16x8*)(qr_s + l16 * 72 + ks * 32 + quad * 8);
        s16x8 b0 = *(const s16x8*)(kr_s + l16 * 72 + ks * 32 + quad * 8);
        s16x8 b1 = *(const s16x8*)(kr_s + (16 + l16) * 72 + ks * 32 + quad * 8);
        sc[0] = __builtin_amdgcn_mfma_f32_16x16x32_bf16(a, b0, sc[0], 0, 0, 0);
        sc[1] = __builtin_amdgcn_mfma_f32_16x16x32_bf16(a, b1, sc[1], 0, 0, 0);
    }

    const float scale = 0.0721687836487032f;   // 1/sqrt(192)
    float inv[4];
    short* pw = P_s[wv];
#pragma unroll
    for (int r = 0; r < 4; ++r) {
        float s0 = sc[0][r] * scale, s1 = sc[1][r] * scale;
        float mx = fmaxf(s0, s1);
#pragma unroll
        for (int off = 1; off < 16; off <<= 1) mx = fmaxf(mx, __shfl_xor(mx, off));
        float p0 = __expf(s0 - mx), p1 = __expf(s1 - mx);
        float l = p0 + p1;
#pragma unroll
        for (int off = 1; off < 16; off <<= 1) l += __shfl_xor(l, off);
        inv[r] = 1.f / l;
        pw[(quad * 4 + r) * 40 + l16]      = __builtin_bit_cast(short, __float2bfloat16(p0));
        pw[(quad * 4 + r) * 40 + 16 + l16] = __builtin_bit_cast(short, __float2bfloat16(p1));
    }

    s16x8 ap = *(const s16x8*)(pw + l16 * 40 + quad * 8);
#pragma unroll
    for (int tt = 0; tt < 8; ++tt) {
        const int n0 = wv * 128 + tt * 16;
        s16x8 b;
#pragma unroll
        for (int j = 0; j < 8; ++j)
            b[j] = ckv_s[(quad * 8 + j) * 520 + n0 + l16];
        f32x4 u = {};
        u = __builtin_amdgcn_mfma_f32_16x16x32_bf16(ap, b, u, 0, 0, 0);
#pragma unroll
        for (int r = 0; r < 4; ++r)
            U[(size_t)tl * 8192 + (quad * 4 + r) * 512 + n0 + l16] =
                __float2bfloat16(u[r] * inv[r]);
    }
}

// ---------------------------------------------------------------------------
extern "C" void kernel_launch(void* const* d_in, const int* in_sizes, int n_in,
                              void* d_out, int out_size, void* d_ws, size_t ws_size,
                              hipStream_t stream)
{
    const float* x    = (const float*)d_in[0];
    const float* Wqd  = (const float*)d_in[1];
    const float* Wqu  = (const float*)d_in[2];
    const float* Wqr  = (const float*)d_in[3];
    const float* Wkvd = (const float*)d_in[4];
    const float* Wku  = (const float*)d_in[5];
    const float* Wvu  = (const float*)d_in[6];
    const float* Wkr  = (const float*)d_in[7];
    const float* Wo   = (const float*)d_in[8];
    const int*   topk = (const int*)d_in[9];
    float* out = (float*)d_out;

    const size_t KB = 1024;
    char* ws = (char*)d_ws;
    const bool flat = ws_size >= (size_t)128000 * KB;
    const int  TCH  = flat ? 2048 : 512;
    const int  NCH  = T_SEQ / TCH;

    size_t oXB, oWxT, oWkrT, oWqub, oWkub, oWqrT, oWvuT, oWcombT, oXW, oKR,
           oQR, oO, oWoT, oQT, oU;
    if (flat) {
        oXB = 0;        oWxT = 8192;   oWkrT = 12288; oWqub = 12544;
        oWkub = 14592;  oWqrT = 16640; oWvuT = 17664; oWcombT = 19712;
        oXW = 27904;    oKR = 32000;   oQR = 32256;   oO = 36352;
        oWoT = 44544;   oQT = 52736;   oU = 85504;
    } else {
        oXB = 0;        oWcombT = 0;   oWoT = 0;       // phase-aliased [0,8M)
        oWvuT = 8192;   oQR = 10240;   oKR = 11264;   oXW = 11520;
        oO = 15616;     oWxT = 15616;  oWkrT = 19712;
        oQT = 23808;    oWqub = 23808; oWkub = 25856;
        oU = 32000;     oWqrT = 40192;
    }
    bf16* xb     = (bf16*)(ws + oXB * KB);
    bf16* WxT    = (bf16*)(ws + oWxT * KB);
    bf16* WkrT   = (bf16*)(ws + oWkrT * KB);
    bf16* Wqub   = (bf16*)(ws + oWqub * KB);
    bf16* Wkub   = (bf16*)(ws + oWkub * KB);
    bf16* WqrT   = (bf16*)(ws + oWqrT * KB);
    bf16* WvuT   = (bf16*)(ws + oWvuT * KB);
    bf16* WcombT = (bf16*)(ws + oWcombT * KB);
    bf16* xw     = (bf16*)(ws + oXW * KB);
    bf16* kr     = (bf16*)(ws + oKR * KB);
    bf16* qrC    = (bf16*)(ws + oQR * KB);
    bf16* o      = (bf16*)(ws + oO * KB);
    bf16* WoT    = (bf16*)(ws + oWoT * KB);
    bf16* qtC    = (bf16*)(ws + oQT * KB);
    bf16* uC     = (bf16*)(ws + oU * KB);

    dim3 blk(256);

    // Phase A: converts (x, Wqu, Wku) + transposes (Wqd,Wkvd,Wkr,Wqr,Wvu[,Wo])
    {
        int n0 = T_SEQ * DIM / 8, n1 = LAT * DIM / 8, n2 = LAT * DIM / 8;
        convert3<<<(n0 + n1 + n2 + 255) / 256, blk, 0, stream>>>(
            x, xb, n0, Wqu, Wqub, n1, Wku, Wkub, n2);
        TPack p;
        p.d[0] = { Wqd,  WxT,                   DIM, LAT,  (DIM/32)*(LAT/32),  LAT/32 };
        p.d[1] = { Wkvd, WxT + (size_t)LAT*DIM, DIM, LAT,  (DIM/32)*(LAT/32),  LAT/32 };
        p.d[2] = { Wkr,  WkrT,                  DIM, RD,   (DIM/32)*(RD/32),   RD/32  };
        p.d[3] = { Wqr,  WqrT,                  LAT, 1024, (LAT/32)*(1024/32), 1024/32 };
        p.d[4] = { Wvu,  WvuT,                  LAT, DIM,  (LAT/32)*(DIM/32),  DIM/32 };
        p.n = 5;
        int tot = p.d[0].tiles + p.d[1].tiles + p.d[2].tiles + p.d[3].tiles + p.d[4].tiles;
        if (flat) {
            p.d[5] = { Wo, WoT, DIM, DIM, (DIM/32)*(DIM/32), DIM/32 };
            p.n = 6; tot += p.d[5].tiles;
        }
        transpose_batch<<<tot, blk, 0, stream>>>(p);
    }

    // Phase B (grouped, 128x64 tiles, BK=64):
    //   xw = xb@WxT^T (256) | WcombT_h = Wku_h@Wqu_h^T (512) | kr (16, rope)
    {
        GPack gp;
        gp.g[0] = { xb,   WxT,  xw,     DIM, DIM, DIM, 1024, 1024/64, T_SEQ/128, 1,
                    0, 0, 0, (1024/64)*(T_SEQ/128), 0, 1024, 0 };
        gp.g[1] = { Wkub, Wqub, WcombT, 128, DIM, DIM, LAT,  LAT/64,  LAT/128,  NH,
                    128, 128, (long)LAT*LAT, (LAT/64)*(LAT/128)*NH, 0, LAT, 0 };
        gp.g[2] = { xb,   WkrT, kr,     DIM, DIM, DIM, RD,   1,       T_SEQ/128, 1,
                    0, 0, 0, T_SEQ/128, 1 /*rope*/, RD, 0 };
        gp.n = 3;
        int tot = gp.g[0].tiles + gp.g[1].tiles + gp.g[2].tiles;
        gemm_group64<<<tot, blk, 0, stream>>>(gp);
    }

    // Phase C/D per chunk: [qt | qr(+rope)] grouped (128-tiles, BK=64),
    // attention, U-projection (64-tiles)
    for (int c = 0; c < NCH; ++c) {
        const int t0 = c * TCH;
        bf16* qt = flat ? qtC + (size_t)t0 * 8192 : qtC;
        bf16* qr = flat ? qrC + (size_t)t0 * 1024 : qrC;
        bf16* U  = flat ? uC  + (size_t)t0 * 8192 : uC;
        const bf16* xwc = xw + (size_t)t0 * 1024;

        {
            GPack gp;
            gp.g[0] = { xwc, WcombT, qt, LAT, 1024, LAT, 8192, 8192/128, TCH/128, 1,
                        0, 0, 0, (8192/128)*(TCH/128), 0, 8192, 0 };
            gp.g[1] = { xwc, WqrT,   qr, LAT, 1024, LAT, 1024, 1024/128, TCH/128, 1,
                        0, 0, 0, (1024/128)*(TCH/128), 1 /*rope*/, 1024, t0 };
            gp.n = 2;
            gemm_group<<<gp.g[0].tiles + gp.g[1].tiles, blk, 0, stream>>>(gp);
        }
        attn_mla<<<TCH, blk, 0, stream>>>(qt, qr, xw, kr, topk, U, t0);
        {
            GPack gp;
            gp.g[0] = { U, WvuT, o + (size_t)t0 * DIM, LAT, 8192, LAT, DIM,
                        2, TCH/128, NH, 512, (long)128*LAT, 128,
                        2*(TCH/128)*NH, 0, 128, 0 };
            gp.n = 1;
            gemm_group64<<<gp.g[0].tiles, blk, 0, stream>>>(gp);
        }
    }

    // Phase E: out = o @ WoT^T (fp32), 128x64 tiles BK=64 -> 512 blocks
    if (!flat) {
        TPack p;
        p.d[0] = { Wo, WoT, DIM, DIM, (DIM/32)*(DIM/32), DIM/32 };
        p.n = 1;
        transpose_batch<<<p.d[0].tiles, blk, 0, stream>>>(p);
    }
    {
        GPack gp;
        gp.g[0] = { o, WoT, (bf16*)out, DIM, DIM, DIM, DIM,
                    DIM/64, T_SEQ/128, 1, 0, 0, 0,
                    (DIM/64)*(T_SEQ/128), 4 /*fp32*/, DIM, 0 };
        gp.n = 1;
        gemm_group64<<<gp.g[0].tiles, blk, 0, stream>>>(gp);
    }
}

// Round 9
// 260.312 us; speedup vs baseline: 2.1654x; 1.0784x over previous
//
#include <hip/hip_runtime.h>
#include <hip/hip_bf16.h>
#include <math.h>

typedef __hip_bfloat16 bf16;
typedef __attribute__((ext_vector_type(4))) float f32x4;
typedef __attribute__((ext_vector_type(8))) short s16x8;

#define T_SEQ 2048
#define DIM   2048
#define NH    16
#define LAT   512
#define RD    64
#define TOPK  32

typedef const __attribute__((address_space(1))) void* gas_ptr;
typedef __attribute__((address_space(3))) void* las_ptr;

// ---------------------------------------------------------------------------
// Grouped GEMM descriptors.
// flags: 1 = RoPE epilogue (rotate col pairs (c, c+32), position = t0+row),
//        2 = column guard (col < N), 4 = fp32 output (C reinterpreted float*).
// ---------------------------------------------------------------------------
struct GGroup {
    const bf16* A; const bf16* BT; bf16* C;
    int K, lda, ldb, ldc;
    int tx, ty, nz;          // tiles in n, m, z
    long aZ, bZ, cZ;         // element strides per z
    int tiles;               // tx*ty*nz
    int flags, N, t0;
};
struct GPack { GGroup g[4]; int n; };

// BK=64 LDS bank-conflict fix: XOR seg swizzle. LDS row stride = 128 B = 32
// banks, so unswizzled b128 fragment reads put 16 lanes on one 4-bank group
// (measured: 7.1e6 conflicts, r8). Staging permutes 16B segs by seg^(row&7)
// via the GLOBAL address (lane->LDS map of global_load_lds is fixed); reads
// un-permute. Bank census: exactly 8 lanes/group -> minimal 8-cy b128.

// ---------------------------------------------------------------------------
// 128x128-tile grouped GEMM, BK=64: 4 waves, wave = 64x64 (4x4 frags).
// ---------------------------------------------------------------------------
__global__ __launch_bounds__(256)
void gemm_group(GPack gp)
{
    int b = blockIdx.x;
    int gi = 0;
    while (gi < gp.n - 1 && b >= gp.g[gi].tiles) { b -= gp.g[gi].tiles; ++gi; }
    const GGroup g = gp.g[gi];

    const int per_z = g.tx * g.ty;
    const int z   = b / per_z;
    const int rem = b - z * per_z;
    const int bx  = rem % g.tx;
    const int by  = rem / g.tx;

    const bf16* A  = g.A  + (size_t)z * g.aZ;
    const bf16* BT = g.BT + (size_t)z * g.bZ;
    bf16*       C  = g.C  + (size_t)z * g.cZ;

    __shared__ bf16 aL[128 * 64];
    __shared__ bf16 bL[128 * 64];

    const int tid  = threadIdx.x;
    const int wave = tid >> 6;
    const int lane = tid & 63;
    const int quad = lane >> 4;
    const int l16  = lane & 15;

    const int tile_m = by * 128;
    const int tile_n = bx * 128;
    const int wrow = (wave >> 1) * 64;
    const int wcol = (wave & 1) * 64;

    const int lrow = lane >> 3;                      // 0..7
    const int lke  = (((lane & 7) ^ lrow) * 8);      // XOR-swizzled seg
    const int sw   = l16 & 7;

    f32x4 acc[4][4] = {};

    for (int k0 = 0; k0 < g.K; k0 += 64) {
#pragma unroll
        for (int p = 0; p < 4; ++p) {
            const int R = (wave * 4 + p) * 8;
            const bf16* src = A + (size_t)(tile_m + R + lrow) * g.lda + k0 + lke;
            __builtin_amdgcn_global_load_lds((gas_ptr)src, (las_ptr)(aL + R * 64), 16, 0, 0);
        }
#pragma unroll
        for (int p = 0; p < 4; ++p) {
            const int R = (wave * 4 + p) * 8;
            const bf16* src = BT + (size_t)(tile_n + R + lrow) * g.ldb + k0 + lke;
            __builtin_amdgcn_global_load_lds((gas_ptr)src, (las_ptr)(bL + R * 64), 16, 0, 0);
        }
        __syncthreads();

#pragma unroll
        for (int ks = 0; ks < 2; ++ks) {
            s16x8 af[4], bfr[4];
#pragma unroll
            for (int i = 0; i < 4; ++i)
                af[i] = *(const s16x8*)(&aL[(wrow + i * 16 + l16) * 64 +
                                            (((ks * 4 + quad) ^ sw) * 8)]);
#pragma unroll
            for (int j = 0; j < 4; ++j)
                bfr[j] = *(const s16x8*)(&bL[(wcol + j * 16 + l16) * 64 +
                                             (((ks * 4 + quad) ^ sw) * 8)]);

#pragma unroll
            for (int i = 0; i < 4; ++i)
#pragma unroll
                for (int j = 0; j < 4; ++j)
                    acc[i][j] = __builtin_amdgcn_mfma_f32_16x16x32_bf16(
                        af[i], bfr[j], acc[i][j], 0, 0, 0);
        }
        __syncthreads();
    }

    // D mapping: col = lane&15, row = (lane>>4)*4 + reg   [m89-verified]
    if (g.flags & 1) {
#pragma unroll
        for (int jp = 0; jp < 2; ++jp) {
            const int colL = tile_n + wcol + jp * 16 + l16;
            if ((g.flags & 2) && colL >= g.N) continue;
            const float fr = powf(10000.f, -(float)(jp * 16 + l16) / 32.f);
#pragma unroll
            for (int i = 0; i < 4; ++i) {
#pragma unroll
                for (int r = 0; r < 4; ++r) {
                    const int row = tile_m + wrow + i * 16 + quad * 4 + r;
                    float sv, cv;
                    sincosf((float)(g.t0 + row) * fr, &sv, &cv);
                    const float x0 = acc[i][jp][r];
                    const float x1 = acc[i][jp + 2][r];
                    C[(size_t)row * g.ldc + colL]      = __float2bfloat16(x0 * cv - x1 * sv);
                    C[(size_t)row * g.ldc + colL + 32] = __float2bfloat16(x1 * cv + x0 * sv);
                }
            }
        }
    } else {
#pragma unroll
        for (int j = 0; j < 4; ++j) {
            const int col = tile_n + wcol + j * 16 + l16;
            if ((g.flags & 2) && col >= g.N) continue;
#pragma unroll
            for (int i = 0; i < 4; ++i)
#pragma unroll
                for (int r = 0; r < 4; ++r) {
                    const int row = tile_m + wrow + i * 16 + quad * 4 + r;
                    C[(size_t)row * g.ldc + col] = __float2bfloat16(acc[i][j][r]);
                }
        }
    }
}

// ---------------------------------------------------------------------------
// 128x64-tile grouped GEMM, BK=64: 4 waves, wave = 32 rows x 64 cols (2x4).
// ---------------------------------------------------------------------------
__global__ __launch_bounds__(256)
void gemm_group64(GPack gp)
{
    int b = blockIdx.x;
    int gi = 0;
    while (gi < gp.n - 1 && b >= gp.g[gi].tiles) { b -= gp.g[gi].tiles; ++gi; }
    const GGroup g = gp.g[gi];

    const int per_z = g.tx * g.ty;
    const int z   = b / per_z;
    const int rem = b - z * per_z;
    const int bx  = rem % g.tx;
    const int by  = rem / g.tx;

    const bf16* A  = g.A  + (size_t)z * g.aZ;
    const bf16* BT = g.BT + (size_t)z * g.bZ;
    bf16*       C  = g.C  + (size_t)z * g.cZ;

    __shared__ bf16 aL[128 * 64];
    __shared__ bf16 bL[64 * 64];

    const int tid  = threadIdx.x;
    const int wave = tid >> 6;
    const int lane = tid & 63;
    const int quad = lane >> 4;
    const int l16  = lane & 15;

    const int tile_m = by * 128;
    const int tile_n = bx * 64;
    const int wrow = wave * 32;

    const int lrow = lane >> 3;
    const int lke  = (((lane & 7) ^ lrow) * 8);      // XOR-swizzled seg
    const int sw   = l16 & 7;

    f32x4 acc[2][4] = {};

    for (int k0 = 0; k0 < g.K; k0 += 64) {
#pragma unroll
        for (int p = 0; p < 4; ++p) {
            const int R = (wave * 4 + p) * 8;
            const bf16* src = A + (size_t)(tile_m + R + lrow) * g.lda + k0 + lke;
            __builtin_amdgcn_global_load_lds((gas_ptr)src, (las_ptr)(aL + R * 64), 16, 0, 0);
        }
#pragma unroll
        for (int p = 0; p < 2; ++p) {
            const int R = (wave * 2 + p) * 8;
            const bf16* src = BT + (size_t)(tile_n + R + lrow) * g.ldb + k0 + lke;
            __builtin_amdgcn_global_load_lds((gas_ptr)src, (las_ptr)(bL + R * 64), 16, 0, 0);
        }
        __syncthreads();

#pragma unroll
        for (int ks = 0; ks < 2; ++ks) {
            s16x8 af[2], bfr[4];
#pragma unroll
            for (int i = 0; i < 2; ++i)
                af[i] = *(const s16x8*)(&aL[(wrow + i * 16 + l16) * 64 +
                                            (((ks * 4 + quad) ^ sw) * 8)]);
#pragma unroll
            for (int j = 0; j < 4; ++j)
                bfr[j] = *(const s16x8*)(&bL[(j * 16 + l16) * 64 +
                                             (((ks * 4 + quad) ^ sw) * 8)]);

#pragma unroll
            for (int i = 0; i < 2; ++i)
#pragma unroll
                for (int j = 0; j < 4; ++j)
                    acc[i][j] = __builtin_amdgcn_mfma_f32_16x16x32_bf16(
                        af[i], bfr[j], acc[i][j], 0, 0, 0);
        }
        __syncthreads();
    }

    if (g.flags & 1) {
#pragma unroll
        for (int jp = 0; jp < 2; ++jp) {
            const int colL = tile_n + jp * 16 + l16;
            if ((g.flags & 2) && colL >= g.N) continue;
            const float fr = powf(10000.f, -(float)(jp * 16 + l16) / 32.f);
#pragma unroll
            for (int i = 0; i < 2; ++i) {
#pragma unroll
                for (int r = 0; r < 4; ++r) {
                    const int row = tile_m + wrow + i * 16 + quad * 4 + r;
                    float sv, cv;
                    sincosf((float)(g.t0 + row) * fr, &sv, &cv);
                    const float x0 = acc[i][jp][r];
                    const float x1 = acc[i][jp + 2][r];
                    C[(size_t)row * g.ldc + colL]      = __float2bfloat16(x0 * cv - x1 * sv);
                    C[(size_t)row * g.ldc + colL + 32] = __float2bfloat16(x1 * cv + x0 * sv);
                }
            }
        }
    } else if (g.flags & 4) {
        float* Cf = (float*)C;
#pragma unroll
        for (int j = 0; j < 4; ++j) {
            const int col = tile_n + j * 16 + l16;
#pragma unroll
            for (int i = 0; i < 2; ++i)
#pragma unroll
                for (int r = 0; r < 4; ++r) {
                    const int row = tile_m + wrow + i * 16 + quad * 4 + r;
                    Cf[(size_t)row * g.ldc + col] = acc[i][j][r];
                }
        }
    } else {
#pragma unroll
        for (int j = 0; j < 4; ++j) {
            const int col = tile_n + j * 16 + l16;
            if ((g.flags & 2) && col >= g.N) continue;
#pragma unroll
            for (int i = 0; i < 2; ++i)
#pragma unroll
                for (int r = 0; r < 4; ++r) {
                    const int row = tile_m + wrow + i * 16 + quad * 4 + r;
                    C[(size_t)row * g.ldc + col] = __float2bfloat16(acc[i][j][r]);
                }
        }
    }
}

// ---------------------------------------------------------------------------
// Batched transpose+convert: fp32 (R x C) -> bf16 (C x R), 32x32 LDS tiles.
// ---------------------------------------------------------------------------
struct TDesc { const float* src; bf16* dst; int R; int C; int tiles; int ctiles; };
struct TPack { TDesc d[6]; int n; };

__global__ __launch_bounds__(256)
void transpose_batch(TPack p)
{
    int b = blockIdx.x;
    int mi = 0;
    while (mi < p.n - 1 && b >= p.d[mi].tiles) { b -= p.d[mi].tiles; ++mi; }
    const TDesc d = p.d[mi];
    const int tr = b / d.ctiles, tc = b % d.ctiles;
    const int r0 = tr * 32, c0 = tc * 32;

    __shared__ float lds[32][33];
    const int tx = threadIdx.x & 31, ty = threadIdx.x >> 5;
#pragma unroll
    for (int i = 0; i < 4; ++i)
        lds[ty * 4 + i][tx] = d.src[(size_t)(r0 + ty * 4 + i) * d.C + c0 + tx];
    __syncthreads();
#pragma unroll
    for (int i = 0; i < 4; ++i)
        d.dst[(size_t)(c0 + ty * 4 + i) * d.R + r0 + tx] =
            __float2bfloat16(lds[tx][ty * 4 + i]);
}

// ---------------------------------------------------------------------------
// Batched fp32 -> bf16 convert (no transpose), 8 elems/thread, 3 segments.
// ---------------------------------------------------------------------------
__global__ __launch_bounds__(256)
void convert3(const float* s0, bf16* d0, int n0,
              const float* s1, bf16* d1, int n1,
              const float* s2, bf16* d2, int n2)
{
    int i = blockIdx.x * blockDim.x + threadIdx.x;   // 8-elem units
    const float* s; bf16* d;
    if (i < n0) { s = s0; d = d0; }
    else if (i < n0 + n1) { i -= n0; s = s1; d = d1; }
    else if (i < n0 + n1 + n2) { i -= n0 + n1; s = s2; d = d2; }
    else return;
    const float4 a = *(const float4*)(s + (size_t)i * 8);
    const float4 b = *(const float4*)(s + (size_t)i * 8 + 4);
    bf16 t[8];
    t[0] = __float2bfloat16(a.x); t[1] = __float2bfloat16(a.y);
    t[2] = __float2bfloat16(a.z); t[3] = __float2bfloat16(a.w);
    t[4] = __float2bfloat16(b.x); t[5] = __float2bfloat16(b.y);
    t[6] = __float2bfloat16(b.z); t[7] = __float2bfloat16(b.w);
    *(uint4*)(d + (size_t)i * 8) = *(uint4*)t;
}

// ---------------------------------------------------------------------------
// MLA-absorbed sparse attention (round-5 proven). One block per query t.
// ---------------------------------------------------------------------------
__global__ __launch_bounds__(256)
void attn_mla(const bf16* __restrict__ qt,   // [rows][8192] chunk
              const bf16* __restrict__ qr,   // [rows][1024] chunk (rope'd)
              const bf16* __restrict__ xw,   // [2048][1024], ckv = cols 512..1023
              const bf16* __restrict__ kr,   // [2048][64] (rope'd)
              const int*  __restrict__ topk, // [2048][32]
              bf16* __restrict__ U,          // [rows][8192]
              int t0)
{
    __shared__ short ckv_s[32 * 520];
    __shared__ short qt_s[16 * 520];
    __shared__ short kr_s[32 * 72];
    __shared__ short qr_s[16 * 72];
    __shared__ short P_s[4][16 * 40];
    __shared__ int   idx_s[32];

    const int tl   = blockIdx.x;
    const int tg   = t0 + tl;
    const int tid  = threadIdx.x;
    const int wv   = tid >> 6;
    const int lane = tid & 63;
    const int quad = lane >> 4;
    const int l16  = lane & 15;

    if (tid < 32) {
        int j = topk[(size_t)tg * TOPK + tid];
        idx_s[tid] = (j < 0 || j >= T_SEQ) ? 0 : j;
    }
    __syncthreads();

#pragma unroll
    for (int i = 0; i < 8; ++i) {
        const int row = wv * 8 + i;
        const int j = idx_s[row];
        __builtin_amdgcn_global_load_lds(
            (gas_ptr)(xw + (size_t)j * 1024 + 512 + lane * 8),
            (las_ptr)(ckv_s + row * 520), 16, 0, 0);
    }
#pragma unroll
    for (int i = 0; i < 4; ++i) {
        const int seg = wv * 4 + i;
        __builtin_amdgcn_global_load_lds(
            (gas_ptr)(qt + (size_t)tl * 8192 + seg * 512 + lane * 8),
            (las_ptr)(qt_s + seg * 520), 16, 0, 0);
    }
    {
        const int row = tid >> 3, seg = tid & 7;
        const int j = idx_s[row];
        *(uint4*)(kr_s + row * 72 + seg * 8) =
            *(const uint4*)(kr + (size_t)j * RD + seg * 8);
    }
    if (tid < 128) {
        const int head = tid >> 3, seg = tid & 7;
        *(uint4*)(qr_s + head * 72 + seg * 8) =
            *(const uint4*)(qr + (size_t)tl * 1024 + head * 64 + seg * 8);
    }
    __syncthreads();

    f32x4 sc[2] = {};
#pragma unroll
    for (int ks = 0; ks < 16; ++ks) {
        s16x8 a  = *(const s16x8*)(qt_s + l16 * 520 + ks * 32 + quad * 8);
        s16x8 b0 = *(const s16x8*)(ckv_s + l16 * 520 + ks * 32 + quad * 8);
        s16x8 b1 = *(const s16x8*)(ckv_s + (16 + l16) * 520 + ks * 32 + quad * 8);
        sc[0] = __builtin_amdgcn_mfma_f32_16x16x32_bf16(a, b0, sc[0], 0, 0, 0);
        sc[1] = __builtin_amdgcn_mfma_f32_16x16x32_bf16(a, b1, sc[1], 0, 0, 0);
    }
#pragma unroll
    for (int ks = 0; ks < 2; ++ks) {
        s16x8 a  = *(const s16x8*)(qr_s + l16 * 72 + ks * 32 + quad * 8);
        s16x8 b0 = *(const s16x8*)(kr_s + l16 * 72 + ks * 32 + quad * 8);
        s16x8 b1 = *(const s16x8*)(kr_s + (16 + l16) * 72 + ks * 32 + quad * 8);
        sc[0] = __builtin_amdgcn_mfma_f32_16x16x32_bf16(a, b0, sc[0], 0, 0, 0);
        sc[1] = __builtin_amdgcn_mfma_f32_16x16x32_bf16(a, b1, sc[1], 0, 0, 0);
    }

    const float scale = 0.0721687836487032f;   // 1/sqrt(192)
    float inv[4];
    short* pw = P_s[wv];
#pragma unroll
    for (int r = 0; r < 4; ++r) {
        float s0 = sc[0][r] * scale, s1 = sc[1][r] * scale;
        float mx = fmaxf(s0, s1);
#pragma unroll
        for (int off = 1; off < 16; off <<= 1) mx = fmaxf(mx, __shfl_xor(mx, off));
        float p0 = __expf(s0 - mx), p1 = __expf(s1 - mx);
        float l = p0 + p1;
#pragma unroll
        for (int off = 1; off < 16; off <<= 1) l += __shfl_xor(l, off);
        inv[r] = 1.f / l;
        pw[(quad * 4 + r) * 40 + l16]      = __builtin_bit_cast(short, __float2bfloat16(p0));
        pw[(quad * 4 + r) * 40 + 16 + l16] = __builtin_bit_cast(short, __float2bfloat16(p1));
    }

    s16x8 ap = *(const s16x8*)(pw + l16 * 40 + quad * 8);
#pragma unroll
    for (int tt = 0; tt < 8; ++tt) {
        const int n0 = wv * 128 + tt * 16;
        s16x8 b;
#pragma unroll
        for (int j = 0; j < 8; ++j)
            b[j] = ckv_s[(quad * 8 + j) * 520 + n0 + l16];
        f32x4 u = {};
        u = __builtin_amdgcn_mfma_f32_16x16x32_bf16(ap, b, u, 0, 0, 0);
#pragma unroll
        for (int r = 0; r < 4; ++r)
            U[(size_t)tl * 8192 + (quad * 4 + r) * 512 + n0 + l16] =
                __float2bfloat16(u[r] * inv[r]);
    }
}

// ---------------------------------------------------------------------------
extern "C" void kernel_launch(void* const* d_in, const int* in_sizes, int n_in,
                              void* d_out, int out_size, void* d_ws, size_t ws_size,
                              hipStream_t stream)
{
    const float* x    = (const float*)d_in[0];
    const float* Wqd  = (const float*)d_in[1];
    const float* Wqu  = (const float*)d_in[2];
    const float* Wqr  = (const float*)d_in[3];
    const float* Wkvd = (const float*)d_in[4];
    const float* Wku  = (const float*)d_in[5];
    const float* Wvu  = (const float*)d_in[6];
    const float* Wkr  = (const float*)d_in[7];
    const float* Wo   = (const float*)d_in[8];
    const int*   topk = (const int*)d_in[9];
    float* out = (float*)d_out;

    const size_t KB = 1024;
    char* ws = (char*)d_ws;
    const bool flat = ws_size >= (size_t)128000 * KB;
    const int  TCH  = flat ? 2048 : 512;
    const int  NCH  = T_SEQ / TCH;

    size_t oXB, oWxT, oWkrT, oWqub, oWkub, oWqrT, oWvuT, oWcombT, oXW, oKR,
           oQR, oO, oWoT, oQT, oU;
    if (flat) {
        oXB = 0;        oWxT = 8192;   oWkrT = 12288; oWqub = 12544;
        oWkub = 14592;  oWqrT = 16640; oWvuT = 17664; oWcombT = 19712;
        oXW = 27904;    oKR = 32000;   oQR = 32256;   oO = 36352;
        oWoT = 44544;   oQT = 52736;   oU = 85504;
    } else {
        oXB = 0;        oWcombT = 0;   oWoT = 0;       // phase-aliased [0,8M)
        oWvuT = 8192;   oQR = 10240;   oKR = 11264;   oXW = 11520;
        oO = 15616;     oWxT = 15616;  oWkrT = 19712;
        oQT = 23808;    oWqub = 23808; oWkub = 25856;
        oU = 32000;     oWqrT = 40192;
    }
    bf16* xb     = (bf16*)(ws + oXB * KB);
    bf16* WxT    = (bf16*)(ws + oWxT * KB);
    bf16* WkrT   = (bf16*)(ws + oWkrT * KB);
    bf16* Wqub   = (bf16*)(ws + oWqub * KB);
    bf16* Wkub   = (bf16*)(ws + oWkub * KB);
    bf16* WqrT   = (bf16*)(ws + oWqrT * KB);
    bf16* WvuT   = (bf16*)(ws + oWvuT * KB);
    bf16* WcombT = (bf16*)(ws + oWcombT * KB);
    bf16* xw     = (bf16*)(ws + oXW * KB);
    bf16* kr     = (bf16*)(ws + oKR * KB);
    bf16* qrC    = (bf16*)(ws + oQR * KB);
    bf16* o      = (bf16*)(ws + oO * KB);
    bf16* WoT    = (bf16*)(ws + oWoT * KB);
    bf16* qtC    = (bf16*)(ws + oQT * KB);
    bf16* uC     = (bf16*)(ws + oU * KB);

    dim3 blk(256);

    // Phase A: converts (x, Wqu, Wku) + transposes (Wqd,Wkvd,Wkr,Wqr,Wvu[,Wo])
    {
        int n0 = T_SEQ * DIM / 8, n1 = LAT * DIM / 8, n2 = LAT * DIM / 8;
        convert3<<<(n0 + n1 + n2 + 255) / 256, blk, 0, stream>>>(
            x, xb, n0, Wqu, Wqub, n1, Wku, Wkub, n2);
        TPack p;
        p.d[0] = { Wqd,  WxT,                   DIM, LAT,  (DIM/32)*(LAT/32),  LAT/32 };
        p.d[1] = { Wkvd, WxT + (size_t)LAT*DIM, DIM, LAT,  (DIM/32)*(LAT/32),  LAT/32 };
        p.d[2] = { Wkr,  WkrT,                  DIM, RD,   (DIM/32)*(RD/32),   RD/32  };
        p.d[3] = { Wqr,  WqrT,                  LAT, 1024, (LAT/32)*(1024/32), 1024/32 };
        p.d[4] = { Wvu,  WvuT,                  LAT, DIM,  (LAT/32)*(DIM/32),  DIM/32 };
        p.n = 5;
        int tot = p.d[0].tiles + p.d[1].tiles + p.d[2].tiles + p.d[3].tiles + p.d[4].tiles;
        if (flat) {
            p.d[5] = { Wo, WoT, DIM, DIM, (DIM/32)*(DIM/32), DIM/32 };
            p.n = 6; tot += p.d[5].tiles;
        }
        transpose_batch<<<tot, blk, 0, stream>>>(p);
    }

    // Phase B (grouped, 128x64 tiles, BK=64):
    //   xw = xb@WxT^T (256) | WcombT_h = Wku_h@Wqu_h^T (512) | kr (16, rope)
    {
        GPack gp;
        gp.g[0] = { xb,   WxT,  xw,     DIM, DIM, DIM, 1024, 1024/64, T_SEQ/128, 1,
                    0, 0, 0, (1024/64)*(T_SEQ/128), 0, 1024, 0 };
        gp.g[1] = { Wkub, Wqub, WcombT, 128, DIM, DIM, LAT,  LAT/64,  LAT/128,  NH,
                    128, 128, (long)LAT*LAT, (LAT/64)*(LAT/128)*NH, 0, LAT, 0 };
        gp.g[2] = { xb,   WkrT, kr,     DIM, DIM, DIM, RD,   1,       T_SEQ/128, 1,
                    0, 0, 0, T_SEQ/128, 1 /*rope*/, RD, 0 };
        gp.n = 3;
        int tot = gp.g[0].tiles + gp.g[1].tiles + gp.g[2].tiles;
        gemm_group64<<<tot, blk, 0, stream>>>(gp);
    }

    // Phase C/D per chunk: [qt | qr(+rope)] grouped (128-tiles, BK=64),
    // attention, U-projection (64-tiles)
    for (int c = 0; c < NCH; ++c) {
        const int t0 = c * TCH;
        bf16* qt = flat ? qtC + (size_t)t0 * 8192 : qtC;
        bf16* qr = flat ? qrC + (size_t)t0 * 1024 : qrC;
        bf16* U  = flat ? uC  + (size_t)t0 * 8192 : uC;
        const bf16* xwc = xw + (size_t)t0 * 1024;

        {
            GPack gp;
            gp.g[0] = { xwc, WcombT, qt, LAT, 1024, LAT, 8192, 8192/128, TCH/128, 1,
                        0, 0, 0, (8192/128)*(TCH/128), 0, 8192, 0 };
            gp.g[1] = { xwc, WqrT,   qr, LAT, 1024, LAT, 1024, 1024/128, TCH/128, 1,
                        0, 0, 0, (1024/128)*(TCH/128), 1 /*rope*/, 1024, t0 };
            gp.n = 2;
            gemm_group<<<gp.g[0].tiles + gp.g[1].tiles, blk, 0, stream>>>(gp);
        }
        attn_mla<<<TCH, blk, 0, stream>>>(qt, qr, xw, kr, topk, U, t0);
        {
            GPack gp;
            gp.g[0] = { U, WvuT, o + (size_t)t0 * DIM, LAT, 8192, LAT, DIM,
                        2, TCH/128, NH, 512, (long)128*LAT, 128,
                        2*(TCH/128)*NH, 0, 128, 0 };
            gp.n = 1;
            gemm_group64<<<gp.g[0].tiles, blk, 0, stream>>>(gp);
        }
    }

    // Phase E: out = o @ WoT^T (fp32), 128x64 tiles BK=64 -> 512 blocks
    if (!flat) {
        TPack p;
        p.d[0] = { Wo, WoT, DIM, DIM, (DIM/32)*(DIM/32), DIM/32 };
        p.n = 1;
        transpose_batch<<<p.d[0].tiles, blk, 0, stream>>>(p);
    }
    {
        GPack gp;
        gp.g[0] = { o, WoT, (bf16*)out, DIM, DIM, DIM, DIM,
                    DIM/64, T_SEQ/128, 1, 0, 0, 0,
                    (DIM/64)*(T_SEQ/128), 4 /*fp32*/, DIM, 0 };
        gp.n = 1;
        gemm_group64<<<gp.g[0].tiles, blk, 0, stream>>>(gp);
    }
}

// Round 10
// 246.555 us; speedup vs baseline: 2.2862x; 1.0558x over previous
//
#include <hip/hip_runtime.h>
#include <hip/hip_bf16.h>
#include <math.h>

typedef __hip_bfloat16 bf16;
typedef __attribute__((ext_vector_type(4))) float f32x4;
typedef __attribute__((ext_vector_type(8))) short s16x8;

#define T_SEQ 2048
#define DIM   2048
#define NH    16
#define LAT   512
#define RD    64
#define TOPK  32

typedef const __attribute__((address_space(1))) void* gas_ptr;
typedef __attribute__((address_space(3))) void* las_ptr;

// ---------------------------------------------------------------------------
// Grouped GEMM descriptors.
// flags: 1 = RoPE epilogue (rotate col pairs (c, c+32), position = t0+row),
//        2 = column guard (col < N), 4 = fp32 output (C reinterpreted float*).
// ---------------------------------------------------------------------------
struct GGroup {
    const bf16* A; const bf16* BT; bf16* C;
    int K, lda, ldb, ldc;
    int tx, ty, nz;          // tiles in n, m, z
    long aZ, bZ, cZ;         // element strides per z
    int tiles;               // tx*ty*nz
    int flags, N, t0;
};
struct GPack { GGroup g[4]; int n; };

// ---------------------------------------------------------------------------
// MT x 64-tile grouped GEMM, BK=64, MT in {64,128}. 4 waves, wave = (MT/4)
// rows x 64 cols. XOR seg swizzle (r8: stride 128B = 32 banks; staging
// permutes 16B segs by seg^(row&7) via the GLOBAL address, reads un-permute
// -> 8 lanes/4-bank-group, conflict-free b128; verified r9: conflicts -> 0).
// ---------------------------------------------------------------------------
template<int MT>
__global__ __launch_bounds__(256)
void gemm_group64(GPack gp)
{
    constexpr int MI = MT / 64;          // i-frags per wave (1 or 2)
    int b = blockIdx.x;
    int gi = 0;
    while (gi < gp.n - 1 && b >= gp.g[gi].tiles) { b -= gp.g[gi].tiles; ++gi; }
    const GGroup g = gp.g[gi];

    const int per_z = g.tx * g.ty;
    const int z   = b / per_z;
    const int rem = b - z * per_z;
    const int bx  = rem % g.tx;
    const int by  = rem / g.tx;

    const bf16* A  = g.A  + (size_t)z * g.aZ;
    const bf16* BT = g.BT + (size_t)z * g.bZ;
    bf16*       C  = g.C  + (size_t)z * g.cZ;

    __shared__ bf16 aL[MT * 64];
    __shared__ bf16 bL[64 * 64];

    const int tid  = threadIdx.x;
    const int wave = tid >> 6;
    const int lane = tid & 63;
    const int quad = lane >> 4;
    const int l16  = lane & 15;

    const int tile_m = by * MT;
    const int tile_n = bx * 64;
    const int wrow = wave * (MT / 4);

    const int lrow = lane >> 3;
    const int lke  = (((lane & 7) ^ lrow) * 8);      // XOR-swizzled seg
    const int sw   = l16 & 7;

    f32x4 acc[MI][4] = {};

    for (int k0 = 0; k0 < g.K; k0 += 64) {
#pragma unroll
        for (int p = 0; p < 2 * MI; ++p) {
            const int R = (wave * 2 * MI + p) * 8;
            const bf16* src = A + (size_t)(tile_m + R + lrow) * g.lda + k0 + lke;
            __builtin_amdgcn_global_load_lds((gas_ptr)src, (las_ptr)(aL + R * 64), 16, 0, 0);
        }
#pragma unroll
        for (int p = 0; p < 2; ++p) {
            const int R = (wave * 2 + p) * 8;
            const bf16* src = BT + (size_t)(tile_n + R + lrow) * g.ldb + k0 + lke;
            __builtin_amdgcn_global_load_lds((gas_ptr)src, (las_ptr)(bL + R * 64), 16, 0, 0);
        }
        __syncthreads();

#pragma unroll
        for (int ks = 0; ks < 2; ++ks) {
            s16x8 af[MI], bfr[4];
#pragma unroll
            for (int i = 0; i < MI; ++i)
                af[i] = *(const s16x8*)(&aL[(wrow + i * 16 + l16) * 64 +
                                            (((ks * 4 + quad) ^ sw) * 8)]);
#pragma unroll
            for (int j = 0; j < 4; ++j)
                bfr[j] = *(const s16x8*)(&bL[(j * 16 + l16) * 64 +
                                             (((ks * 4 + quad) ^ sw) * 8)]);

#pragma unroll
            for (int i = 0; i < MI; ++i)
#pragma unroll
                for (int j = 0; j < 4; ++j)
                    acc[i][j] = __builtin_amdgcn_mfma_f32_16x16x32_bf16(
                        af[i], bfr[j], acc[i][j], 0, 0, 0);
        }
        __syncthreads();
    }

    // D mapping: col = lane&15, row = (lane>>4)*4 + reg   [m89-verified]
    if (g.flags & 1) {
#pragma unroll
        for (int jp = 0; jp < 2; ++jp) {
            const int colL = tile_n + jp * 16 + l16;
            if ((g.flags & 2) && colL >= g.N) continue;
            const float fr = powf(10000.f, -(float)(jp * 16 + l16) / 32.f);
#pragma unroll
            for (int i = 0; i < MI; ++i) {
#pragma unroll
                for (int r = 0; r < 4; ++r) {
                    const int row = tile_m + wrow + i * 16 + quad * 4 + r;
                    float sv, cv;
                    sincosf((float)(g.t0 + row) * fr, &sv, &cv);
                    const float x0 = acc[i][jp][r];
                    const float x1 = acc[i][jp + 2][r];
                    C[(size_t)row * g.ldc + colL]      = __float2bfloat16(x0 * cv - x1 * sv);
                    C[(size_t)row * g.ldc + colL + 32] = __float2bfloat16(x1 * cv + x0 * sv);
                }
            }
        }
    } else if (g.flags & 4) {
        float* Cf = (float*)C;
#pragma unroll
        for (int j = 0; j < 4; ++j) {
            const int col = tile_n + j * 16 + l16;
#pragma unroll
            for (int i = 0; i < MI; ++i)
#pragma unroll
                for (int r = 0; r < 4; ++r) {
                    const int row = tile_m + wrow + i * 16 + quad * 4 + r;
                    Cf[(size_t)row * g.ldc + col] = acc[i][j][r];
                }
        }
    } else {
#pragma unroll
        for (int j = 0; j < 4; ++j) {
            const int col = tile_n + j * 16 + l16;
            if ((g.flags & 2) && col >= g.N) continue;
#pragma unroll
            for (int i = 0; i < MI; ++i)
#pragma unroll
                for (int r = 0; r < 4; ++r) {
                    const int row = tile_m + wrow + i * 16 + quad * 4 + r;
                    C[(size_t)row * g.ldc + col] = __float2bfloat16(acc[i][j][r]);
                }
        }
    }
}

// ---------------------------------------------------------------------------
// Batched transpose+convert: fp32 (R x C) -> bf16 (C x R), 32x32 LDS tiles.
// ---------------------------------------------------------------------------
struct TDesc { const float* src; bf16* dst; int R; int C; int tiles; int ctiles; };
struct TPack { TDesc d[8]; int n; };

__global__ __launch_bounds__(256)
void transpose_batch(TPack p)
{
    int b = blockIdx.x;
    int mi = 0;
    while (mi < p.n - 1 && b >= p.d[mi].tiles) { b -= p.d[mi].tiles; ++mi; }
    const TDesc d = p.d[mi];
    const int tr = b / d.ctiles, tc = b % d.ctiles;
    const int r0 = tr * 32, c0 = tc * 32;

    __shared__ float lds[32][33];
    const int tx = threadIdx.x & 31, ty = threadIdx.x >> 5;
#pragma unroll
    for (int i = 0; i < 4; ++i)
        lds[ty * 4 + i][tx] = d.src[(size_t)(r0 + ty * 4 + i) * d.C + c0 + tx];
    __syncthreads();
#pragma unroll
    for (int i = 0; i < 4; ++i)
        d.dst[(size_t)(c0 + ty * 4 + i) * d.R + r0 + tx] =
            __float2bfloat16(lds[tx][ty * 4 + i]);
}

// ---------------------------------------------------------------------------
// Batched fp32 -> bf16 convert (no transpose), 8 elems/thread, 2 segments.
// ---------------------------------------------------------------------------
__global__ __launch_bounds__(256)
void convert2(const float* s0, bf16* d0, int n0,
              const float* s1, bf16* d1, int n1)
{
    int i = blockIdx.x * blockDim.x + threadIdx.x;   // 8-elem units
    const float* s; bf16* d;
    if (i < n0) { s = s0; d = d0; }
    else if (i < n0 + n1) { i -= n0; s = s1; d = d1; }
    else return;
    const float4 a = *(const float4*)(s + (size_t)i * 8);
    const float4 b = *(const float4*)(s + (size_t)i * 8 + 4);
    bf16 t[8];
    t[0] = __float2bfloat16(a.x); t[1] = __float2bfloat16(a.y);
    t[2] = __float2bfloat16(a.z); t[3] = __float2bfloat16(a.w);
    t[4] = __float2bfloat16(b.x); t[5] = __float2bfloat16(b.y);
    t[6] = __float2bfloat16(b.z); t[7] = __float2bfloat16(b.w);
    *(uint4*)(d + (size_t)i * 8) = *(uint4*)t;
}

// ---------------------------------------------------------------------------
// MLA-absorbed sparse attention (round-5 proven). One block per query t.
// ---------------------------------------------------------------------------
__global__ __launch_bounds__(256)
void attn_mla(const bf16* __restrict__ qt,   // [rows][8192] chunk (q~ per head)
              const bf16* __restrict__ qr,   // [rows][1024] chunk (rope'd)
              const bf16* __restrict__ xw,   // [2048][1024], ckv = cols 512..1023
              const bf16* __restrict__ kr,   // [2048][64] (rope'd)
              const int*  __restrict__ topk, // [2048][32]
              bf16* __restrict__ U,          // [rows][8192]
              int t0)
{
    __shared__ short ckv_s[32 * 520];
    __shared__ short qt_s[16 * 520];
    __shared__ short kr_s[32 * 72];
    __shared__ short qr_s[16 * 72];
    __shared__ short P_s[4][16 * 40];
    __shared__ int   idx_s[32];

    const int tl   = blockIdx.x;
    const int tg   = t0 + tl;
    const int tid  = threadIdx.x;
    const int wv   = tid >> 6;
    const int lane = tid & 63;
    const int quad = lane >> 4;
    const int l16  = lane & 15;

    if (tid < 32) {
        int j = topk[(size_t)tg * TOPK + tid];
        idx_s[tid] = (j < 0 || j >= T_SEQ) ? 0 : j;
    }
    __syncthreads();

#pragma unroll
    for (int i = 0; i < 8; ++i) {
        const int row = wv * 8 + i;
        const int j = idx_s[row];
        __builtin_amdgcn_global_load_lds(
            (gas_ptr)(xw + (size_t)j * 1024 + 512 + lane * 8),
            (las_ptr)(ckv_s + row * 520), 16, 0, 0);
    }
#pragma unroll
    for (int i = 0; i < 4; ++i) {
        const int seg = wv * 4 + i;
        __builtin_amdgcn_global_load_lds(
            (gas_ptr)(qt + (size_t)tl * 8192 + seg * 512 + lane * 8),
            (las_ptr)(qt_s + seg * 520), 16, 0, 0);
    }
    {
        const int row = tid >> 3, seg = tid & 7;
        const int j = idx_s[row];
        *(uint4*)(kr_s + row * 72 + seg * 8) =
            *(const uint4*)(kr + (size_t)j * RD + seg * 8);
    }
    if (tid < 128) {
        const int head = tid >> 3, seg = tid & 7;
        *(uint4*)(qr_s + head * 72 + seg * 8) =
            *(const uint4*)(qr + (size_t)tl * 1024 + head * 64 + seg * 8);
    }
    __syncthreads();

    f32x4 sc[2] = {};
#pragma unroll
    for (int ks = 0; ks < 16; ++ks) {
        s16x8 a  = *(const s16x8*)(qt_s + l16 * 520 + ks * 32 + quad * 8);
        s16x8 b0 = *(const s16x8*)(ckv_s + l16 * 520 + ks * 32 + quad * 8);
        s16x8 b1 = *(const s16x8*)(ckv_s + (16 + l16) * 520 + ks * 32 + quad * 8);
        sc[0] = __builtin_amdgcn_mfma_f32_16x16x32_bf16(a, b0, sc[0], 0, 0, 0);
        sc[1] = __builtin_amdgcn_mfma_f32_16x16x32_bf16(a, b1, sc[1], 0, 0, 0);
    }
#pragma unroll
    for (int ks = 0; ks < 2; ++ks) {
        s16x8 a  = *(const s16x8*)(qr_s + l16 * 72 + ks * 32 + quad * 8);
        s16x8 b0 = *(const s16x8*)(kr_s + l16 * 72 + ks * 32 + quad * 8);
        s16x8 b1 = *(const s16x8*)(kr_s + (16 + l16) * 72 + ks * 32 + quad * 8);
        sc[0] = __builtin_amdgcn_mfma_f32_16x16x32_bf16(a, b0, sc[0], 0, 0, 0);
        sc[1] = __builtin_amdgcn_mfma_f32_16x16x32_bf16(a, b1, sc[1], 0, 0, 0);
    }

    const float scale = 0.0721687836487032f;   // 1/sqrt(192)
    float inv[4];
    short* pw = P_s[wv];
#pragma unroll
    for (int r = 0; r < 4; ++r) {
        float s0 = sc[0][r] * scale, s1 = sc[1][r] * scale;
        float mx = fmaxf(s0, s1);
#pragma unroll
        for (int off = 1; off < 16; off <<= 1) mx = fmaxf(mx, __shfl_xor(mx, off));
        float p0 = __expf(s0 - mx), p1 = __expf(s1 - mx);
        float l = p0 + p1;
#pragma unroll
        for (int off = 1; off < 16; off <<= 1) l += __shfl_xor(l, off);
        inv[r] = 1.f / l;
        pw[(quad * 4 + r) * 40 + l16]      = __builtin_bit_cast(short, __float2bfloat16(p0));
        pw[(quad * 4 + r) * 40 + 16 + l16] = __builtin_bit_cast(short, __float2bfloat16(p1));
    }

    s16x8 ap = *(const s16x8*)(pw + l16 * 40 + quad * 8);
#pragma unroll
    for (int tt = 0; tt < 8; ++tt) {
        const int n0 = wv * 128 + tt * 16;
        s16x8 b;
#pragma unroll
        for (int j = 0; j < 8; ++j)
            b[j] = ckv_s[(quad * 8 + j) * 520 + n0 + l16];
        f32x4 u = {};
        u = __builtin_amdgcn_mfma_f32_16x16x32_bf16(ap, b, u, 0, 0, 0);
#pragma unroll
        for (int r = 0; r < 4; ++r)
            U[(size_t)tl * 8192 + (quad * 4 + r) * 512 + n0 + l16] =
                __float2bfloat16(u[r] * inv[r]);
    }
}

// ---------------------------------------------------------------------------
extern "C" void kernel_launch(void* const* d_in, const int* in_sizes, int n_in,
                              void* d_out, int out_size, void* d_ws, size_t ws_size,
                              hipStream_t stream)
{
    const float* x    = (const float*)d_in[0];
    const float* Wqd  = (const float*)d_in[1];
    const float* Wqu  = (const float*)d_in[2];
    const float* Wqr  = (const float*)d_in[3];
    const float* Wkvd = (const float*)d_in[4];
    const float* Wku  = (const float*)d_in[5];
    const float* Wvu  = (const float*)d_in[6];
    const float* Wkr  = (const float*)d_in[7];
    const float* Wo   = (const float*)d_in[8];
    const int*   topk = (const int*)d_in[9];
    float* out = (float*)d_out;

    const size_t KB = 1024;
    char* ws = (char*)d_ws;
    const bool flat = ws_size >= (size_t)128000 * KB;
    const int  TCH  = flat ? 2048 : 512;
    const int  NCH  = T_SEQ / TCH;

    // q~ factorization (r10): q = ql@Wqu (ref-exact), q~_h = q_h@Wku_h^T
    // (rank-128 bottleneck) -> 8.6 GF vs 17.2+1.1 GF for the Wcomb path.
    size_t oXB, oWxT, oWkrT, oWquT, oWkub, oWqrT, oWvuT, oQ, oXW, oKR,
           oQR, oO, oWoT, oQT, oU;
    if (flat) {
        oXB = 0;       oWxT = 8192;   oWkrT = 12288; oWquT = 12544;
        oWkub = 14592; oWqrT = 16640; oWvuT = 17664; oQ = 19712;
        oXW = 27904;   oKR = 32000;   oQR = 32256;   oO = 36352;
        oWoT = 44544;  oQT = 52736;   oU = 85504;
    } else {
        // chunked (TCH=512), 38.3 MB peak; xb/WxT/WkrT die after phase B,
        // q aliases into dead-xb region, WoT over dead qt at the end.
        oXW = 0;       oKR = 4096;    oWquT = 4352;  oWkub = 6400;
        oWqrT = 8448;  oWvuT = 9472;  oO = 11520;    oXB = 19712;
        oWxT = 27904;  oWkrT = 32000; oQ = 19712;    oQT = 21760;
        oQR = 29952;   oU = 30976;    oWoT = 21760;
    }
    bf16* xb   = (bf16*)(ws + oXB * KB);
    bf16* WxT  = (bf16*)(ws + oWxT * KB);
    bf16* WkrT = (bf16*)(ws + oWkrT * KB);
    bf16* WquT = (bf16*)(ws + oWquT * KB);
    bf16* Wkub = (bf16*)(ws + oWkub * KB);
    bf16* WqrT = (bf16*)(ws + oWqrT * KB);
    bf16* WvuT = (bf16*)(ws + oWvuT * KB);
    bf16* qB   = (bf16*)(ws + oQ * KB);
    bf16* xw   = (bf16*)(ws + oXW * KB);
    bf16* kr   = (bf16*)(ws + oKR * KB);
    bf16* qrC  = (bf16*)(ws + oQR * KB);
    bf16* o    = (bf16*)(ws + oO * KB);
    bf16* WoT  = (bf16*)(ws + oWoT * KB);
    bf16* qtC  = (bf16*)(ws + oQT * KB);
    bf16* uC   = (bf16*)(ws + oU * KB);

    dim3 blk(256);

    // Phase A: convert (x, Wku) + transposes (Wqd,Wkvd,Wkr,Wqr,Wvu,Wqu[,Wo])
    {
        int n0 = T_SEQ * DIM / 8, n1 = LAT * DIM / 8;
        convert2<<<(n0 + n1 + 255) / 256, blk, 0, stream>>>(x, xb, n0, Wku, Wkub, n1);
        TPack p;
        p.d[0] = { Wqd,  WxT,                   DIM, LAT,  (DIM/32)*(LAT/32),  LAT/32 };
        p.d[1] = { Wkvd, WxT + (size_t)LAT*DIM, DIM, LAT,  (DIM/32)*(LAT/32),  LAT/32 };
        p.d[2] = { Wkr,  WkrT,                  DIM, RD,   (DIM/32)*(RD/32),   RD/32  };
        p.d[3] = { Wqr,  WqrT,                  LAT, 1024, (LAT/32)*(1024/32), 1024/32 };
        p.d[4] = { Wvu,  WvuT,                  LAT, DIM,  (LAT/32)*(DIM/32),  DIM/32 };
        p.d[5] = { Wqu,  WquT,                  LAT, DIM,  (LAT/32)*(DIM/32),  DIM/32 };
        p.n = 6;
        int tot = 0;
        for (int i = 0; i < p.n; ++i) tot += p.d[i].tiles;
        if (flat) {
            p.d[6] = { Wo, WoT, DIM, DIM, (DIM/32)*(DIM/32), DIM/32 };
            p.n = 7; tot += p.d[6].tiles;
        }
        transpose_batch<<<tot, blk, 0, stream>>>(p);
    }

    // Phase B (64x64 tiles -> 544 blocks): xw = xb@WxT^T | kr (rope)
    {
        GPack gp;
        gp.g[0] = { xb, WxT,  xw, DIM, DIM, DIM, 1024, 1024/64, T_SEQ/64, 1,
                    0, 0, 0, (1024/64)*(T_SEQ/64), 0, 1024, 0 };
        gp.g[1] = { xb, WkrT, kr, DIM, DIM, DIM, RD,   1,       T_SEQ/64, 1,
                    0, 0, 0, T_SEQ/64, 1 /*rope*/, RD, 0 };
        gp.n = 2;
        gemm_group64<64><<<gp.g[0].tiles + gp.g[1].tiles, blk, 0, stream>>>(gp);
    }

    // Phase C/D per chunk: {q, qr(+rope)} group -> q~ (z=16, K=128) ->
    // attention -> U-projection
    for (int c = 0; c < NCH; ++c) {
        const int t0 = c * TCH;
        bf16* q  = flat ? qB  + (size_t)t0 * 2048 : qB;
        bf16* qt = flat ? qtC + (size_t)t0 * 8192 : qtC;
        bf16* qr = flat ? qrC + (size_t)t0 * 1024 : qrC;
        bf16* U  = flat ? uC  + (size_t)t0 * 8192 : uC;
        const bf16* xwc = xw + (size_t)t0 * 1024;

        {
            GPack gp;
            gp.g[0] = { xwc, WquT, q,  LAT, 1024, LAT, 2048, 2048/64, TCH/128, 1,
                        0, 0, 0, (2048/64)*(TCH/128), 0, 2048, 0 };
            gp.g[1] = { xwc, WqrT, qr, LAT, 1024, LAT, 1024, 1024/64, TCH/128, 1,
                        0, 0, 0, (1024/64)*(TCH/128), 1 /*rope*/, 1024, t0 };
            gp.n = 2;
            gemm_group64<128><<<gp.g[0].tiles + gp.g[1].tiles, blk, 0, stream>>>(gp);
        }
        {
            GPack gp;  // q~_h = q_h @ Wku_h^T : M=TCH, N=512, K=128, z=16
            gp.g[0] = { q, Wkub, qt, 128, 2048, 2048, 8192, 512/64, TCH/128, NH,
                        128, 128, 512, (512/64)*(TCH/128)*NH, 0, 512, 0 };
            gp.n = 1;
            gemm_group64<128><<<gp.g[0].tiles, blk, 0, stream>>>(gp);
        }
        attn_mla<<<TCH, blk, 0, stream>>>(qt, qr, xw, kr, topk, U, t0);
        {
            GPack gp;
            gp.g[0] = { U, WvuT, o + (size_t)t0 * DIM, LAT, 8192, LAT, DIM,
                        2, TCH/128, NH, 512, (long)128*LAT, 128,
                        2*(TCH/128)*NH, 0, 128, 0 };
            gp.n = 1;
            gemm_group64<128><<<gp.g[0].tiles, blk, 0, stream>>>(gp);
        }
    }

    // Phase E: out = o @ WoT^T (fp32), 512 blocks
    if (!flat) {
        TPack p;
        p.d[0] = { Wo, WoT, DIM, DIM, (DIM/32)*(DIM/32), DIM/32 };
        p.n = 1;
        transpose_batch<<<p.d[0].tiles, blk, 0, stream>>>(p);
    }
    {
        GPack gp;
        gp.g[0] = { o, WoT, (bf16*)out, DIM, DIM, DIM, DIM,
                    DIM/64, T_SEQ/128, 1, 0, 0, 0,
                    (DIM/64)*(T_SEQ/128), 4 /*fp32*/, DIM, 0 };
        gp.n = 1;
        gemm_group64<128><<<gp.g[0].tiles, blk, 0, stream>>>(gp);
    }
}